// Round 18
// baseline (1211.992 us; speedup 1.0000x reference)
//
#include <hip/hip_runtime.h>

#define HID 256
#define BATCH 512
#define MENC 16
#define HWIN 25
#define SALSZ 4096
#define BH (BATCH * HID)   // 131072

typedef __attribute__((ext_vector_type(8))) short bf16x8;
typedef __attribute__((ext_vector_type(4))) float f32x4;

__device__ __forceinline__ float sigmf(float x) { return 1.0f / (1.0f + __expf(-x)); }
__device__ __forceinline__ ushort f2bf(float f) {
    uint32_t u = __float_as_uint(f);
    return (ushort)((u + 0x7fffu + ((u >> 16) & 1u)) >> 16);   // RNE
}

#define GLOAD_LDS(gp, lp) \
    __builtin_amdgcn_global_load_lds((const __attribute__((address_space(1))) void*)(gp), \
                                     (__attribute__((address_space(3))) void*)(lp), 16, 0, 0)

// ---- wide write-through store for cross-block exchange (L3-visible) ----
__device__ __forceinline__ void st_u64(void* p, unsigned long long v) {
    __hip_atomic_store((unsigned long long*)p, v, __ATOMIC_RELAXED, __HIP_MEMORY_SCOPE_AGENT);
}

// ---- split fence-free barrier (R14-proven) ----
__device__ __forceinline__ void gbar_arrive(unsigned int* slot)
{
    __syncthreads();    // drains vmcnt: this block's stores are L3-acked
    if (threadIdx.x == 0) atomicAdd(slot, 1u);
}
__device__ __forceinline__ void gbar_wait(unsigned int* slot, unsigned int nblk)
{
    if (threadIdx.x == 0) {
        while (__hip_atomic_load(slot, __ATOMIC_RELAXED, __HIP_MEMORY_SCOPE_AGENT) < nblk)
            __builtin_amdgcn_s_sleep(1);
    }
    __syncthreads();
}

// ---- W tile staging for chains: [64][256] bf16, XOR-swizzled 16B units ----
__device__ __forceinline__ void stage_wtile(const ushort* Wsrc, int ldw, int u0,
                                            ushort* lds, int lane, int wq)
{
    const int sub = lane >> 5, uu = lane & 31;
#pragma unroll
    for (int i = 0; i < 8; ++i) {
        const int row = i * 8 + wq * 2 + sub;
        const int su  = uu ^ (row & 7);
        const int gr  = (row >> 4) * HID + u0 + (row & 15);
        GLOAD_LDS(Wsrc + (size_t)gr * ldw + su * 8, lds + i * 2048 + wq * 512);
    }
}

// ---- chain cell quarter: H from global, W from swizzled LDS; 32 MFMA/wave ----
__device__ __forceinline__ void cell_g(const ushort* hrow0, int ldh,
                                       const ushort* WsL, f32x4 acc[4], int lane)
{
    const int fr = lane & 15, fq = lane >> 4;
    const ushort* hrow = hrow0 + (size_t)fr * ldh;
#pragma unroll
    for (int ks = 0; ks < 8; ++ks) {
        const bf16x8 af = *(const bf16x8*)(hrow + ks * 32 + fq * 8);
#pragma unroll
        for (int g = 0; g < 4; ++g) {
            const int vr = g * 16 + fr;
            const bf16x8 bf = *(const bf16x8*)(WsL + vr * 256 + (((ks * 4 + fq)) ^ (vr & 7)) * 8);
            acc[g] = __builtin_amdgcn_mfma_f32_16x16x32_bf16(af, bf, acc[g], 0, 0, 0);
        }
    }
}

// ---------------- fp32 -> bf16, 9 weight segments in one launch ----------------
struct Cvt9 {
    const float* s[9];
    ushort*      d[9];
    int          end[9];
};
__global__ __launch_bounds__(256)
void cvt_multi(Cvt9 A)
{
    int i = blockIdx.x * 256 + threadIdx.x;
    if (i >= A.end[8]) return;
    int seg = 0, beg = 0;
#pragma unroll
    for (int k = 0; k < 8; ++k)
        if (i >= A.end[k]) { seg = k + 1; beg = A.end[k]; }
    const int j = i - beg;
    const float4 v = *(const float4*)(A.s[seg] + (size_t)j * 4);
    *(ushort4*)(A.d[seg] + (size_t)j * 4) = make_ushort4(f2bf(v.x), f2bf(v.y), f2bf(v.z), f2bf(v.w));
}

// ======== 256x128 GEMM, BK=32, 48 KB LDS -> 2 blocks/CU; fused fp32->bf16 A. ========
// Swizzle s(row) = (row>>1)&3 on 16B units (64B rows), same involution on A-src,
// B-src and fragment reads. Two jobs (se + sd) in one launch.
__device__ __forceinline__ void loadA32(const float* Ag, int lda, int tid, float4 ra[4])
{
    const int row = tid >> 1, ub = tid & 1;
#pragma unroll
    for (int i = 0; i < 2; ++i) {
        const int u = ub + i * 2;
        const int su = u ^ ((row >> 1) & 3);
        ra[2 * i + 0] = *(const float4*)(Ag + (size_t)row * lda + su * 8);
        ra[2 * i + 1] = *(const float4*)(Ag + (size_t)row * lda + su * 8 + 4);
    }
}
__device__ __forceinline__ void writeA32(const float4 ra[4], ushort* Al, int tid)
{
    const int row = tid >> 1, ub = tid & 1;
#pragma unroll
    for (int i = 0; i < 2; ++i) {
        const int u = ub + i * 2;
        uint4 v;
        v.x = (uint)f2bf(ra[2 * i].x) | ((uint)f2bf(ra[2 * i].y) << 16);
        v.y = (uint)f2bf(ra[2 * i].z) | ((uint)f2bf(ra[2 * i].w) << 16);
        v.z = (uint)f2bf(ra[2 * i + 1].x) | ((uint)f2bf(ra[2 * i + 1].y) << 16);
        v.w = (uint)f2bf(ra[2 * i + 1].z) | ((uint)f2bf(ra[2 * i + 1].w) << 16);
        *(uint4*)(Al + row * 32 + u * 8) = v;
    }
}
__device__ __forceinline__ void stageB32(const ushort* Bg, int ldw, ushort* Bl, int tid)
{
    const int row = tid >> 2, u = tid & 3;
    const int su = u ^ ((row >> 1) & 3);
    GLOAD_LDS(Bg + (size_t)row * ldw + su * 8, Bl + row * 32 + u * 8);
}

struct GemmJob { const float* A; const ushort* W; float* C; int nwg; };

__global__ __launch_bounds__(512, 4)
void gemm256f2(GemmJob j0, GemmJob j1)
{
    __shared__ ushort As[2][256 * 32];   // 32 KB
    __shared__ ushort Bs[2][128 * 32];   // 16 KB
    const int tid = threadIdx.x, lane = tid & 63, wid = tid >> 6;

    const GemmJob J = (blockIdx.x < (unsigned)j0.nwg) ? j0 : j1;
    int bid = (blockIdx.x < (unsigned)j0.nwg) ? blockIdx.x : blockIdx.x - j0.nwg;
    {   // bijective XCD-chunked swizzle within this job's sub-grid
        const int nwg = J.nwg, q = nwg >> 3, r = nwg & 7;
        const int xcd = bid & 7, o = bid >> 3;
        bid = (xcd < r) ? xcd * (q + 1) + o : r * (q + 1) + (xcd - r) * q + o;
    }
    const int gx = 8;   // N = 1024 -> 8 n-tiles of 128
    const int m0 = (bid / gx) * 256, n0 = (bid % gx) * 128;
    const int lda = SALSZ, ldw = SALSZ, ldc = 1024, K = SALSZ;

    const int wr = wid >> 1, wc = wid & 1;     // 4m x 2n wave grid
    const int fr = lane & 15, fq = lane >> 4;

    f32x4 acc[4][4] = {};
    const int nt = K / 32;
    const float*  Ab0 = J.A + (size_t)m0 * lda;
    const ushort* Bb0 = J.W + (size_t)n0 * ldw;

    float4 ra[4];
    loadA32(Ab0, lda, tid, ra);              // 4 loads (A0)
    stageB32(Bb0, ldw, Bs[0], tid);          // 1 load  (B0)
    writeA32(ra, As[0], tid);                // waits A0
    loadA32(Ab0 + 32, lda, tid, ra);         // 4 loads (A1, in flight)
    asm volatile("s_waitcnt vmcnt(4) lgkmcnt(0)" ::: "memory");  // B0 done
    __builtin_amdgcn_sched_barrier(0);
    __builtin_amdgcn_s_barrier();
    __builtin_amdgcn_sched_barrier(0);

    for (int t = 0; t < nt; ++t) {
        const int p = t & 1;
        const int t1 = (t + 1 < nt) ? t + 1 : nt - 1;
        const int t2 = (t + 2 < nt) ? t + 2 : nt - 1;
        stageB32(Bb0 + t1 * 32, ldw, Bs[p ^ 1], tid);   // 1 load
        writeA32(ra, As[p ^ 1], tid);                    // A(t+1) -> LDS
        loadA32(Ab0 + t2 * 32, lda, tid, ra);            // 4 loads (A t+2)

        const ushort* Ab = As[p];
        const ushort* Bb = Bs[p];
        bf16x8 bfr[4];
#pragma unroll
        for (int nf = 0; nf < 4; ++nf) {
            const int row = wc * 64 + nf * 16 + fr;
            bfr[nf] = *(const bf16x8*)(Bb + row * 32 + (fq ^ ((row >> 1) & 3)) * 8);
        }
        bf16x8 af[4];
#pragma unroll
        for (int mf = 0; mf < 4; ++mf) {
            const int row = wr * 64 + mf * 16 + fr;
            af[mf] = *(const bf16x8*)(Ab + row * 32 + (fq ^ ((row >> 1) & 3)) * 8);
        }
        __builtin_amdgcn_s_setprio(1);
#pragma unroll
        for (int mf = 0; mf < 4; ++mf)
#pragma unroll
            for (int nf = 0; nf < 4; ++nf)
                acc[mf][nf] = __builtin_amdgcn_mfma_f32_16x16x32_bf16(
                    af[mf], bfr[nf], acc[mf][nf], 0, 0, 0);
        __builtin_amdgcn_s_setprio(0);

        if (t == nt - 1) break;
        asm volatile("s_waitcnt vmcnt(4) lgkmcnt(0)" ::: "memory");
        __builtin_amdgcn_sched_barrier(0);
        __builtin_amdgcn_s_barrier();
        __builtin_amdgcn_sched_barrier(0);
    }

    const int cl = lane & 15, ch = lane >> 4;
#pragma unroll
    for (int mf = 0; mf < 4; ++mf)
#pragma unroll
        for (int nf = 0; nf < 4; ++nf)
#pragma unroll
            for (int r = 0; r < 4; ++r)
                J.C[(size_t)(m0 + wr * 64 + mf * 16 + ch * 4 + r) * ldc
                    + n0 + wc * 64 + nf * 16 + cl] = acc[mf][nf][r];
}

// ---------------- 128x128 bf16 MFMA GEMM (small shapes) ----------------
__global__ __launch_bounds__(256)
void gemm_mfma_bt(const ushort* __restrict__ A, const ushort* __restrict__ W,
                  float* __restrict__ C, int M, int N, int K,
                  int lda, int ldw, int ldc, const float* __restrict__ rbias)
{
    __shared__ ushort As[128 * 32];
    __shared__ ushort Bs[128 * 32];
    const int t    = threadIdx.x;
    const int lane = t & 63, wid = t >> 6;
    const int m0 = blockIdx.y * 128, n0 = blockIdx.x * 128;
    const int wr = wid >> 1, wc = wid & 1;

    f32x4 acc[4][4] = {};

    const int sr = wid * 16 + (lane >> 2);
    const int su = ((lane & 3) ^ ((lane >> 3) & 3)) * 8;
    const ushort* Ag = A + (size_t)(m0 + sr) * lda + su;
    const ushort* Wg = W + (size_t)(n0 + sr) * ldw + su;
    ushort* Al = As + wid * 512;
    ushort* Bl = Bs + wid * 512;

    const int fr = lane & 15;
    const int fq = lane >> 4;
    const int sw = (fr >> 1) & 3;

    for (int k0 = 0; k0 < K; k0 += 32) {
        GLOAD_LDS(Ag,                    Al);
        GLOAD_LDS(Ag + (size_t)64 * lda, Al + 2048);
        GLOAD_LDS(Wg,                    Bl);
        GLOAD_LDS(Wg + (size_t)64 * ldw, Bl + 2048);
        Ag += 32; Wg += 32;
        __syncthreads();

        bf16x8 af[4], bfr[4];
#pragma unroll
        for (int m = 0; m < 4; ++m)
            af[m] = *(const bf16x8*)(As + (wr * 64 + m * 16 + fr) * 32 + (fq ^ sw) * 8);
#pragma unroll
        for (int n = 0; n < 4; ++n)
            bfr[n] = *(const bf16x8*)(Bs + (wc * 64 + n * 16 + fr) * 32 + (fq ^ sw) * 8);
#pragma unroll
        for (int m = 0; m < 4; ++m)
#pragma unroll
            for (int n = 0; n < 4; ++n)
                acc[m][n] = __builtin_amdgcn_mfma_f32_16x16x32_bf16(af[m], bfr[n], acc[m][n], 0, 0, 0);
        __syncthreads();
    }

    const int cl = lane & 15, ch = lane >> 4;
#pragma unroll
    for (int m = 0; m < 4; ++m)
#pragma unroll
        for (int n = 0; n < 4; ++n)
#pragma unroll
            for (int r = 0; r < 4; ++r) {
                const int mm = m0 + wr * 64 + m * 16 + ch * 4 + r;
                const int nn = n0 + wc * 64 + n * 16 + cl;
                float v = acc[m][n][r];
                if (rbias) v += rbias[(size_t)(mm & 511) * ldc + nn];
                C[(size_t)mm * ldc + nn] = v;
            }
}

// ---------------- fp32 tiled GEMM (GBIAS one-off) ----------------
__global__ __launch_bounds__(256)
void gemm_tn(const float* __restrict__ A, const float* __restrict__ W,
             const float* __restrict__ b1, const float* __restrict__ b2,
             float* __restrict__ C,
             int M, int N, int K, int lda, int ldw, int ldc)
{
    __shared__ float AsT[16][68];
    __shared__ float WsT[16][68];
    const int t  = threadIdx.x;
    const int tx = t & 15, ty = t >> 4;
    const int m0 = blockIdx.y * 64, n0 = blockIdx.x * 64;
    const int lr = t >> 2;
    const int c4 = t & 3;

    float acc[4][4];
#pragma unroll
    for (int i = 0; i < 4; ++i)
#pragma unroll
        for (int j = 0; j < 4; ++j) acc[i][j] = 0.0f;

    for (int k0 = 0; k0 < K; k0 += 16) {
        float a[4], w[4];
        const int kb = k0 + c4 * 4;
#pragma unroll
        for (int k = 0; k < 4; ++k) {
            a[k] = (kb + k < K) ? A[(size_t)(m0 + lr) * lda + kb + k] : 0.0f;
            w[k] = (kb + k < K) ? W[(size_t)(n0 + lr) * ldw + kb + k] : 0.0f;
        }
        __syncthreads();
#pragma unroll
        for (int k = 0; k < 4; ++k) {
            AsT[c4 * 4 + k][lr] = a[k];
            WsT[c4 * 4 + k][lr] = w[k];
        }
        __syncthreads();
#pragma unroll
        for (int kk = 0; kk < 16; ++kk) {
            const float4 av = *(const float4*)&AsT[kk][ty * 4];
            const float4 wv = *(const float4*)&WsT[kk][tx * 4];
            acc[0][0] += av.x * wv.x; acc[0][1] += av.x * wv.y; acc[0][2] += av.x * wv.z; acc[0][3] += av.x * wv.w;
            acc[1][0] += av.y * wv.x; acc[1][1] += av.y * wv.y; acc[1][2] += av.y * wv.z; acc[1][3] += av.y * wv.w;
            acc[2][0] += av.z * wv.x; acc[2][1] += av.z * wv.y; acc[2][2] += av.z * wv.z; acc[2][3] += av.z * wv.w;
            acc[3][0] += av.w * wv.x; acc[3][1] += av.w * wv.y; acc[3][2] += av.w * wv.z; acc[3][3] += av.w * wv.w;
        }
    }

#pragma unroll
    for (int i = 0; i < 4; ++i) {
        const int m = m0 + ty * 4 + i;
#pragma unroll
        for (int j = 0; j < 4; ++j) {
            const int n = n0 + tx * 4 + j;
            float v = acc[i][j];
            if (b1) v += b1[n];
            if (b2) v += b2[n];
            C[(size_t)m * ldc + n] = v;
        }
    }
}

// ---------------- persistent encoder: se + pe chains, 16 steps ----------------
struct EncArgs {
    const ushort *WHse, *WHpe;
    const float  *xg_se;
    const float  *enc_pos;
    const float  *se_b1, *se_b2, *pe_b1, *pe_b2;
    const float  *pe_Wih;
    ushort       *conc;      // [16][512][512]
    float        *SE_C, *PE_C;
    unsigned int *bar;
};

__global__ __launch_bounds__(1024)
void enc_chain(EncArgs A)
{
    __shared__ ushort Ws[4][64 * 256];
    __shared__ ushort hloc[64][64];
    const int tid = threadIdx.x, lane = tid & 63, w = tid >> 6;
    const int role  = blockIdx.x >> 5;
    const int rem   = blockIdx.x & 31;
    const int btile = rem & 7, usup = rem >> 3;
    const int b0 = btile * 64, ub = usup * 64;
    const int usub = w & 3, bsub = w >> 2;
    const int u0t = ub + usub * 16;
    const int grp = role * 8 + btile;
    const int fr = lane & 15, fq = lane >> 4;
    const int u = u0t + fr;
    const int ul = usub * 16 + fr;
    const int coff = role ? 256 : 0;

    stage_wtile(role ? A.WHpe : A.WHse, HID, u0t, Ws[usub], lane, bsub);

    const float* b1 = role ? A.pe_b1 : A.se_b1;
    const float* b2 = role ? A.pe_b2 : A.se_b2;
    float bias[4], wxs[4][3];
#pragma unroll
    for (int g = 0; g < 4; ++g) {
        bias[g] = b1[g * HID + u] + b2[g * HID + u];
        wxs[g][0] = wxs[g][1] = wxs[g][2] = 0.0f;
        if (role) {
            wxs[g][0] = A.pe_Wih[(g * HID + u) * 3 + 0];
            wxs[g][1] = A.pe_Wih[(g * HID + u) * 3 + 1];
            wxs[g][2] = A.pe_Wih[(g * HID + u) * 3 + 2];
        }
    }
    float c[4] = {0.f, 0.f, 0.f, 0.f};
    __syncthreads();

    for (int t = 0; t < MENC; ++t) {
        float xg[4][4];
#pragma unroll
        for (int r = 0; r < 4; ++r) {
            const int b = b0 + bsub * 16 + fq * 4 + r;
            if (role) {
                const float* xp = A.enc_pos + ((size_t)b * MENC + t) * 3;
                xg[r][0] = xp[0]; xg[r][1] = xp[1]; xg[r][2] = xp[2]; xg[r][3] = 0.f;
            } else {
#pragma unroll
                for (int g = 0; g < 4; ++g)
                    xg[r][g] = A.xg_se[((size_t)b * MENC + t) * 1024 + g * HID + u];
            }
        }
        if (t > 0) gbar_wait(A.bar + grp * MENC + (t - 1), 4);
        f32x4 acc[4] = {};
        if (t > 0)
            cell_g(A.conc + ((size_t)(t - 1) * 512 + b0 + bsub * 16) * 512 + coff, 512,
                   Ws[usub], acc, lane);
#pragma unroll
        for (int r = 0; r < 4; ++r) {
            const int bl = bsub * 16 + fq * 4 + r;
            const int b = b0 + bl;
            float gv[4];
#pragma unroll
            for (int g = 0; g < 4; ++g) {
                float v = acc[g][r] + bias[g];
                if (role) v += xg[r][0] * wxs[g][0] + xg[r][1] * wxs[g][1] + xg[r][2] * wxs[g][2];
                else      v += xg[r][g];
                gv[g] = v;
            }
            const float cn = sigmf(gv[1]) * c[r] + sigmf(gv[0]) * tanhf(gv[2]);
            const float hn = sigmf(gv[3]) * tanhf(cn);
            c[r] = cn;
            hloc[bl][ul] = f2bf(hn);
            if (t == MENC - 1) (role ? A.PE_C : A.SE_C)[(size_t)b * HID + u] = cn;
        }
        __syncthreads();
        {
            const int row = tid >> 4, c8 = tid & 15;
            const unsigned long long v = *(const unsigned long long*)&hloc[row][c8 * 4];
            st_u64(A.conc + ((size_t)t * 512 + b0 + row) * 512 + coff + ub + c8 * 4, v);
        }
        if (t != MENC - 1) gbar_arrive(A.bar + grp * MENC + t);
    }
}

// ---------------- persistent mid: sd (25) + fe (16) ----------------
struct MidArgs {
    const ushort *WHsd, *WHfe;
    const float  *xg_sd;
    const float  *xg_fe;
    const float  *sd_b1, *sd_b2, *fe_b1, *fe_b2;
    const ushort *conc;
    const float  *SE_C;
    ushort       *SDB;       // [25][512][256]
    ushort       *FEB;       // [16][512][256]
    float        *FEH, *FE_C;
    unsigned int *bar;
};

__global__ __launch_bounds__(1024)
void mid_chain(MidArgs A)
{
    __shared__ ushort Ws[4][64 * 256];
    __shared__ ushort hloc[64][64];
    const int tid = threadIdx.x, lane = tid & 63, w = tid >> 6;
    const int role  = blockIdx.x >> 5;
    const int rem   = blockIdx.x & 31;
    const int btile = rem & 7, usup = rem >> 3;
    const int b0 = btile * 64, ub = usup * 64;
    const int usub = w & 3, bsub = w >> 2;
    const int u0t = ub + usub * 16;
    const int grp = role * 8 + btile;
    const int fr = lane & 15, fq = lane >> 4;
    const int u = u0t + fr;
    const int ul = usub * 16 + fr;
    const int NT = role ? MENC : HWIN;

    stage_wtile(role ? A.WHfe : A.WHsd, HID, u0t, Ws[usub], lane, bsub);

    const float* b1 = role ? A.fe_b1 : A.sd_b1;
    const float* b2 = role ? A.fe_b2 : A.sd_b2;
    float bias[4];
#pragma unroll
    for (int g = 0; g < 4; ++g) bias[g] = b1[g * HID + u] + b2[g * HID + u];

    float c[4];
#pragma unroll
    for (int r = 0; r < 4; ++r) {
        const int b = b0 + bsub * 16 + fq * 4 + r;
        c[r] = role ? 0.0f : A.SE_C[(size_t)b * HID + u];
    }
    __syncthreads();

    for (int t = 0; t < NT; ++t) {
        float xg[4][4];
#pragma unroll
        for (int r = 0; r < 4; ++r) {
            const int b = b0 + bsub * 16 + fq * 4 + r;
#pragma unroll
            for (int g = 0; g < 4; ++g)
                xg[r][g] = role ? A.xg_fe[((size_t)t * 512 + b) * 1024 + g * HID + u]
                                : A.xg_sd[((size_t)b * HWIN + t) * 1024 + g * HID + u];
        }
        if (t > 0) gbar_wait(A.bar + grp * HWIN + (t - 1), 4);
        f32x4 acc[4] = {};
        if (role == 0) {
            if (t == 0) cell_g(A.conc + ((size_t)15 * 512 + b0 + bsub * 16) * 512, 512,
                               Ws[usub], acc, lane);
            else        cell_g(A.SDB + ((size_t)(t - 1) * 512 + b0 + bsub * 16) * HID, HID,
                               Ws[usub], acc, lane);
        } else if (t > 0) {
            cell_g(A.FEB + ((size_t)(t - 1) * BATCH + b0 + bsub * 16) * HID, HID,
                   Ws[usub], acc, lane);
        }
#pragma unroll
        for (int r = 0; r < 4; ++r) {
            const int bl = bsub * 16 + fq * 4 + r;
            const int b = b0 + bl;
            float gv[4];
#pragma unroll
            for (int g = 0; g < 4; ++g)
                gv[g] = acc[g][r] + bias[g] + xg[r][g];
            const float cn = sigmf(gv[1]) * c[r] + sigmf(gv[0]) * tanhf(gv[2]);
            const float hn = sigmf(gv[3]) * tanhf(cn);
            c[r] = cn;
            hloc[bl][ul] = f2bf(hn);
            if (role == 1 && t == MENC - 1) {
                A.FEH[(size_t)b * HID + u] = hn;
                A.FE_C[(size_t)b * HID + u] = cn;
            }
        }
        __syncthreads();
        {
            const int row = tid >> 4, c8 = tid & 15;
            const unsigned long long v = *(const unsigned long long*)&hloc[row][c8 * 4];
            ushort* dst = role ? (A.FEB + ((size_t)t * BATCH + b0 + row) * 256 + ub + c8 * 4)
                               : (A.SDB + ((size_t)t * 512 + b0 + row) * 256 + ub + c8 * 4);
            st_u64(dst, v);
        }
        if (t != NT - 1) gbar_arrive(A.bar + grp * HWIN + t);
    }
}

// ---------------- persistent decoder: pd + fd + tail, 25 steps (R14 structure) ----------------
struct DecArgs {
    const ushort *WHpd;
    const ushort *WFDh;
    const ushort *peF;
    const float  *PE_C, *FE_C;
    const float  *xh2;
    const float  *pd_b1, *pd_b2, *pd_Wih;
    const float  *G, *c3, *dec_pos;
    ushort       *H1;        // [25][512][256]
    float        *DELTA;     // [25][512][3], pre-zeroed
    float        *out;       // [512][25][3]
    unsigned int *bar;       // 8 groups x 50
};

__global__ __launch_bounds__(512)
void dec_chain(DecArgs A)
{
    __shared__ ushort Wpd[2][64 * 256], Wfd[2][64 * 256];
    __shared__ ushort hloc[64][32];
    __shared__ float pred_lds[192];
    const int tid = threadIdx.x, lane = tid & 63, w = tid >> 6;
    const int btile = blockIdx.x & 7, usup = blockIdx.x >> 3;
    const int b0 = btile * 64, ub = usup * 32;
    const int usub = w & 1, bsub = w >> 1;
    const int u0t = ub + usub * 16;
    const int fr = lane & 15, fq = lane >> 4;
    const int u = u0t + fr;
    const int ul = usub * 16 + fr;
    unsigned int* bars = A.bar + btile * 2 * HWIN;

    stage_wtile(A.WHpd, HID, u0t, Wpd[usub], lane, bsub);
    stage_wtile(A.WFDh, 512, u0t, Wfd[usub], lane, bsub);

    float pdb[4], wxs[4][3], cf[4], c1[4], Gu[3];
#pragma unroll
    for (int g = 0; g < 4; ++g) {
        pdb[g] = A.pd_b1[g * HID + u] + A.pd_b2[g * HID + u];
        wxs[g][0] = A.pd_Wih[(g * HID + u) * 3 + 0];
        wxs[g][1] = A.pd_Wih[(g * HID + u) * 3 + 1];
        wxs[g][2] = A.pd_Wih[(g * HID + u) * 3 + 2];
    }
#pragma unroll
    for (int r = 0; r < 4; ++r) {
        const int b = b0 + bsub * 16 + fq * 4 + r;
        c1[r] = A.PE_C[(size_t)b * HID + u];
        cf[r] = A.FE_C[(size_t)b * HID + u];
    }
    Gu[0] = A.G[0 * HID + u]; Gu[1] = A.G[1 * HID + u]; Gu[2] = A.G[2 * HID + u];
    const float c3r = (tid < 192) ? A.c3[tid % 3] : 0.0f;
    if (tid < 192) pred_lds[tid] = A.dec_pos[(size_t)(b0 + tid / 3) * 3 + tid % 3];
    __syncthreads();

    for (int t = 0; t < HWIN; ++t) {
        // ---- phase A: pd MFMA (DELTA(t-1) wait deferred past it) ----
        f32x4 acc[4] = {};
        if (t == 0) cell_g(A.peF + (size_t)(b0 + bsub * 16) * 512, 512, Wpd[usub], acc, lane);
        else        cell_g(A.H1 + ((size_t)(t - 1) * BATCH + b0 + bsub * 16) * HID, HID,
                           Wpd[usub], acc, lane);
        if (t > 0) {
            gbar_wait(bars + 2 * (t - 1) + 1, 8);
            if (tid < 192) {
                pred_lds[tid] += A.DELTA[((size_t)(t - 1) * 512 + b0 + tid / 3) * 3 + tid % 3] + c3r;
                if (usup == 0)
                    A.out[((size_t)(b0 + tid / 3) * HWIN + (t - 1)) * 3 + tid % 3] = pred_lds[tid];
            }
            __syncthreads();
        }
#pragma unroll
        for (int r = 0; r < 4; ++r) {
            const int bl = bsub * 16 + fq * 4 + r;
            const float x0 = pred_lds[bl * 3 + 0];
            const float x1 = pred_lds[bl * 3 + 1];
            const float x2 = pred_lds[bl * 3 + 2];
            float gv[4];
#pragma unroll
            for (int g = 0; g < 4; ++g)
                gv[g] = acc[g][r] + pdb[g] + x0 * wxs[g][0] + x1 * wxs[g][1] + x2 * wxs[g][2];
            const float cn = sigmf(gv[1]) * c1[r] + sigmf(gv[0]) * tanhf(gv[2]);
            const float hn = sigmf(gv[3]) * tanhf(cn);
            c1[r] = cn;
            hloc[bl][ul] = f2bf(hn);
        }
        __syncthreads();
        {
            const int row = tid >> 3, c8 = tid & 7;
            const unsigned long long v = *(const unsigned long long*)&hloc[row][c8 * 4];
            st_u64(A.H1 + ((size_t)t * BATCH + b0 + row) * 256 + ub + c8 * 4, v);
        }
        gbar_arrive(bars + 2 * t);
        float xh[4][4];
#pragma unroll
        for (int r = 0; r < 4; ++r) {
            const int b = b0 + bsub * 16 + fq * 4 + r;
#pragma unroll
            for (int g = 0; g < 4; ++g)
                xh[r][g] = A.xh2[((size_t)t * 512 + b) * 1024 + g * HID + u];
        }
        gbar_wait(bars + 2 * t, 8);
        // ---- phase B: fd cell + delta partials ----
        {
            f32x4 accB[4] = {};
            cell_g(A.H1 + ((size_t)t * BATCH + b0 + bsub * 16) * HID, HID,
                   Wfd[usub], accB, lane);
#pragma unroll
            for (int r = 0; r < 4; ++r) {
                const int b = b0 + bsub * 16 + fq * 4 + r;
                float gv[4];
#pragma unroll
                for (int g = 0; g < 4; ++g)
                    gv[g] = accB[g][r] + xh[r][g];
                const float cn = sigmf(gv[1]) * cf[r] + sigmf(gv[0]) * tanhf(gv[2]);
                const float hn = sigmf(gv[3]) * tanhf(cn);
                float p0 = hn * Gu[0], p1 = hn * Gu[1], p2 = hn * Gu[2];
#pragma unroll
                for (int s = 1; s < 16; s <<= 1) {
                    p0 += __shfl_xor(p0, s);
                    p1 += __shfl_xor(p1, s);
                    p2 += __shfl_xor(p2, s);
                }
                if (fr == 0) {
                    float* d = A.DELTA + ((size_t)t * 512 + b) * 3;
                    atomicAdd(d + 0, p0); atomicAdd(d + 1, p1); atomicAdd(d + 2, p2);
                }
            }
        }
        gbar_arrive(bars + 2 * t + 1);
    }
    gbar_wait(bars + 2 * (HWIN - 1) + 1, 8);
    if (tid < 192) {
        pred_lds[tid] += A.DELTA[((size_t)(HWIN - 1) * 512 + b0 + tid / 3) * 3 + tid % 3] + c3r;
        if (usup == 0)
            A.out[((size_t)(b0 + tid / 3) * HWIN + (HWIN - 1)) * 3 + tid % 3] = pred_lds[tid];
    }
}

// ---------------- G = out_W @ f2_W, c3 = out_b + out_W @ f2_b ----------------
__global__ __launch_bounds__(256)
void precompute_G(const float* __restrict__ f2W, const float* __restrict__ f2b,
                  const float* __restrict__ outW, const float* __restrict__ outb,
                  float* __restrict__ G, float* __restrict__ c3)
{
    const int k = threadIdx.x;
    float g0 = 0.f, g1 = 0.f, g2 = 0.f;
    for (int n = 0; n < HID; ++n) {
        const float w = f2W[n * HID + k];
        g0 += outW[n] * w;
        g1 += outW[HID + n] * w;
        g2 += outW[2 * HID + n] * w;
    }
    G[k] = g0; G[HID + k] = g1; G[2 * HID + k] = g2;
    if (k < 3) {
        float s = outb[k];
        for (int n = 0; n < HID; ++n) s += outW[k * HID + n] * f2b[n];
        c3[k] = s;
    }
}

extern "C" void kernel_launch(void* const* d_in, const int* in_sizes, int n_in,
                              void* d_out, int out_size, void* d_ws, size_t ws_size,
                              hipStream_t stream)
{
    (void)in_sizes; (void)n_in; (void)out_size; (void)ws_size;
    const float* enc_pos = (const float*)d_in[0];
    const float* enc_sal = (const float*)d_in[1];
    const float* dec_pos = (const float*)d_in[2];
    const float* dec_sal = (const float*)d_in[3];
    const float *pe_Wih = (const float*)d_in[4],  *pe_Whh = (const float*)d_in[5],
                *pe_bih = (const float*)d_in[6],  *pe_bhh = (const float*)d_in[7];
    const float *se_Wih = (const float*)d_in[8],  *se_Whh = (const float*)d_in[9],
                *se_bih = (const float*)d_in[10], *se_bhh = (const float*)d_in[11];
    const float *fe_Wih = (const float*)d_in[12], *fe_Whh = (const float*)d_in[13],
                *fe_bih = (const float*)d_in[14], *fe_bhh = (const float*)d_in[15];
    const float *pd_Wih = (const float*)d_in[16], *pd_Whh = (const float*)d_in[17],
                *pd_bih = (const float*)d_in[18], *pd_bhh = (const float*)d_in[19];
    const float *sd_Wih = (const float*)d_in[20], *sd_Whh = (const float*)d_in[21],
                *sd_bih = (const float*)d_in[22], *sd_bhh = (const float*)d_in[23];
    const float *fd_Wih = (const float*)d_in[24], *fd_Whh = (const float*)d_in[25],
                *fd_bih = (const float*)d_in[26], *fd_bhh = (const float*)d_in[27];
    const float *f2_W = (const float*)d_in[28], *f2_b = (const float*)d_in[29];
    const float *out_W = (const float*)d_in[30], *out_b = (const float*)d_in[31];
    float* out = (float*)d_out;
    float* ws  = (float*)d_ws;

    size_t off = 0;
    float* XG_SE = ws + off; off += (size_t)8192 * 1024;
    float* XG_FE = ws + off; off += (size_t)8192 * 1024;
    float* BIG   = ws + off; off += (size_t)12800 * 1024;
    float* BIG2  = ws + off; off += (size_t)12800 * 1024;
    float* GBIAS = ws + off; off += (size_t)BATCH * 1024;
    float* PE_C  = ws + off; off += BH;
    float* SE_C  = ws + off; off += BH;
    float* FE_C  = ws + off; off += BH;
    float* FEH   = ws + off; off += BH;
    float* Gm    = ws + off; off += 1024;
    float* C3    = ws + off; off += 8;
    float* DELTA = ws + off; off += (size_t)HWIN * BATCH * 3 + 64;
    unsigned int* BAR = (unsigned int*)(ws + off); off += 1280;
    ushort* WSE  = (ushort*)(ws + off); off += ((size_t)1024 * 4096) / 2;
    ushort* WSD  = (ushort*)(ws + off); off += ((size_t)1024 * 4096) / 2;
    ushort* WFE  = (ushort*)(ws + off); off += ((size_t)1024 * 512) / 2;
    ushort* WFD  = (ushort*)(ws + off); off += ((size_t)1024 * 512) / 2;
    ushort* WHpe = (ushort*)(ws + off); off += ((size_t)1024 * 256) / 2;
    ushort* WHse = (ushort*)(ws + off); off += ((size_t)1024 * 256) / 2;
    ushort* WHfe = (ushort*)(ws + off); off += ((size_t)1024 * 256) / 2;
    ushort* WHsd = (ushort*)(ws + off); off += ((size_t)1024 * 256) / 2;
    ushort* WHpd = (ushort*)(ws + off); off += ((size_t)1024 * 256) / 2;
    ushort* CONC = (ushort*)(ws + off); off += ((size_t)MENC * 512 * 512) / 2;
    ushort* SDB  = (ushort*)(ws + off); off += ((size_t)HWIN * BH) / 2;
    ushort* FEB  = (ushort*)(ws + off); off += ((size_t)MENC * BH) / 2;
    ushort* H1   = (ushort*)(ws + off); off += ((size_t)HWIN * BH) / 2;

    // DELTA and BAR contiguous: one memset
    hipMemsetAsync(DELTA, 0, ((size_t)HWIN * BATCH * 3 + 64 + 1280) * 4, stream);

    auto mgemm = [&](const ushort* A, const ushort* W, float* C,
                     int M, int N, int K, int lda, int ldw, int ldc, const float* rb) {
        gemm_mfma_bt<<<dim3(N / 128, M / 128), 256, 0, stream>>>(A, W, C, M, N, K, lda, ldw, ldc, rb);
    };

    // ---- all 9 weight conversions in ONE launch ----
    {
        Cvt9 a;
        const float* srcs[9] = { se_Wih, sd_Wih, fe_Wih, fd_Wih, pe_Whh, se_Whh, fe_Whh, sd_Whh, pd_Whh };
        ushort*      dsts[9] = { WSE,    WSD,    WFE,    WFD,    WHpe,   WHse,   WHfe,   WHsd,   WHpd };
        const int    n4s[9]  = { 1024*4096/4, 1024*4096/4, 1024*512/4, 1024*512/4,
                                 1024*256/4, 1024*256/4, 1024*256/4, 1024*256/4, 1024*256/4 };
        int acc9 = 0;
        for (int i = 0; i < 9; ++i) { a.s[i] = srcs[i]; a.d[i] = dsts[i]; acc9 += n4s[i]; a.end[i] = acc9; }
        cvt_multi<<<(acc9 + 255) / 256, 256, 0, stream>>>(a);
    }
    precompute_G<<<1, 256, 0, stream>>>(f2_W, f2_b, out_W, out_b, Gm, C3);

    // ---- se + sd x-projections: merged, 256x128 tiles, 2 blocks/CU ----
    {
        GemmJob j0, j1;
        j0.A = enc_sal; j0.W = WSE; j0.C = XG_SE; j0.nwg = (8192 / 256) * 8;    // 256
        j1.A = dec_sal; j1.W = WSD; j1.C = BIG;   j1.nwg = (12800 / 256) * 8;   // 400
        gemm256f2<<<j0.nwg + j1.nwg, 512, 0, stream>>>(j0, j1);
    }

    // ---- persistent encoder (se + pe): 64 blocks x 1024 ----
    {
        EncArgs a;
        a.WHse = WHse; a.WHpe = WHpe; a.xg_se = XG_SE; a.enc_pos = enc_pos;
        a.se_b1 = se_bih; a.se_b2 = se_bhh; a.pe_b1 = pe_bih; a.pe_b2 = pe_bhh;
        a.pe_Wih = pe_Wih; a.conc = CONC; a.SE_C = SE_C; a.PE_C = PE_C;
        a.bar = BAR;
        enc_chain<<<64, 1024, 0, stream>>>(a);
    }

    // ---- fe x-proj (rows t,b) ----
    mgemm(CONC, WFE, XG_FE, 8192, 1024, 512, 512, 512, 1024, nullptr);

    // ---- persistent mid (sd + fe): 64 blocks x 1024 ----
    {
        MidArgs a;
        a.WHsd = WHsd; a.WHfe = WHfe; a.xg_sd = BIG; a.xg_fe = XG_FE;
        a.sd_b1 = sd_bih; a.sd_b2 = sd_bhh; a.fe_b1 = fe_bih; a.fe_b2 = fe_bhh;
        a.conc = CONC; a.SE_C = SE_C; a.SDB = SDB; a.FEB = FEB;
        a.FEH = FEH; a.FE_C = FE_C; a.bar = BAR + 256;
        mid_chain<<<64, 1024, 0, stream>>>(a);
    }

    // ---- fd precomputations ----
    gemm_tn<<<dim3(16, 8), 256, 0, stream>>>(FEH, fd_Whh, fd_bih, fd_bhh, GBIAS,
                                             BATCH, 1024, HID, HID, HID, 1024);
    mgemm(SDB, WFD, BIG2, 12800, 1024, HID, HID, 512, 1024, GBIAS);

    // ---- persistent decoder (pd + fd + tail): 64 blocks x 512 ----
    {
        DecArgs a;
        a.WHpd = WHpd; a.WFDh = WFD + 256;
        a.peF = CONC + ((size_t)15 * 512) * 512 + 256;
        a.PE_C = PE_C; a.FE_C = FE_C; a.xh2 = BIG2;
        a.pd_b1 = pd_bih; a.pd_b2 = pd_bhh; a.pd_Wih = pd_Wih;
        a.G = Gm; a.c3 = C3; a.dec_pos = dec_pos;
        a.H1 = H1; a.DELTA = DELTA; a.out = out; a.bar = BAR + 656;
        dec_chain<<<64, 512, 0, stream>>>(a);
    }
}

// Round 19
// 1172.989 us; speedup vs baseline: 1.0333x; 1.0333x over previous
//
#include <hip/hip_runtime.h>

#define HID 256
#define BATCH 512
#define MENC 16
#define HWIN 25
#define SALSZ 4096
#define BH (BATCH * HID)   // 131072

typedef __attribute__((ext_vector_type(8))) short bf16x8;
typedef __attribute__((ext_vector_type(4))) float f32x4;

__device__ __forceinline__ float sigmf(float x) { return 1.0f / (1.0f + __expf(-x)); }
__device__ __forceinline__ ushort f2bf(float f) {
    uint32_t u = __float_as_uint(f);
    return (ushort)((u + 0x7fffu + ((u >> 16) & 1u)) >> 16);   // RNE
}

#define GLOAD_LDS(gp, lp) \
    __builtin_amdgcn_global_load_lds((const __attribute__((address_space(1))) void*)(gp), \
                                     (__attribute__((address_space(3))) void*)(lp), 16, 0, 0)

// ---- wide write-through store for cross-block exchange (L3-visible) ----
__device__ __forceinline__ void st_u64(void* p, unsigned long long v) {
    __hip_atomic_store((unsigned long long*)p, v, __ATOMIC_RELAXED, __HIP_MEMORY_SCOPE_AGENT);
}

// ---- split fence-free barrier (R14-proven: atomicAdd counter, relaxed poll) ----
__device__ __forceinline__ void gbar_arrive(unsigned int* slot)
{
    __syncthreads();    // drains vmcnt: this block's stores are L3-acked
    if (threadIdx.x == 0) atomicAdd(slot, 1u);
}
__device__ __forceinline__ void gbar_wait(unsigned int* slot, unsigned int nblk)
{
    if (threadIdx.x == 0) {
        while (__hip_atomic_load(slot, __ATOMIC_RELAXED, __HIP_MEMORY_SCOPE_AGENT) < nblk)
            __builtin_amdgcn_s_sleep(1);
    }
    __syncthreads();
}

// ---- W tile staging for chains: [64][256] bf16, XOR-swizzled 16B units ----
__device__ __forceinline__ void stage_wtile(const ushort* Wsrc, int ldw, int u0,
                                            ushort* lds, int lane, int wq)
{
    const int sub = lane >> 5, uu = lane & 31;
#pragma unroll
    for (int i = 0; i < 8; ++i) {
        const int row = i * 8 + wq * 2 + sub;
        const int su  = uu ^ (row & 7);
        const int gr  = (row >> 4) * HID + u0 + (row & 15);
        GLOAD_LDS(Wsrc + (size_t)gr * ldw + su * 8, lds + i * 2048 + wq * 512);
    }
}

// ---- chain cell quarter: H from global, W from swizzled LDS; 32 MFMA/wave ----
__device__ __forceinline__ void cell_g(const ushort* hrow0, int ldh,
                                       const ushort* WsL, f32x4 acc[4], int lane)
{
    const int fr = lane & 15, fq = lane >> 4;
    const ushort* hrow = hrow0 + (size_t)fr * ldh;
#pragma unroll
    for (int ks = 0; ks < 8; ++ks) {
        const bf16x8 af = *(const bf16x8*)(hrow + ks * 32 + fq * 8);
#pragma unroll
        for (int g = 0; g < 4; ++g) {
            const int vr = g * 16 + fr;
            const bf16x8 bf = *(const bf16x8*)(WsL + vr * 256 + (((ks * 4 + fq)) ^ (vr & 7)) * 8);
            acc[g] = __builtin_amdgcn_mfma_f32_16x16x32_bf16(af, bf, acc[g], 0, 0, 0);
        }
    }
}

// ---------------- fp32 -> bf16, 9 weight segments in one launch ----------------
struct Cvt9 {
    const float* s[9];
    ushort*      d[9];
    int          end[9];
};
__global__ __launch_bounds__(256)
void cvt_multi(Cvt9 A)
{
    int i = blockIdx.x * 256 + threadIdx.x;
    if (i >= A.end[8]) return;
    int seg = 0, beg = 0;
#pragma unroll
    for (int k = 0; k < 8; ++k)
        if (i >= A.end[k]) { seg = k + 1; beg = A.end[k]; }
    const int j = i - beg;
    const float4 v = *(const float4*)(A.s[seg] + (size_t)j * 4);
    *(ushort4*)(A.d[seg] + (size_t)j * 4) = make_ushort4(f2bf(v.x), f2bf(v.y), f2bf(v.z), f2bf(v.w));
}

// ======== 256x256 8-wave GEMM with FUSED fp32->bf16 A-conversion (reg-staged A), ========
// ======== bf16 B via global_load_lds, counted-vmcnt pipeline + T1 XCD swizzle.  ========
__device__ __forceinline__ void loadA_f32(const float* Ag, int lda, int tid, float4 a[8])
{
    const int row_in = tid >> 3, ulin = tid & 7;
#pragma unroll
    for (int i = 0; i < 4; ++i) {
        const int row = i * 64 + row_in;
        const int su = (ulin ^ (row & 7)) * 8;
        a[2 * i + 0] = *(const float4*)(Ag + (size_t)row * lda + su);
        a[2 * i + 1] = *(const float4*)(Ag + (size_t)row * lda + su + 4);
    }
}
__device__ __forceinline__ void writeA_bf16(const float4 a[8], ushort* Al, int tid)
{
    const int row_in = tid >> 3, ulin = tid & 7;
#pragma unroll
    for (int i = 0; i < 4; ++i) {
        const int row = i * 64 + row_in;
        uint4 v;
        v.x = (uint)f2bf(a[2 * i].x) | ((uint)f2bf(a[2 * i].y) << 16);
        v.y = (uint)f2bf(a[2 * i].z) | ((uint)f2bf(a[2 * i].w) << 16);
        v.z = (uint)f2bf(a[2 * i + 1].x) | ((uint)f2bf(a[2 * i + 1].y) << 16);
        v.w = (uint)f2bf(a[2 * i + 1].z) | ((uint)f2bf(a[2 * i + 1].w) << 16);
        *(uint4*)(Al + row * 64 + ulin * 8) = v;
    }
}
__device__ __forceinline__ void stageB(const ushort* Bg, int ldw, ushort* Bl, int tid)
{
    const int row_in = tid >> 3, ulin = tid & 7;
#pragma unroll
    for (int i = 0; i < 4; ++i) {
        const int row = i * 64 + row_in;
        const int su = (ulin ^ (row & 7)) * 8;
        GLOAD_LDS(Bg + (size_t)row * ldw + su, Bl + row * 64 + ulin * 8);
    }
}

__global__ __launch_bounds__(512, 2)
void gemm256f(const float* __restrict__ A, const ushort* __restrict__ W,
              float* __restrict__ C, int M, int N, int K,
              int lda, int ldw, int ldc)
{
    __shared__ ushort As[2][256 * 64];
    __shared__ ushort Bs[2][256 * 64];
    const int tid = threadIdx.x, lane = tid & 63, wid = tid >> 6;

    const int gx = gridDim.x, nwg = gx * gridDim.y;
    int bid = blockIdx.y * gx + blockIdx.x;
    {
        const int q = nwg >> 3, r = nwg & 7;
        const int xcd = bid & 7, o = bid >> 3;
        bid = (xcd < r) ? xcd * (q + 1) + o : r * (q + 1) + (xcd - r) * q + o;
    }
    const int m0 = (bid / gx) * 256, n0 = (bid % gx) * 256;

    const int wr = wid >> 2, wc = wid & 3;
    const int fr = lane & 15, fq = lane >> 4;

    f32x4 acc[8][4] = {};
    const int nt = K / 64;
    const float*  Ab0 = A + (size_t)m0 * lda;
    const ushort* Bb0 = W + (size_t)n0 * ldw;

    float4 ra[8];
    loadA_f32(Ab0, lda, tid, ra);            // 8 loads (A0)
    stageB(Bb0, ldw, Bs[0], tid);            // 4 loads (B0)
    writeA_bf16(ra, As[0], tid);             // waits A0
    loadA_f32(Ab0 + 64, lda, tid, ra);       // 8 loads (A1, in flight)
    asm volatile("s_waitcnt vmcnt(8) lgkmcnt(0)" ::: "memory");  // B0 done
    __builtin_amdgcn_sched_barrier(0);
    __builtin_amdgcn_s_barrier();
    __builtin_amdgcn_sched_barrier(0);

    for (int t = 0; t < nt; ++t) {
        const int p = t & 1;
        const int t1 = (t + 1 < nt) ? t + 1 : nt - 1;
        const int t2 = (t + 2 < nt) ? t + 2 : nt - 1;
        stageB(Bb0 + t1 * 64, ldw, Bs[p ^ 1], tid);   // 4 loads
        writeA_bf16(ra, As[p ^ 1], tid);              // A(t+1) -> LDS (auto-wait)
        loadA_f32(Ab0 + t2 * 64, lda, tid, ra);       // 8 loads (A t+2)

        const ushort* Ab = As[p];
        const ushort* Bb = Bs[p];
#pragma unroll
        for (int ks = 0; ks < 2; ++ks) {
            bf16x8 bfr[4];
#pragma unroll
            for (int nf = 0; nf < 4; ++nf) {
                const int row = wc * 64 + nf * 16 + fr;
                bfr[nf] = *(const bf16x8*)(Bb + row * 64 + ((ks * 4 + fq) ^ (row & 7)) * 8);
            }
#pragma unroll
            for (int mh = 0; mh < 2; ++mh) {
                bf16x8 af[4];
#pragma unroll
                for (int i = 0; i < 4; ++i) {
                    const int row = wr * 128 + (mh * 4 + i) * 16 + fr;
                    af[i] = *(const bf16x8*)(Ab + row * 64 + ((ks * 4 + fq) ^ (row & 7)) * 8);
                }
                __builtin_amdgcn_s_setprio(1);
#pragma unroll
                for (int i = 0; i < 4; ++i)
#pragma unroll
                    for (int nf = 0; nf < 4; ++nf)
                        acc[mh * 4 + i][nf] = __builtin_amdgcn_mfma_f32_16x16x32_bf16(
                            af[i], bfr[nf], acc[mh * 4 + i][nf], 0, 0, 0);
                __builtin_amdgcn_s_setprio(0);
            }
        }
        if (t == nt - 1) break;
        asm volatile("s_waitcnt vmcnt(8) lgkmcnt(0)" ::: "memory");
        __builtin_amdgcn_sched_barrier(0);
        __builtin_amdgcn_s_barrier();
        __builtin_amdgcn_sched_barrier(0);
    }

    const int cl = lane & 15, ch = lane >> 4;
#pragma unroll
    for (int mf = 0; mf < 8; ++mf)
#pragma unroll
        for (int nf = 0; nf < 4; ++nf)
#pragma unroll
            for (int r = 0; r < 4; ++r)
                C[(size_t)(m0 + wr * 128 + mf * 16 + ch * 4 + r) * ldc
                  + n0 + wc * 64 + nf * 16 + cl] = acc[mf][nf][r];
}

// ---------------- 128x128 bf16 MFMA GEMM (small shapes) ----------------
__global__ __launch_bounds__(256)
void gemm_mfma_bt(const ushort* __restrict__ A, const ushort* __restrict__ W,
                  float* __restrict__ C, int M, int N, int K,
                  int lda, int ldw, int ldc, const float* __restrict__ rbias)
{
    __shared__ ushort As[128 * 32];
    __shared__ ushort Bs[128 * 32];
    const int t    = threadIdx.x;
    const int lane = t & 63, wid = t >> 6;
    const int m0 = blockIdx.y * 128, n0 = blockIdx.x * 128;
    const int wr = wid >> 1, wc = wid & 1;

    f32x4 acc[4][4] = {};

    const int sr = wid * 16 + (lane >> 2);
    const int su = ((lane & 3) ^ ((lane >> 3) & 3)) * 8;
    const ushort* Ag = A + (size_t)(m0 + sr) * lda + su;
    const ushort* Wg = W + (size_t)(n0 + sr) * ldw + su;
    ushort* Al = As + wid * 512;
    ushort* Bl = Bs + wid * 512;

    const int fr = lane & 15;
    const int fq = lane >> 4;
    const int sw = (fr >> 1) & 3;

    for (int k0 = 0; k0 < K; k0 += 32) {
        GLOAD_LDS(Ag,                    Al);
        GLOAD_LDS(Ag + (size_t)64 * lda, Al + 2048);
        GLOAD_LDS(Wg,                    Bl);
        GLOAD_LDS(Wg + (size_t)64 * ldw, Bl + 2048);
        Ag += 32; Wg += 32;
        __syncthreads();

        bf16x8 af[4], bfr[4];
#pragma unroll
        for (int m = 0; m < 4; ++m)
            af[m] = *(const bf16x8*)(As + (wr * 64 + m * 16 + fr) * 32 + (fq ^ sw) * 8);
#pragma unroll
        for (int n = 0; n < 4; ++n)
            bfr[n] = *(const bf16x8*)(Bs + (wc * 64 + n * 16 + fr) * 32 + (fq ^ sw) * 8);
#pragma unroll
        for (int m = 0; m < 4; ++m)
#pragma unroll
            for (int n = 0; n < 4; ++n)
                acc[m][n] = __builtin_amdgcn_mfma_f32_16x16x32_bf16(af[m], bfr[n], acc[m][n], 0, 0, 0);
        __syncthreads();
    }

    const int cl = lane & 15, ch = lane >> 4;
#pragma unroll
    for (int m = 0; m < 4; ++m)
#pragma unroll
        for (int n = 0; n < 4; ++n)
#pragma unroll
            for (int r = 0; r < 4; ++r) {
                const int mm = m0 + wr * 64 + m * 16 + ch * 4 + r;
                const int nn = n0 + wc * 64 + n * 16 + cl;
                float v = acc[m][n][r];
                if (rbias) v += rbias[(size_t)(mm & 511) * ldc + nn];
                C[(size_t)mm * ldc + nn] = v;
            }
}

// ---------------- fp32 tiled GEMM (GBIAS one-off) ----------------
__global__ __launch_bounds__(256)
void gemm_tn(const float* __restrict__ A, const float* __restrict__ W,
             const float* __restrict__ b1, const float* __restrict__ b2,
             float* __restrict__ C,
             int M, int N, int K, int lda, int ldw, int ldc)
{
    __shared__ float AsT[16][68];
    __shared__ float WsT[16][68];
    const int t  = threadIdx.x;
    const int tx = t & 15, ty = t >> 4;
    const int m0 = blockIdx.y * 64, n0 = blockIdx.x * 64;
    const int lr = t >> 2;
    const int c4 = t & 3;

    float acc[4][4];
#pragma unroll
    for (int i = 0; i < 4; ++i)
#pragma unroll
        for (int j = 0; j < 4; ++j) acc[i][j] = 0.0f;

    for (int k0 = 0; k0 < K; k0 += 16) {
        float a[4], w[4];
        const int kb = k0 + c4 * 4;
#pragma unroll
        for (int k = 0; k < 4; ++k) {
            a[k] = (kb + k < K) ? A[(size_t)(m0 + lr) * lda + kb + k] : 0.0f;
            w[k] = (kb + k < K) ? W[(size_t)(n0 + lr) * ldw + kb + k] : 0.0f;
        }
        __syncthreads();
#pragma unroll
        for (int k = 0; k < 4; ++k) {
            AsT[c4 * 4 + k][lr] = a[k];
            WsT[c4 * 4 + k][lr] = w[k];
        }
        __syncthreads();
#pragma unroll
        for (int kk = 0; kk < 16; ++kk) {
            const float4 av = *(const float4*)&AsT[kk][ty * 4];
            const float4 wv = *(const float4*)&WsT[kk][tx * 4];
            acc[0][0] += av.x * wv.x; acc[0][1] += av.x * wv.y; acc[0][2] += av.x * wv.z; acc[0][3] += av.x * wv.w;
            acc[1][0] += av.y * wv.x; acc[1][1] += av.y * wv.y; acc[1][2] += av.y * wv.z; acc[1][3] += av.y * wv.w;
            acc[2][0] += av.z * wv.x; acc[2][1] += av.z * wv.y; acc[2][2] += av.z * wv.z; acc[2][3] += av.z * wv.w;
            acc[3][0] += av.w * wv.x; acc[3][1] += av.w * wv.y; acc[3][2] += av.w * wv.z; acc[3][3] += av.w * wv.w;
        }
    }

#pragma unroll
    for (int i = 0; i < 4; ++i) {
        const int m = m0 + ty * 4 + i;
#pragma unroll
        for (int j = 0; j < 4; ++j) {
            const int n = n0 + tx * 4 + j;
            float v = acc[i][j];
            if (b1) v += b1[n];
            if (b2) v += b2[n];
            C[(size_t)m * ldc + n] = v;
        }
    }
}

// ---------------- persistent encoder: se + pe chains, 16 steps ----------------
struct EncArgs {
    const ushort *WHse, *WHpe;
    const float  *xg_se;
    const float  *enc_pos;
    const float  *se_b1, *se_b2, *pe_b1, *pe_b2;
    const float  *pe_Wih;
    ushort       *conc;      // [16][512][512]
    float        *SE_C, *PE_C;
    unsigned int *bar;
};

__global__ __launch_bounds__(1024)
void enc_chain(EncArgs A)
{
    __shared__ ushort Ws[4][64 * 256];
    __shared__ ushort hloc[64][64];
    const int tid = threadIdx.x, lane = tid & 63, w = tid >> 6;
    const int role  = blockIdx.x >> 5;
    const int rem   = blockIdx.x & 31;
    const int btile = rem & 7, usup = rem >> 3;
    const int b0 = btile * 64, ub = usup * 64;
    const int usub = w & 3, bsub = w >> 2;
    const int u0t = ub + usub * 16;
    const int grp = role * 8 + btile;
    const int fr = lane & 15, fq = lane >> 4;
    const int u = u0t + fr;
    const int ul = usub * 16 + fr;
    const int coff = role ? 256 : 0;

    stage_wtile(role ? A.WHpe : A.WHse, HID, u0t, Ws[usub], lane, bsub);

    const float* b1 = role ? A.pe_b1 : A.se_b1;
    const float* b2 = role ? A.pe_b2 : A.se_b2;
    float bias[4], wxs[4][3];
#pragma unroll
    for (int g = 0; g < 4; ++g) {
        bias[g] = b1[g * HID + u] + b2[g * HID + u];
        wxs[g][0] = wxs[g][1] = wxs[g][2] = 0.0f;
        if (role) {
            wxs[g][0] = A.pe_Wih[(g * HID + u) * 3 + 0];
            wxs[g][1] = A.pe_Wih[(g * HID + u) * 3 + 1];
            wxs[g][2] = A.pe_Wih[(g * HID + u) * 3 + 2];
        }
    }
    float c[4] = {0.f, 0.f, 0.f, 0.f};
    __syncthreads();

    for (int t = 0; t < MENC; ++t) {
        float xg[4][4];
#pragma unroll
        for (int r = 0; r < 4; ++r) {
            const int b = b0 + bsub * 16 + fq * 4 + r;
            if (role) {
                const float* xp = A.enc_pos + ((size_t)b * MENC + t) * 3;
                xg[r][0] = xp[0]; xg[r][1] = xp[1]; xg[r][2] = xp[2]; xg[r][3] = 0.f;
            } else {
#pragma unroll
                for (int g = 0; g < 4; ++g)
                    xg[r][g] = A.xg_se[((size_t)b * MENC + t) * 1024 + g * HID + u];
            }
        }
        if (t > 0) gbar_wait(A.bar + grp * MENC + (t - 1), 4);
        f32x4 acc[4] = {};
        if (t > 0)
            cell_g(A.conc + ((size_t)(t - 1) * 512 + b0 + bsub * 16) * 512 + coff, 512,
                   Ws[usub], acc, lane);
#pragma unroll
        for (int r = 0; r < 4; ++r) {
            const int bl = bsub * 16 + fq * 4 + r;
            const int b = b0 + bl;
            float gv[4];
#pragma unroll
            for (int g = 0; g < 4; ++g) {
                float v = acc[g][r] + bias[g];
                if (role) v += xg[r][0] * wxs[g][0] + xg[r][1] * wxs[g][1] + xg[r][2] * wxs[g][2];
                else      v += xg[r][g];
                gv[g] = v;
            }
            const float cn = sigmf(gv[1]) * c[r] + sigmf(gv[0]) * tanhf(gv[2]);
            const float hn = sigmf(gv[3]) * tanhf(cn);
            c[r] = cn;
            hloc[bl][ul] = f2bf(hn);
            if (t == MENC - 1) (role ? A.PE_C : A.SE_C)[(size_t)b * HID + u] = cn;
        }
        __syncthreads();
        {
            const int row = tid >> 4, c8 = tid & 15;
            const unsigned long long v = *(const unsigned long long*)&hloc[row][c8 * 4];
            st_u64(A.conc + ((size_t)t * 512 + b0 + row) * 512 + coff + ub + c8 * 4, v);
        }
        if (t != MENC - 1) gbar_arrive(A.bar + grp * MENC + t);
    }
}

// ---------------- persistent mid: sd (25) + fe (16) ----------------
struct MidArgs {
    const ushort *WHsd, *WHfe;
    const float  *xg_sd;
    const float  *xg_fe;
    const float  *sd_b1, *sd_b2, *fe_b1, *fe_b2;
    const ushort *conc;
    const float  *SE_C;
    ushort       *SDB;       // [25][512][256]
    ushort       *FEB;       // [16][512][256]
    float        *FEH, *FE_C;
    unsigned int *bar;
};

__global__ __launch_bounds__(1024)
void mid_chain(MidArgs A)
{
    __shared__ ushort Ws[4][64 * 256];
    __shared__ ushort hloc[64][64];
    const int tid = threadIdx.x, lane = tid & 63, w = tid >> 6;
    const int role  = blockIdx.x >> 5;
    const int rem   = blockIdx.x & 31;
    const int btile = rem & 7, usup = rem >> 3;
    const int b0 = btile * 64, ub = usup * 64;
    const int usub = w & 3, bsub = w >> 2;
    const int u0t = ub + usub * 16;
    const int grp = role * 8 + btile;
    const int fr = lane & 15, fq = lane >> 4;
    const int u = u0t + fr;
    const int ul = usub * 16 + fr;
    const int NT = role ? MENC : HWIN;

    stage_wtile(role ? A.WHfe : A.WHsd, HID, u0t, Ws[usub], lane, bsub);

    const float* b1 = role ? A.fe_b1 : A.sd_b1;
    const float* b2 = role ? A.fe_b2 : A.sd_b2;
    float bias[4];
#pragma unroll
    for (int g = 0; g < 4; ++g) bias[g] = b1[g * HID + u] + b2[g * HID + u];

    float c[4];
#pragma unroll
    for (int r = 0; r < 4; ++r) {
        const int b = b0 + bsub * 16 + fq * 4 + r;
        c[r] = role ? 0.0f : A.SE_C[(size_t)b * HID + u];
    }
    __syncthreads();

    for (int t = 0; t < NT; ++t) {
        float xg[4][4];
#pragma unroll
        for (int r = 0; r < 4; ++r) {
            const int b = b0 + bsub * 16 + fq * 4 + r;
#pragma unroll
            for (int g = 0; g < 4; ++g)
                xg[r][g] = role ? A.xg_fe[((size_t)t * 512 + b) * 1024 + g * HID + u]
                                : A.xg_sd[((size_t)b * HWIN + t) * 1024 + g * HID + u];
        }
        if (t > 0) gbar_wait(A.bar + grp * HWIN + (t - 1), 4);
        f32x4 acc[4] = {};
        if (role == 0) {
            if (t == 0) cell_g(A.conc + ((size_t)15 * 512 + b0 + bsub * 16) * 512, 512,
                               Ws[usub], acc, lane);
            else        cell_g(A.SDB + ((size_t)(t - 1) * 512 + b0 + bsub * 16) * HID, HID,
                               Ws[usub], acc, lane);
        } else if (t > 0) {
            cell_g(A.FEB + ((size_t)(t - 1) * BATCH + b0 + bsub * 16) * HID, HID,
                   Ws[usub], acc, lane);
        }
#pragma unroll
        for (int r = 0; r < 4; ++r) {
            const int bl = bsub * 16 + fq * 4 + r;
            const int b = b0 + bl;
            float gv[4];
#pragma unroll
            for (int g = 0; g < 4; ++g)
                gv[g] = acc[g][r] + bias[g] + xg[r][g];
            const float cn = sigmf(gv[1]) * c[r] + sigmf(gv[0]) * tanhf(gv[2]);
            const float hn = sigmf(gv[3]) * tanhf(cn);
            c[r] = cn;
            hloc[bl][ul] = f2bf(hn);
            if (role == 1 && t == MENC - 1) {
                A.FEH[(size_t)b * HID + u] = hn;
                A.FE_C[(size_t)b * HID + u] = cn;
            }
        }
        __syncthreads();
        {
            const int row = tid >> 4, c8 = tid & 15;
            const unsigned long long v = *(const unsigned long long*)&hloc[row][c8 * 4];
            ushort* dst = role ? (A.FEB + ((size_t)t * BATCH + b0 + row) * 256 + ub + c8 * 4)
                               : (A.SDB + ((size_t)t * 512 + b0 + row) * 256 + ub + c8 * 4);
            st_u64(dst, v);
        }
        if (t != NT - 1) gbar_arrive(A.bar + grp * HWIN + t);
    }
}

// ---------------- persistent decoder: pd + fd + tail, 25 steps ----------------
struct DecArgs {
    const ushort *WHpd;
    const ushort *WFDh;
    const ushort *peF;
    const float  *PE_C, *FE_C;
    const float  *xh2;
    const float  *pd_b1, *pd_b2, *pd_Wih;
    const float  *G, *c3, *dec_pos;
    ushort       *H1;        // [25][512][256]
    float        *DELTA;     // [25][512][3], pre-zeroed
    float        *out;       // [512][25][3]
    unsigned int *bar;       // 8 groups x 50
};

__global__ __launch_bounds__(512)
void dec_chain(DecArgs A)
{
    __shared__ ushort Wpd[2][64 * 256], Wfd[2][64 * 256];
    __shared__ ushort hloc[64][32];
    __shared__ float pred_lds[192];
    const int tid = threadIdx.x, lane = tid & 63, w = tid >> 6;
    const int btile = blockIdx.x & 7, usup = blockIdx.x >> 3;
    const int b0 = btile * 64, ub = usup * 32;
    const int usub = w & 1, bsub = w >> 1;
    const int u0t = ub + usub * 16;
    const int fr = lane & 15, fq = lane >> 4;
    const int u = u0t + fr;
    const int ul = usub * 16 + fr;
    unsigned int* bars = A.bar + btile * 2 * HWIN;

    stage_wtile(A.WHpd, HID, u0t, Wpd[usub], lane, bsub);
    stage_wtile(A.WFDh, 512, u0t, Wfd[usub], lane, bsub);

    float pdb[4], wxs[4][3], cf[4], c1[4], Gu[3];
#pragma unroll
    for (int g = 0; g < 4; ++g) {
        pdb[g] = A.pd_b1[g * HID + u] + A.pd_b2[g * HID + u];
        wxs[g][0] = A.pd_Wih[(g * HID + u) * 3 + 0];
        wxs[g][1] = A.pd_Wih[(g * HID + u) * 3 + 1];
        wxs[g][2] = A.pd_Wih[(g * HID + u) * 3 + 2];
    }
#pragma unroll
    for (int r = 0; r < 4; ++r) {
        const int b = b0 + bsub * 16 + fq * 4 + r;
        c1[r] = A.PE_C[(size_t)b * HID + u];
        cf[r] = A.FE_C[(size_t)b * HID + u];
    }
    Gu[0] = A.G[0 * HID + u]; Gu[1] = A.G[1 * HID + u]; Gu[2] = A.G[2 * HID + u];
    const float c3r = (tid < 192) ? A.c3[tid % 3] : 0.0f;
    if (tid < 192) pred_lds[tid] = A.dec_pos[(size_t)(b0 + tid / 3) * 3 + tid % 3];
    __syncthreads();

    for (int t = 0; t < HWIN; ++t) {
        f32x4 acc[4] = {};
        if (t == 0) cell_g(A.peF + (size_t)(b0 + bsub * 16) * 512, 512, Wpd[usub], acc, lane);
        else        cell_g(A.H1 + ((size_t)(t - 1) * BATCH + b0 + bsub * 16) * HID, HID,
                           Wpd[usub], acc, lane);
        if (t > 0) {
            gbar_wait(bars + 2 * (t - 1) + 1, 8);
            if (tid < 192) {
                pred_lds[tid] += A.DELTA[((size_t)(t - 1) * 512 + b0 + tid / 3) * 3 + tid % 3] + c3r;
                if (usup == 0)
                    A.out[((size_t)(b0 + tid / 3) * HWIN + (t - 1)) * 3 + tid % 3] = pred_lds[tid];
            }
            __syncthreads();
        }
#pragma unroll
        for (int r = 0; r < 4; ++r) {
            const int bl = bsub * 16 + fq * 4 + r;
            const float x0 = pred_lds[bl * 3 + 0];
            const float x1 = pred_lds[bl * 3 + 1];
            const float x2 = pred_lds[bl * 3 + 2];
            float gv[4];
#pragma unroll
            for (int g = 0; g < 4; ++g)
                gv[g] = acc[g][r] + pdb[g] + x0 * wxs[g][0] + x1 * wxs[g][1] + x2 * wxs[g][2];
            const float cn = sigmf(gv[1]) * c1[r] + sigmf(gv[0]) * tanhf(gv[2]);
            const float hn = sigmf(gv[3]) * tanhf(cn);
            c1[r] = cn;
            hloc[bl][ul] = f2bf(hn);
        }
        __syncthreads();
        {
            const int row = tid >> 3, c8 = tid & 7;
            const unsigned long long v = *(const unsigned long long*)&hloc[row][c8 * 4];
            st_u64(A.H1 + ((size_t)t * BATCH + b0 + row) * 256 + ub + c8 * 4, v);
        }
        gbar_arrive(bars + 2 * t);
        float xh[4][4];
#pragma unroll
        for (int r = 0; r < 4; ++r) {
            const int b = b0 + bsub * 16 + fq * 4 + r;
#pragma unroll
            for (int g = 0; g < 4; ++g)
                xh[r][g] = A.xh2[((size_t)t * 512 + b) * 1024 + g * HID + u];
        }
        gbar_wait(bars + 2 * t, 8);
        {
            f32x4 accB[4] = {};
            cell_g(A.H1 + ((size_t)t * BATCH + b0 + bsub * 16) * HID, HID,
                   Wfd[usub], accB, lane);
#pragma unroll
            for (int r = 0; r < 4; ++r) {
                const int b = b0 + bsub * 16 + fq * 4 + r;
                float gv[4];
#pragma unroll
                for (int g = 0; g < 4; ++g)
                    gv[g] = accB[g][r] + xh[r][g];
                const float cn = sigmf(gv[1]) * cf[r] + sigmf(gv[0]) * tanhf(gv[2]);
                const float hn = sigmf(gv[3]) * tanhf(cn);
                float p0 = hn * Gu[0], p1 = hn * Gu[1], p2 = hn * Gu[2];
#pragma unroll
                for (int s = 1; s < 16; s <<= 1) {
                    p0 += __shfl_xor(p0, s);
                    p1 += __shfl_xor(p1, s);
                    p2 += __shfl_xor(p2, s);
                }
                if (fr == 0) {
                    float* d = A.DELTA + ((size_t)t * 512 + b) * 3;
                    atomicAdd(d + 0, p0); atomicAdd(d + 1, p1); atomicAdd(d + 2, p2);
                }
            }
        }
        gbar_arrive(bars + 2 * t + 1);
    }
    gbar_wait(bars + 2 * (HWIN - 1) + 1, 8);
    if (tid < 192) {
        pred_lds[tid] += A.DELTA[((size_t)(HWIN - 1) * 512 + b0 + tid / 3) * 3 + tid % 3] + c3r;
        if (usup == 0)
            A.out[((size_t)(b0 + tid / 3) * HWIN + (HWIN - 1)) * 3 + tid % 3] = pred_lds[tid];
    }
}

// ---------------- G = out_W @ f2_W, c3 = out_b + out_W @ f2_b ----------------
__global__ __launch_bounds__(256)
void precompute_G(const float* __restrict__ f2W, const float* __restrict__ f2b,
                  const float* __restrict__ outW, const float* __restrict__ outb,
                  float* __restrict__ G, float* __restrict__ c3)
{
    const int k = threadIdx.x;
    float g0 = 0.f, g1 = 0.f, g2 = 0.f;
    for (int n = 0; n < HID; ++n) {
        const float w = f2W[n * HID + k];
        g0 += outW[n] * w;
        g1 += outW[HID + n] * w;
        g2 += outW[2 * HID + n] * w;
    }
    G[k] = g0; G[HID + k] = g1; G[2 * HID + k] = g2;
    if (k < 3) {
        float s = outb[k];
        for (int n = 0; n < HID; ++n) s += outW[k * HID + n] * f2b[n];
        c3[k] = s;
    }
}

extern "C" void kernel_launch(void* const* d_in, const int* in_sizes, int n_in,
                              void* d_out, int out_size, void* d_ws, size_t ws_size,
                              hipStream_t stream)
{
    (void)in_sizes; (void)n_in; (void)out_size; (void)ws_size;
    const float* enc_pos = (const float*)d_in[0];
    const float* enc_sal = (const float*)d_in[1];
    const float* dec_pos = (const float*)d_in[2];
    const float* dec_sal = (const float*)d_in[3];
    const float *pe_Wih = (const float*)d_in[4],  *pe_Whh = (const float*)d_in[5],
                *pe_bih = (const float*)d_in[6],  *pe_bhh = (const float*)d_in[7];
    const float *se_Wih = (const float*)d_in[8],  *se_Whh = (const float*)d_in[9],
                *se_bih = (const float*)d_in[10], *se_bhh = (const float*)d_in[11];
    const float *fe_Wih = (const float*)d_in[12], *fe_Whh = (const float*)d_in[13],
                *fe_bih = (const float*)d_in[14], *fe_bhh = (const float*)d_in[15];
    const float *pd_Wih = (const float*)d_in[16], *pd_Whh = (const float*)d_in[17],
                *pd_bih = (const float*)d_in[18], *pd_bhh = (const float*)d_in[19];
    const float *sd_Wih = (const float*)d_in[20], *sd_Whh = (const float*)d_in[21],
                *sd_bih = (const float*)d_in[22], *sd_bhh = (const float*)d_in[23];
    const float *fd_Wih = (const float*)d_in[24], *fd_Whh = (const float*)d_in[25],
                *fd_bih = (const float*)d_in[26], *fd_bhh = (const float*)d_in[27];
    const float *f2_W = (const float*)d_in[28], *f2_b = (const float*)d_in[29];
    const float *out_W = (const float*)d_in[30], *out_b = (const float*)d_in[31];
    float* out = (float*)d_out;
    float* ws  = (float*)d_ws;

    size_t off = 0;
    float* XG_SE = ws + off; off += (size_t)8192 * 1024;
    float* XG_FE = ws + off; off += (size_t)8192 * 1024;
    float* BIG   = ws + off; off += (size_t)12800 * 1024;
    float* BIG2  = ws + off; off += (size_t)12800 * 1024;
    float* GBIAS = ws + off; off += (size_t)BATCH * 1024;
    float* PE_C  = ws + off; off += BH;
    float* SE_C  = ws + off; off += BH;
    float* FE_C  = ws + off; off += BH;
    float* FEH   = ws + off; off += BH;
    float* Gm    = ws + off; off += 1024;
    float* C3    = ws + off; off += 8;
    float* DELTA = ws + off; off += (size_t)HWIN * BATCH * 3 + 64;
    unsigned int* BAR = (unsigned int*)(ws + off); off += 1280;
    ushort* WSE  = (ushort*)(ws + off); off += ((size_t)1024 * 4096) / 2;
    ushort* WSD  = (ushort*)(ws + off); off += ((size_t)1024 * 4096) / 2;
    ushort* WFE  = (ushort*)(ws + off); off += ((size_t)1024 * 512) / 2;
    ushort* WFD  = (ushort*)(ws + off); off += ((size_t)1024 * 512) / 2;
    ushort* WHpe = (ushort*)(ws + off); off += ((size_t)1024 * 256) / 2;
    ushort* WHse = (ushort*)(ws + off); off += ((size_t)1024 * 256) / 2;
    ushort* WHfe = (ushort*)(ws + off); off += ((size_t)1024 * 256) / 2;
    ushort* WHsd = (ushort*)(ws + off); off += ((size_t)1024 * 256) / 2;
    ushort* WHpd = (ushort*)(ws + off); off += ((size_t)1024 * 256) / 2;
    ushort* CONC = (ushort*)(ws + off); off += ((size_t)MENC * 512 * 512) / 2;
    ushort* SDB  = (ushort*)(ws + off); off += ((size_t)HWIN * BH) / 2;
    ushort* FEB  = (ushort*)(ws + off); off += ((size_t)MENC * BH) / 2;
    ushort* H1   = (ushort*)(ws + off); off += ((size_t)HWIN * BH) / 2;

    // DELTA and BAR contiguous: one memset
    hipMemsetAsync(DELTA, 0, ((size_t)HWIN * BATCH * 3 + 64 + 1280) * 4, stream);

    auto mgemm = [&](const ushort* A, const ushort* W, float* C,
                     int M, int N, int K, int lda, int ldw, int ldc, const float* rb) {
        gemm_mfma_bt<<<dim3(N / 128, M / 128), 256, 0, stream>>>(A, W, C, M, N, K, lda, ldw, ldc, rb);
    };
    auto mgemm256f = [&](const float* A, const ushort* W, float* C,
                         int M, int N, int K, int lda, int ldw, int ldc) {
        gemm256f<<<dim3(N / 256, M / 256), 512, 0, stream>>>(A, W, C, M, N, K, lda, ldw, ldc);
    };

    // ---- all 9 weight conversions in ONE launch ----
    {
        Cvt9 a;
        const float* srcs[9] = { se_Wih, sd_Wih, fe_Wih, fd_Wih, pe_Whh, se_Whh, fe_Whh, sd_Whh, pd_Whh };
        ushort*      dsts[9] = { WSE,    WSD,    WFE,    WFD,    WHpe,   WHse,   WHfe,   WHsd,   WHpd };
        const int    n4s[9]  = { 1024*4096/4, 1024*4096/4, 1024*512/4, 1024*512/4,
                                 1024*256/4, 1024*256/4, 1024*256/4, 1024*256/4, 1024*256/4 };
        int acc9 = 0;
        for (int i = 0; i < 9; ++i) { a.s[i] = srcs[i]; a.d[i] = dsts[i]; acc9 += n4s[i]; a.end[i] = acc9; }
        cvt_multi<<<(acc9 + 255) / 256, 256, 0, stream>>>(a);
    }
    precompute_G<<<1, 256, 0, stream>>>(f2_W, f2_b, out_W, out_b, Gm, C3);

    // ---- se x-proj; sd x-proj — fused fp32->bf16 A staging ----
    mgemm256f(enc_sal, WSE, XG_SE, 8192, 1024, SALSZ, SALSZ, SALSZ, 1024);
    mgemm256f(dec_sal, WSD, BIG, 12800, 1024, SALSZ, SALSZ, SALSZ, 1024);

    // ---- persistent encoder (se + pe): 64 blocks x 1024 ----
    {
        EncArgs a;
        a.WHse = WHse; a.WHpe = WHpe; a.xg_se = XG_SE; a.enc_pos = enc_pos;
        a.se_b1 = se_bih; a.se_b2 = se_bhh; a.pe_b1 = pe_bih; a.pe_b2 = pe_bhh;
        a.pe_Wih = pe_Wih; a.conc = CONC; a.SE_C = SE_C; a.PE_C = PE_C;
        a.bar = BAR;
        enc_chain<<<64, 1024, 0, stream>>>(a);
    }

    // ---- fe x-proj (rows t,b) ----
    mgemm(CONC, WFE, XG_FE, 8192, 1024, 512, 512, 512, 1024, nullptr);

    // ---- persistent mid (sd + fe): 64 blocks x 1024 ----
    {
        MidArgs a;
        a.WHsd = WHsd; a.WHfe = WHfe; a.xg_sd = BIG; a.xg_fe = XG_FE;
        a.sd_b1 = sd_bih; a.sd_b2 = sd_bhh; a.fe_b1 = fe_bih; a.fe_b2 = fe_bhh;
        a.conc = CONC; a.SE_C = SE_C; a.SDB = SDB; a.FEB = FEB;
        a.FEH = FEH; a.FE_C = FE_C; a.bar = BAR + 256;
        mid_chain<<<64, 1024, 0, stream>>>(a);
    }

    // ---- fd precomputations ----
    gemm_tn<<<dim3(16, 8), 256, 0, stream>>>(FEH, fd_Whh, fd_bih, fd_bhh, GBIAS,
                                             BATCH, 1024, HID, HID, HID, 1024);
    mgemm(SDB, WFD, BIG2, 12800, 1024, HID, HID, 512, 1024, GBIAS);

    // ---- persistent decoder (pd + fd + tail): 64 blocks x 512 ----
    {
        DecArgs a;
        a.WHpd = WHpd; a.WFDh = WFD + 256;
        a.peF = CONC + ((size_t)15 * 512) * 512 + 256;
        a.PE_C = PE_C; a.FE_C = FE_C; a.xh2 = BIG2;
        a.pd_b1 = pd_bih; a.pd_b2 = pd_bhh; a.pd_Wih = pd_Wih;
        a.G = Gm; a.c3 = C3; a.dec_pos = dec_pos;
        a.H1 = H1; a.DELTA = DELTA; a.out = out; a.bar = BAR + 656;
        dec_chain<<<64, 512, 0, stream>>>(a);
    }
}

// Round 20
// 1144.970 us; speedup vs baseline: 1.0585x; 1.0245x over previous
//
#include <hip/hip_runtime.h>

#define HID 256
#define BATCH 512
#define MENC 16
#define HWIN 25
#define SALSZ 4096
#define BH (BATCH * HID)   // 131072

typedef __attribute__((ext_vector_type(8))) short bf16x8;
typedef __attribute__((ext_vector_type(4))) float f32x4;

__device__ __forceinline__ float sigmf(float x) { return 1.0f / (1.0f + __expf(-x)); }
__device__ __forceinline__ ushort f2bf(float f) {
    uint32_t u = __float_as_uint(f);
    return (ushort)((u + 0x7fffu + ((u >> 16) & 1u)) >> 16);   // RNE
}

#define GLOAD_LDS(gp, lp) \
    __builtin_amdgcn_global_load_lds((const __attribute__((address_space(1))) void*)(gp), \
                                     (__attribute__((address_space(3))) void*)(lp), 16, 0, 0)

// ---- wide write-through store for cross-block exchange (L3-visible) ----
__device__ __forceinline__ void st_u64(void* p, unsigned long long v) {
    __hip_atomic_store((unsigned long long*)p, v, __ATOMIC_RELAXED, __HIP_MEMORY_SCOPE_AGENT);
}

// ---- split fence-free barrier (R14-proven: atomicAdd counter, relaxed poll) ----
__device__ __forceinline__ void gbar_arrive(unsigned int* slot)
{
    __syncthreads();    // drains vmcnt: this block's stores are L3-acked
    if (threadIdx.x == 0) atomicAdd(slot, 1u);
}
__device__ __forceinline__ void gbar_wait(unsigned int* slot, unsigned int nblk)
{
    if (threadIdx.x == 0) {
        while (__hip_atomic_load(slot, __ATOMIC_RELAXED, __HIP_MEMORY_SCOPE_AGENT) < nblk)
            __builtin_amdgcn_s_sleep(1);
    }
    __syncthreads();
}

// ---- W tile staging for chains: [64][256] bf16, XOR-swizzled 16B units ----
__device__ __forceinline__ void stage_wtile(const ushort* Wsrc, int ldw, int u0,
                                            ushort* lds, int lane, int wq)
{
    const int sub = lane >> 5, uu = lane & 31;
#pragma unroll
    for (int i = 0; i < 8; ++i) {
        const int row = i * 8 + wq * 2 + sub;
        const int su  = uu ^ (row & 7);
        const int gr  = (row >> 4) * HID + u0 + (row & 15);
        GLOAD_LDS(Wsrc + (size_t)gr * ldw + su * 8, lds + i * 2048 + wq * 512);
    }
}

// ---- chain cell quarter: H from global, W from swizzled LDS; 32 MFMA/wave ----
__device__ __forceinline__ void cell_g(const ushort* hrow0, int ldh,
                                       const ushort* WsL, f32x4 acc[4], int lane)
{
    const int fr = lane & 15, fq = lane >> 4;
    const ushort* hrow = hrow0 + (size_t)fr * ldh;
#pragma unroll
    for (int ks = 0; ks < 8; ++ks) {
        const bf16x8 af = *(const bf16x8*)(hrow + ks * 32 + fq * 8);
#pragma unroll
        for (int g = 0; g < 4; ++g) {
            const int vr = g * 16 + fr;
            const bf16x8 bf = *(const bf16x8*)(WsL + vr * 256 + (((ks * 4 + fq)) ^ (vr & 7)) * 8);
            acc[g] = __builtin_amdgcn_mfma_f32_16x16x32_bf16(af, bf, acc[g], 0, 0, 0);
        }
    }
}

// ---------------- fp32 -> bf16, 9 weight segments in one launch ----------------
struct Cvt9 {
    const float* s[9];
    ushort*      d[9];
    int          end[9];
};
__global__ __launch_bounds__(256)
void cvt_multi(Cvt9 A)
{
    int i = blockIdx.x * 256 + threadIdx.x;
    if (i >= A.end[8]) return;
    int seg = 0, beg = 0;
#pragma unroll
    for (int k = 0; k < 8; ++k)
        if (i >= A.end[k]) { seg = k + 1; beg = A.end[k]; }
    const int j = i - beg;
    const float4 v = *(const float4*)(A.s[seg] + (size_t)j * 4);
    *(ushort4*)(A.d[seg] + (size_t)j * 4) = make_ushort4(f2bf(v.x), f2bf(v.y), f2bf(v.z), f2bf(v.w));
}

// ======== 128x128 GEMM, BK=64, 64 KB LDS -> 2 blocks/CU; fused fp32->bf16 A. ========
// Same verified row layout as R16 (64-bf16 rows, unit swizzle u^(row&7), 0 conflicts).
// Linear idx staging keeps global_load_lds wave-uniform-base+lane*16.
__device__ __forceinline__ void loadA128(const float* Ag, int lda, int tid, float4 ra[4])
{
#pragma unroll
    for (int j = 0; j < 2; ++j) {
        const int idx = j * 512 + tid;
        const int row = idx >> 3, u = idx & 7;
        const int su = (u ^ (row & 7)) * 8;
        ra[2 * j + 0] = *(const float4*)(Ag + (size_t)row * lda + su);
        ra[2 * j + 1] = *(const float4*)(Ag + (size_t)row * lda + su + 4);
    }
}
__device__ __forceinline__ void writeA128(const float4 ra[4], ushort* Al, int tid)
{
#pragma unroll
    for (int j = 0; j < 2; ++j) {
        const int idx = j * 512 + tid;
        uint4 v;
        v.x = (uint)f2bf(ra[2 * j].x) | ((uint)f2bf(ra[2 * j].y) << 16);
        v.y = (uint)f2bf(ra[2 * j].z) | ((uint)f2bf(ra[2 * j].w) << 16);
        v.z = (uint)f2bf(ra[2 * j + 1].x) | ((uint)f2bf(ra[2 * j + 1].y) << 16);
        v.w = (uint)f2bf(ra[2 * j + 1].z) | ((uint)f2bf(ra[2 * j + 1].w) << 16);
        *(uint4*)(Al + idx * 8) = v;
    }
}
__device__ __forceinline__ void stageB128(const ushort* Bg, int ldw, ushort* Bl, int tid)
{
#pragma unroll
    for (int j = 0; j < 2; ++j) {
        const int idx = j * 512 + tid;
        const int row = idx >> 3, u = idx & 7;
        const int su = (u ^ (row & 7)) * 8;
        GLOAD_LDS(Bg + (size_t)row * ldw + su, Bl + idx * 8);
    }
}

__global__ __launch_bounds__(512, 4)
void gemm128f(const float* __restrict__ A, const ushort* __restrict__ W,
              float* __restrict__ C, int M, int N, int K,
              int lda, int ldw, int ldc)
{
    __shared__ ushort As[2][128 * 64];   // 32 KB
    __shared__ ushort Bs[2][128 * 64];   // 32 KB
    const int tid = threadIdx.x, lane = tid & 63, wid = tid >> 6;

    const int gx = gridDim.x, nwg = gx * gridDim.y;
    int bid = blockIdx.y * gx + blockIdx.x;
    {   // bijective XCD-chunked swizzle (nwg % 8 == 0 for both shapes)
        const int q = nwg >> 3, r = nwg & 7;
        const int xcd = bid & 7, o = bid >> 3;
        bid = (xcd < r) ? xcd * (q + 1) + o : r * (q + 1) + (xcd - r) * q + o;
    }
    const int m0 = (bid / gx) * 128, n0 = (bid % gx) * 128;

    const int wr = wid >> 1, wc = wid & 1;     // 4m x 2n wave grid
    const int fr = lane & 15, fq = lane >> 4;

    f32x4 acc[2][4] = {};
    const int nt = K / 64;
    const float*  Ab0 = A + (size_t)m0 * lda;
    const ushort* Bb0 = W + (size_t)n0 * ldw;

    float4 ra[4];
    loadA128(Ab0, lda, tid, ra);             // 4 loads (A0)
    stageB128(Bb0, ldw, Bs[0], tid);         // 2 loads (B0)
    writeA128(ra, As[0], tid);               // compiler waits A0
    loadA128(Ab0 + 64, lda, tid, ra);        // 4 loads (A1, in flight)
    asm volatile("s_waitcnt vmcnt(4) lgkmcnt(0)" ::: "memory");  // B0 done
    __builtin_amdgcn_sched_barrier(0);
    __builtin_amdgcn_s_barrier();
    __builtin_amdgcn_sched_barrier(0);

    for (int t = 0; t < nt; ++t) {
        const int p = t & 1;
        const int t1 = (t + 1 < nt) ? t + 1 : nt - 1;
        const int t2 = (t + 2 < nt) ? t + 2 : nt - 1;
        stageB128(Bb0 + t1 * 64, ldw, Bs[p ^ 1], tid);   // 2 loads
        writeA128(ra, As[p ^ 1], tid);                    // A(t+1) -> LDS
        loadA128(Ab0 + t2 * 64, lda, tid, ra);            // 4 loads (A t+2)

        const ushort* Ab = As[p];
        const ushort* Bb = Bs[p];
#pragma unroll
        for (int ks = 0; ks < 2; ++ks) {
            bf16x8 bfr[4];
#pragma unroll
            for (int nf = 0; nf < 4; ++nf) {
                const int row = wc * 64 + nf * 16 + fr;
                bfr[nf] = *(const bf16x8*)(Bb + row * 64 + ((ks * 4 + fq) ^ (row & 7)) * 8);
            }
            bf16x8 af[2];
#pragma unroll
            for (int mf = 0; mf < 2; ++mf) {
                const int row = wr * 32 + mf * 16 + fr;
                af[mf] = *(const bf16x8*)(Ab + row * 64 + ((ks * 4 + fq) ^ (row & 7)) * 8);
            }
            __builtin_amdgcn_s_setprio(1);
#pragma unroll
            for (int mf = 0; mf < 2; ++mf)
#pragma unroll
                for (int nf = 0; nf < 4; ++nf)
                    acc[mf][nf] = __builtin_amdgcn_mfma_f32_16x16x32_bf16(
                        af[mf], bfr[nf], acc[mf][nf], 0, 0, 0);
            __builtin_amdgcn_s_setprio(0);
        }
        if (t == nt - 1) break;
        asm volatile("s_waitcnt vmcnt(4) lgkmcnt(0)" ::: "memory");
        __builtin_amdgcn_sched_barrier(0);
        __builtin_amdgcn_s_barrier();
        __builtin_amdgcn_sched_barrier(0);
    }

    const int cl = lane & 15, ch = lane >> 4;
#pragma unroll
    for (int mf = 0; mf < 2; ++mf)
#pragma unroll
        for (int nf = 0; nf < 4; ++nf)
#pragma unroll
            for (int r = 0; r < 4; ++r)
                C[(size_t)(m0 + wr * 32 + mf * 16 + ch * 4 + r) * ldc
                  + n0 + wc * 64 + nf * 16 + cl] = acc[mf][nf][r];
}

// ---------------- 128x128 bf16 MFMA GEMM (small shapes) ----------------
__global__ __launch_bounds__(256)
void gemm_mfma_bt(const ushort* __restrict__ A, const ushort* __restrict__ W,
                  float* __restrict__ C, int M, int N, int K,
                  int lda, int ldw, int ldc, const float* __restrict__ rbias)
{
    __shared__ ushort As[128 * 32];
    __shared__ ushort Bs[128 * 32];
    const int t    = threadIdx.x;
    const int lane = t & 63, wid = t >> 6;
    const int m0 = blockIdx.y * 128, n0 = blockIdx.x * 128;
    const int wr = wid >> 1, wc = wid & 1;

    f32x4 acc[4][4] = {};

    const int sr = wid * 16 + (lane >> 2);
    const int su = ((lane & 3) ^ ((lane >> 3) & 3)) * 8;
    const ushort* Ag = A + (size_t)(m0 + sr) * lda + su;
    const ushort* Wg = W + (size_t)(n0 + sr) * ldw + su;
    ushort* Al = As + wid * 512;
    ushort* Bl = Bs + wid * 512;

    const int fr = lane & 15;
    const int fq = lane >> 4;
    const int sw = (fr >> 1) & 3;

    for (int k0 = 0; k0 < K; k0 += 32) {
        GLOAD_LDS(Ag,                    Al);
        GLOAD_LDS(Ag + (size_t)64 * lda, Al + 2048);
        GLOAD_LDS(Wg,                    Bl);
        GLOAD_LDS(Wg + (size_t)64 * ldw, Bl + 2048);
        Ag += 32; Wg += 32;
        __syncthreads();

        bf16x8 af[4], bfr[4];
#pragma unroll
        for (int m = 0; m < 4; ++m)
            af[m] = *(const bf16x8*)(As + (wr * 64 + m * 16 + fr) * 32 + (fq ^ sw) * 8);
#pragma unroll
        for (int n = 0; n < 4; ++n)
            bfr[n] = *(const bf16x8*)(Bs + (wc * 64 + n * 16 + fr) * 32 + (fq ^ sw) * 8);
#pragma unroll
        for (int m = 0; m < 4; ++m)
#pragma unroll
            for (int n = 0; n < 4; ++n)
                acc[m][n] = __builtin_amdgcn_mfma_f32_16x16x32_bf16(af[m], bfr[n], acc[m][n], 0, 0, 0);
        __syncthreads();
    }

    const int cl = lane & 15, ch = lane >> 4;
#pragma unroll
    for (int m = 0; m < 4; ++m)
#pragma unroll
        for (int n = 0; n < 4; ++n)
#pragma unroll
            for (int r = 0; r < 4; ++r) {
                const int mm = m0 + wr * 64 + m * 16 + ch * 4 + r;
                const int nn = n0 + wc * 64 + n * 16 + cl;
                float v = acc[m][n][r];
                if (rbias) v += rbias[(size_t)(mm & 511) * ldc + nn];
                C[(size_t)mm * ldc + nn] = v;
            }
}

// ---------------- fp32 tiled GEMM (GBIAS one-off) ----------------
__global__ __launch_bounds__(256)
void gemm_tn(const float* __restrict__ A, const float* __restrict__ W,
             const float* __restrict__ b1, const float* __restrict__ b2,
             float* __restrict__ C,
             int M, int N, int K, int lda, int ldw, int ldc)
{
    __shared__ float AsT[16][68];
    __shared__ float WsT[16][68];
    const int t  = threadIdx.x;
    const int tx = t & 15, ty = t >> 4;
    const int m0 = blockIdx.y * 64, n0 = blockIdx.x * 64;
    const int lr = t >> 2;
    const int c4 = t & 3;

    float acc[4][4];
#pragma unroll
    for (int i = 0; i < 4; ++i)
#pragma unroll
        for (int j = 0; j < 4; ++j) acc[i][j] = 0.0f;

    for (int k0 = 0; k0 < K; k0 += 16) {
        float a[4], w[4];
        const int kb = k0 + c4 * 4;
#pragma unroll
        for (int k = 0; k < 4; ++k) {
            a[k] = (kb + k < K) ? A[(size_t)(m0 + lr) * lda + kb + k] : 0.0f;
            w[k] = (kb + k < K) ? W[(size_t)(n0 + lr) * ldw + kb + k] : 0.0f;
        }
        __syncthreads();
#pragma unroll
        for (int k = 0; k < 4; ++k) {
            AsT[c4 * 4 + k][lr] = a[k];
            WsT[c4 * 4 + k][lr] = w[k];
        }
        __syncthreads();
#pragma unroll
        for (int kk = 0; kk < 16; ++kk) {
            const float4 av = *(const float4*)&AsT[kk][ty * 4];
            const float4 wv = *(const float4*)&WsT[kk][tx * 4];
            acc[0][0] += av.x * wv.x; acc[0][1] += av.x * wv.y; acc[0][2] += av.x * wv.z; acc[0][3] += av.x * wv.w;
            acc[1][0] += av.y * wv.x; acc[1][1] += av.y * wv.y; acc[1][2] += av.y * wv.z; acc[1][3] += av.y * wv.w;
            acc[2][0] += av.z * wv.x; acc[2][1] += av.z * wv.y; acc[2][2] += av.z * wv.z; acc[2][3] += av.z * wv.w;
            acc[3][0] += av.w * wv.x; acc[3][1] += av.w * wv.y; acc[3][2] += av.w * wv.z; acc[3][3] += av.w * wv.w;
        }
    }

#pragma unroll
    for (int i = 0; i < 4; ++i) {
        const int m = m0 + ty * 4 + i;
#pragma unroll
        for (int j = 0; j < 4; ++j) {
            const int n = n0 + tx * 4 + j;
            float v = acc[i][j];
            if (b1) v += b1[n];
            if (b2) v += b2[n];
            C[(size_t)m * ldc + n] = v;
        }
    }
}

// ---------------- persistent encoder: se + pe chains, 16 steps ----------------
struct EncArgs {
    const ushort *WHse, *WHpe;
    const float  *xg_se;
    const float  *enc_pos;
    const float  *se_b1, *se_b2, *pe_b1, *pe_b2;
    const float  *pe_Wih;
    ushort       *conc;      // [16][512][512]
    float        *SE_C, *PE_C;
    unsigned int *bar;
};

__global__ __launch_bounds__(1024)
void enc_chain(EncArgs A)
{
    __shared__ ushort Ws[4][64 * 256];
    __shared__ ushort hloc[64][64];
    const int tid = threadIdx.x, lane = tid & 63, w = tid >> 6;
    const int role  = blockIdx.x >> 5;
    const int rem   = blockIdx.x & 31;
    const int btile = rem & 7, usup = rem >> 3;
    const int b0 = btile * 64, ub = usup * 64;
    const int usub = w & 3, bsub = w >> 2;
    const int u0t = ub + usub * 16;
    const int grp = role * 8 + btile;
    const int fr = lane & 15, fq = lane >> 4;
    const int u = u0t + fr;
    const int ul = usub * 16 + fr;
    const int coff = role ? 256 : 0;

    stage_wtile(role ? A.WHpe : A.WHse, HID, u0t, Ws[usub], lane, bsub);

    const float* b1 = role ? A.pe_b1 : A.se_b1;
    const float* b2 = role ? A.pe_b2 : A.se_b2;
    float bias[4], wxs[4][3];
#pragma unroll
    for (int g = 0; g < 4; ++g) {
        bias[g] = b1[g * HID + u] + b2[g * HID + u];
        wxs[g][0] = wxs[g][1] = wxs[g][2] = 0.0f;
        if (role) {
            wxs[g][0] = A.pe_Wih[(g * HID + u) * 3 + 0];
            wxs[g][1] = A.pe_Wih[(g * HID + u) * 3 + 1];
            wxs[g][2] = A.pe_Wih[(g * HID + u) * 3 + 2];
        }
    }
    float c[4] = {0.f, 0.f, 0.f, 0.f};
    __syncthreads();

    for (int t = 0; t < MENC; ++t) {
        float xg[4][4];
#pragma unroll
        for (int r = 0; r < 4; ++r) {
            const int b = b0 + bsub * 16 + fq * 4 + r;
            if (role) {
                const float* xp = A.enc_pos + ((size_t)b * MENC + t) * 3;
                xg[r][0] = xp[0]; xg[r][1] = xp[1]; xg[r][2] = xp[2]; xg[r][3] = 0.f;
            } else {
#pragma unroll
                for (int g = 0; g < 4; ++g)
                    xg[r][g] = A.xg_se[((size_t)b * MENC + t) * 1024 + g * HID + u];
            }
        }
        if (t > 0) gbar_wait(A.bar + grp * MENC + (t - 1), 4);
        f32x4 acc[4] = {};
        if (t > 0)
            cell_g(A.conc + ((size_t)(t - 1) * 512 + b0 + bsub * 16) * 512 + coff, 512,
                   Ws[usub], acc, lane);
#pragma unroll
        for (int r = 0; r < 4; ++r) {
            const int bl = bsub * 16 + fq * 4 + r;
            const int b = b0 + bl;
            float gv[4];
#pragma unroll
            for (int g = 0; g < 4; ++g) {
                float v = acc[g][r] + bias[g];
                if (role) v += xg[r][0] * wxs[g][0] + xg[r][1] * wxs[g][1] + xg[r][2] * wxs[g][2];
                else      v += xg[r][g];
                gv[g] = v;
            }
            const float cn = sigmf(gv[1]) * c[r] + sigmf(gv[0]) * tanhf(gv[2]);
            const float hn = sigmf(gv[3]) * tanhf(cn);
            c[r] = cn;
            hloc[bl][ul] = f2bf(hn);
            if (t == MENC - 1) (role ? A.PE_C : A.SE_C)[(size_t)b * HID + u] = cn;
        }
        __syncthreads();
        {
            const int row = tid >> 4, c8 = tid & 15;
            const unsigned long long v = *(const unsigned long long*)&hloc[row][c8 * 4];
            st_u64(A.conc + ((size_t)t * 512 + b0 + row) * 512 + coff + ub + c8 * 4, v);
        }
        if (t != MENC - 1) gbar_arrive(A.bar + grp * MENC + t);
    }
}

// ---------------- persistent mid: sd (25) + fe (16) ----------------
struct MidArgs {
    const ushort *WHsd, *WHfe;
    const float  *xg_sd;
    const float  *xg_fe;
    const float  *sd_b1, *sd_b2, *fe_b1, *fe_b2;
    const ushort *conc;
    const float  *SE_C;
    ushort       *SDB;       // [25][512][256]
    ushort       *FEB;       // [16][512][256]
    float        *FEH, *FE_C;
    unsigned int *bar;
};

__global__ __launch_bounds__(1024)
void mid_chain(MidArgs A)
{
    __shared__ ushort Ws[4][64 * 256];
    __shared__ ushort hloc[64][64];
    const int tid = threadIdx.x, lane = tid & 63, w = tid >> 6;
    const int role  = blockIdx.x >> 5;
    const int rem   = blockIdx.x & 31;
    const int btile = rem & 7, usup = rem >> 3;
    const int b0 = btile * 64, ub = usup * 64;
    const int usub = w & 3, bsub = w >> 2;
    const int u0t = ub + usub * 16;
    const int grp = role * 8 + btile;
    const int fr = lane & 15, fq = lane >> 4;
    const int u = u0t + fr;
    const int ul = usub * 16 + fr;
    const int NT = role ? MENC : HWIN;

    stage_wtile(role ? A.WHfe : A.WHsd, HID, u0t, Ws[usub], lane, bsub);

    const float* b1 = role ? A.fe_b1 : A.sd_b1;
    const float* b2 = role ? A.fe_b2 : A.sd_b2;
    float bias[4];
#pragma unroll
    for (int g = 0; g < 4; ++g) bias[g] = b1[g * HID + u] + b2[g * HID + u];

    float c[4];
#pragma unroll
    for (int r = 0; r < 4; ++r) {
        const int b = b0 + bsub * 16 + fq * 4 + r;
        c[r] = role ? 0.0f : A.SE_C[(size_t)b * HID + u];
    }
    __syncthreads();

    for (int t = 0; t < NT; ++t) {
        float xg[4][4];
#pragma unroll
        for (int r = 0; r < 4; ++r) {
            const int b = b0 + bsub * 16 + fq * 4 + r;
#pragma unroll
            for (int g = 0; g < 4; ++g)
                xg[r][g] = role ? A.xg_fe[((size_t)t * 512 + b) * 1024 + g * HID + u]
                                : A.xg_sd[((size_t)b * HWIN + t) * 1024 + g * HID + u];
        }
        if (t > 0) gbar_wait(A.bar + grp * HWIN + (t - 1), 4);
        f32x4 acc[4] = {};
        if (role == 0) {
            if (t == 0) cell_g(A.conc + ((size_t)15 * 512 + b0 + bsub * 16) * 512, 512,
                               Ws[usub], acc, lane);
            else        cell_g(A.SDB + ((size_t)(t - 1) * 512 + b0 + bsub * 16) * HID, HID,
                               Ws[usub], acc, lane);
        } else if (t > 0) {
            cell_g(A.FEB + ((size_t)(t - 1) * BATCH + b0 + bsub * 16) * HID, HID,
                   Ws[usub], acc, lane);
        }
#pragma unroll
        for (int r = 0; r < 4; ++r) {
            const int bl = bsub * 16 + fq * 4 + r;
            const int b = b0 + bl;
            float gv[4];
#pragma unroll
            for (int g = 0; g < 4; ++g)
                gv[g] = acc[g][r] + bias[g] + xg[r][g];
            const float cn = sigmf(gv[1]) * c[r] + sigmf(gv[0]) * tanhf(gv[2]);
            const float hn = sigmf(gv[3]) * tanhf(cn);
            c[r] = cn;
            hloc[bl][ul] = f2bf(hn);
            if (role == 1 && t == MENC - 1) {
                A.FEH[(size_t)b * HID + u] = hn;
                A.FE_C[(size_t)b * HID + u] = cn;
            }
        }
        __syncthreads();
        {
            const int row = tid >> 4, c8 = tid & 15;
            const unsigned long long v = *(const unsigned long long*)&hloc[row][c8 * 4];
            ushort* dst = role ? (A.FEB + ((size_t)t * BATCH + b0 + row) * 256 + ub + c8 * 4)
                               : (A.SDB + ((size_t)t * 512 + b0 + row) * 256 + ub + c8 * 4);
            st_u64(dst, v);
        }
        if (t != NT - 1) gbar_arrive(A.bar + grp * HWIN + t);
    }
}

// ---------------- persistent decoder: pd + fd + tail, 25 steps ----------------
struct DecArgs {
    const ushort *WHpd;
    const ushort *WFDh;
    const ushort *peF;
    const float  *PE_C, *FE_C;
    const float  *xh2;
    const float  *pd_b1, *pd_b2, *pd_Wih;
    const float  *G, *c3, *dec_pos;
    ushort       *H1;        // [25][512][256]
    float        *DELTA;     // [25][512][3], pre-zeroed
    float        *out;       // [512][25][3]
    unsigned int *bar;       // 8 groups x 50
};

__global__ __launch_bounds__(512)
void dec_chain(DecArgs A)
{
    __shared__ ushort Wpd[2][64 * 256], Wfd[2][64 * 256];
    __shared__ ushort hloc[64][32];
    __shared__ float pred_lds[192];
    const int tid = threadIdx.x, lane = tid & 63, w = tid >> 6;
    const int btile = blockIdx.x & 7, usup = blockIdx.x >> 3;
    const int b0 = btile * 64, ub = usup * 32;
    const int usub = w & 1, bsub = w >> 1;
    const int u0t = ub + usub * 16;
    const int fr = lane & 15, fq = lane >> 4;
    const int u = u0t + fr;
    const int ul = usub * 16 + fr;
    unsigned int* bars = A.bar + btile * 2 * HWIN;

    stage_wtile(A.WHpd, HID, u0t, Wpd[usub], lane, bsub);
    stage_wtile(A.WFDh, 512, u0t, Wfd[usub], lane, bsub);

    float pdb[4], wxs[4][3], cf[4], c1[4], Gu[3];
#pragma unroll
    for (int g = 0; g < 4; ++g) {
        pdb[g] = A.pd_b1[g * HID + u] + A.pd_b2[g * HID + u];
        wxs[g][0] = A.pd_Wih[(g * HID + u) * 3 + 0];
        wxs[g][1] = A.pd_Wih[(g * HID + u) * 3 + 1];
        wxs[g][2] = A.pd_Wih[(g * HID + u) * 3 + 2];
    }
#pragma unroll
    for (int r = 0; r < 4; ++r) {
        const int b = b0 + bsub * 16 + fq * 4 + r;
        c1[r] = A.PE_C[(size_t)b * HID + u];
        cf[r] = A.FE_C[(size_t)b * HID + u];
    }
    Gu[0] = A.G[0 * HID + u]; Gu[1] = A.G[1 * HID + u]; Gu[2] = A.G[2 * HID + u];
    const float c3r = (tid < 192) ? A.c3[tid % 3] : 0.0f;
    if (tid < 192) pred_lds[tid] = A.dec_pos[(size_t)(b0 + tid / 3) * 3 + tid % 3];
    __syncthreads();

    for (int t = 0; t < HWIN; ++t) {
        f32x4 acc[4] = {};
        if (t == 0) cell_g(A.peF + (size_t)(b0 + bsub * 16) * 512, 512, Wpd[usub], acc, lane);
        else        cell_g(A.H1 + ((size_t)(t - 1) * BATCH + b0 + bsub * 16) * HID, HID,
                           Wpd[usub], acc, lane);
        if (t > 0) {
            gbar_wait(bars + 2 * (t - 1) + 1, 8);
            if (tid < 192) {
                pred_lds[tid] += A.DELTA[((size_t)(t - 1) * 512 + b0 + tid / 3) * 3 + tid % 3] + c3r;
                if (usup == 0)
                    A.out[((size_t)(b0 + tid / 3) * HWIN + (t - 1)) * 3 + tid % 3] = pred_lds[tid];
            }
            __syncthreads();
        }
#pragma unroll
        for (int r = 0; r < 4; ++r) {
            const int bl = bsub * 16 + fq * 4 + r;
            const float x0 = pred_lds[bl * 3 + 0];
            const float x1 = pred_lds[bl * 3 + 1];
            const float x2 = pred_lds[bl * 3 + 2];
            float gv[4];
#pragma unroll
            for (int g = 0; g < 4; ++g)
                gv[g] = acc[g][r] + pdb[g] + x0 * wxs[g][0] + x1 * wxs[g][1] + x2 * wxs[g][2];
            const float cn = sigmf(gv[1]) * c1[r] + sigmf(gv[0]) * tanhf(gv[2]);
            const float hn = sigmf(gv[3]) * tanhf(cn);
            c1[r] = cn;
            hloc[bl][ul] = f2bf(hn);
        }
        __syncthreads();
        {
            const int row = tid >> 3, c8 = tid & 7;
            const unsigned long long v = *(const unsigned long long*)&hloc[row][c8 * 4];
            st_u64(A.H1 + ((size_t)t * BATCH + b0 + row) * 256 + ub + c8 * 4, v);
        }
        gbar_arrive(bars + 2 * t);
        float xh[4][4];
#pragma unroll
        for (int r = 0; r < 4; ++r) {
            const int b = b0 + bsub * 16 + fq * 4 + r;
#pragma unroll
            for (int g = 0; g < 4; ++g)
                xh[r][g] = A.xh2[((size_t)t * 512 + b) * 1024 + g * HID + u];
        }
        gbar_wait(bars + 2 * t, 8);
        {
            f32x4 accB[4] = {};
            cell_g(A.H1 + ((size_t)t * BATCH + b0 + bsub * 16) * HID, HID,
                   Wfd[usub], accB, lane);
#pragma unroll
            for (int r = 0; r < 4; ++r) {
                const int b = b0 + bsub * 16 + fq * 4 + r;
                float gv[4];
#pragma unroll
                for (int g = 0; g < 4; ++g)
                    gv[g] = accB[g][r] + xh[r][g];
                const float cn = sigmf(gv[1]) * cf[r] + sigmf(gv[0]) * tanhf(gv[2]);
                const float hn = sigmf(gv[3]) * tanhf(cn);
                float p0 = hn * Gu[0], p1 = hn * Gu[1], p2 = hn * Gu[2];
#pragma unroll
                for (int s = 1; s < 16; s <<= 1) {
                    p0 += __shfl_xor(p0, s);
                    p1 += __shfl_xor(p1, s);
                    p2 += __shfl_xor(p2, s);
                }
                if (fr == 0) {
                    float* d = A.DELTA + ((size_t)t * 512 + b) * 3;
                    atomicAdd(d + 0, p0); atomicAdd(d + 1, p1); atomicAdd(d + 2, p2);
                }
            }
        }
        gbar_arrive(bars + 2 * t + 1);
    }
    gbar_wait(bars + 2 * (HWIN - 1) + 1, 8);
    if (tid < 192) {
        pred_lds[tid] += A.DELTA[((size_t)(HWIN - 1) * 512 + b0 + tid / 3) * 3 + tid % 3] + c3r;
        if (usup == 0)
            A.out[((size_t)(b0 + tid / 3) * HWIN + (HWIN - 1)) * 3 + tid % 3] = pred_lds[tid];
    }
}

// ---------------- G = out_W @ f2_W, c3 = out_b + out_W @ f2_b ----------------
__global__ __launch_bounds__(256)
void precompute_G(const float* __restrict__ f2W, const float* __restrict__ f2b,
                  const float* __restrict__ outW, const float* __restrict__ outb,
                  float* __restrict__ G, float* __restrict__ c3)
{
    const int k = threadIdx.x;
    float g0 = 0.f, g1 = 0.f, g2 = 0.f;
    for (int n = 0; n < HID; ++n) {
        const float w = f2W[n * HID + k];
        g0 += outW[n] * w;
        g1 += outW[HID + n] * w;
        g2 += outW[2 * HID + n] * w;
    }
    G[k] = g0; G[HID + k] = g1; G[2 * HID + k] = g2;
    if (k < 3) {
        float s = outb[k];
        for (int n = 0; n < HID; ++n) s += outW[k * HID + n] * f2b[n];
        c3[k] = s;
    }
}

extern "C" void kernel_launch(void* const* d_in, const int* in_sizes, int n_in,
                              void* d_out, int out_size, void* d_ws, size_t ws_size,
                              hipStream_t stream)
{
    (void)in_sizes; (void)n_in; (void)out_size; (void)ws_size;
    const float* enc_pos = (const float*)d_in[0];
    const float* enc_sal = (const float*)d_in[1];
    const float* dec_pos = (const float*)d_in[2];
    const float* dec_sal = (const float*)d_in[3];
    const float *pe_Wih = (const float*)d_in[4],  *pe_Whh = (const float*)d_in[5],
                *pe_bih = (const float*)d_in[6],  *pe_bhh = (const float*)d_in[7];
    const float *se_Wih = (const float*)d_in[8],  *se_Whh = (const float*)d_in[9],
                *se_bih = (const float*)d_in[10], *se_bhh = (const float*)d_in[11];
    const float *fe_Wih = (const float*)d_in[12], *fe_Whh = (const float*)d_in[13],
                *fe_bih = (const float*)d_in[14], *fe_bhh = (const float*)d_in[15];
    const float *pd_Wih = (const float*)d_in[16], *pd_Whh = (const float*)d_in[17],
                *pd_bih = (const float*)d_in[18], *pd_bhh = (const float*)d_in[19];
    const float *sd_Wih = (const float*)d_in[20], *sd_Whh = (const float*)d_in[21],
                *sd_bih = (const float*)d_in[22], *sd_bhh = (const float*)d_in[23];
    const float *fd_Wih = (const float*)d_in[24], *fd_Whh = (const float*)d_in[25],
                *fd_bih = (const float*)d_in[26], *fd_bhh = (const float*)d_in[27];
    const float *f2_W = (const float*)d_in[28], *f2_b = (const float*)d_in[29];
    const float *out_W = (const float*)d_in[30], *out_b = (const float*)d_in[31];
    float* out = (float*)d_out;
    float* ws  = (float*)d_ws;

    size_t off = 0;
    float* XG_SE = ws + off; off += (size_t)8192 * 1024;
    float* XG_FE = ws + off; off += (size_t)8192 * 1024;
    float* BIG   = ws + off; off += (size_t)12800 * 1024;
    float* BIG2  = ws + off; off += (size_t)12800 * 1024;
    float* GBIAS = ws + off; off += (size_t)BATCH * 1024;
    float* PE_C  = ws + off; off += BH;
    float* SE_C  = ws + off; off += BH;
    float* FE_C  = ws + off; off += BH;
    float* FEH   = ws + off; off += BH;
    float* Gm    = ws + off; off += 1024;
    float* C3    = ws + off; off += 8;
    float* DELTA = ws + off; off += (size_t)HWIN * BATCH * 3 + 64;
    unsigned int* BAR = (unsigned int*)(ws + off); off += 1280;
    ushort* WSE  = (ushort*)(ws + off); off += ((size_t)1024 * 4096) / 2;
    ushort* WSD  = (ushort*)(ws + off); off += ((size_t)1024 * 4096) / 2;
    ushort* WFE  = (ushort*)(ws + off); off += ((size_t)1024 * 512) / 2;
    ushort* WFD  = (ushort*)(ws + off); off += ((size_t)1024 * 512) / 2;
    ushort* WHpe = (ushort*)(ws + off); off += ((size_t)1024 * 256) / 2;
    ushort* WHse = (ushort*)(ws + off); off += ((size_t)1024 * 256) / 2;
    ushort* WHfe = (ushort*)(ws + off); off += ((size_t)1024 * 256) / 2;
    ushort* WHsd = (ushort*)(ws + off); off += ((size_t)1024 * 256) / 2;
    ushort* WHpd = (ushort*)(ws + off); off += ((size_t)1024 * 256) / 2;
    ushort* CONC = (ushort*)(ws + off); off += ((size_t)MENC * 512 * 512) / 2;
    ushort* SDB  = (ushort*)(ws + off); off += ((size_t)HWIN * BH) / 2;
    ushort* FEB  = (ushort*)(ws + off); off += ((size_t)MENC * BH) / 2;
    ushort* H1   = (ushort*)(ws + off); off += ((size_t)HWIN * BH) / 2;

    // DELTA and BAR contiguous: one memset
    hipMemsetAsync(DELTA, 0, ((size_t)HWIN * BATCH * 3 + 64 + 1280) * 4, stream);

    auto mgemm = [&](const ushort* A, const ushort* W, float* C,
                     int M, int N, int K, int lda, int ldw, int ldc, const float* rb) {
        gemm_mfma_bt<<<dim3(N / 128, M / 128), 256, 0, stream>>>(A, W, C, M, N, K, lda, ldw, ldc, rb);
    };
    auto mgemm128f = [&](const float* A, const ushort* W, float* C,
                         int M, int N, int K, int lda, int ldw, int ldc) {
        gemm128f<<<dim3(N / 128, M / 128), 512, 0, stream>>>(A, W, C, M, N, K, lda, ldw, ldc);
    };

    // ---- all 9 weight conversions in ONE launch ----
    {
        Cvt9 a;
        const float* srcs[9] = { se_Wih, sd_Wih, fe_Wih, fd_Wih, pe_Whh, se_Whh, fe_Whh, sd_Whh, pd_Whh };
        ushort*      dsts[9] = { WSE,    WSD,    WFE,    WFD,    WHpe,   WHse,   WHfe,   WHsd,   WHpd };
        const int    n4s[9]  = { 1024*4096/4, 1024*4096/4, 1024*512/4, 1024*512/4,
                                 1024*256/4, 1024*256/4, 1024*256/4, 1024*256/4, 1024*256/4 };
        int acc9 = 0;
        for (int i = 0; i < 9; ++i) { a.s[i] = srcs[i]; a.d[i] = dsts[i]; acc9 += n4s[i]; a.end[i] = acc9; }
        cvt_multi<<<(acc9 + 255) / 256, 256, 0, stream>>>(a);
    }
    precompute_G<<<1, 256, 0, stream>>>(f2_W, f2_b, out_W, out_b, Gm, C3);

    // ---- se x-proj; sd x-proj — 128² tiles, 2 blocks/CU, fused fp32->bf16 A ----
    mgemm128f(enc_sal, WSE, XG_SE, 8192, 1024, SALSZ, SALSZ, SALSZ, 1024);
    mgemm128f(dec_sal, WSD, BIG, 12800, 1024, SALSZ, SALSZ, SALSZ, 1024);

    // ---- persistent encoder (se + pe): 64 blocks x 1024 ----
    {
        EncArgs a;
        a.WHse = WHse; a.WHpe = WHpe; a.xg_se = XG_SE; a.enc_pos = enc_pos;
        a.se_b1 = se_bih; a.se_b2 = se_bhh; a.pe_b1 = pe_bih; a.pe_b2 = pe_bhh;
        a.pe_Wih = pe_Wih; a.conc = CONC; a.SE_C = SE_C; a.PE_C = PE_C;
        a.bar = BAR;
        enc_chain<<<64, 1024, 0, stream>>>(a);
    }

    // ---- fe x-proj (rows t,b) ----
    mgemm(CONC, WFE, XG_FE, 8192, 1024, 512, 512, 512, 1024, nullptr);

    // ---- persistent mid (sd + fe): 64 blocks x 1024 ----
    {
        MidArgs a;
        a.WHsd = WHsd; a.WHfe = WHfe; a.xg_sd = BIG; a.xg_fe = XG_FE;
        a.sd_b1 = sd_bih; a.sd_b2 = sd_bhh; a.fe_b1 = fe_bih; a.fe_b2 = fe_bhh;
        a.conc = CONC; a.SE_C = SE_C; a.SDB = SDB; a.FEB = FEB;
        a.FEH = FEH; a.FE_C = FE_C; a.bar = BAR + 256;
        mid_chain<<<64, 1024, 0, stream>>>(a);
    }

    // ---- fd precomputations ----
    gemm_tn<<<dim3(16, 8), 256, 0, stream>>>(FEH, fd_Whh, fd_bih, fd_bhh, GBIAS,
                                             BATCH, 1024, HID, HID, HID, 1024);
    mgemm(SDB, WFD, BIG2, 12800, 1024, HID, HID, 512, 1024, GBIAS);

    // ---- persistent decoder (pd + fd + tail): 64 blocks x 512 ----
    {
        DecArgs a;
        a.WHpd = WHpd; a.WFDh = WFD + 256;
        a.peF = CONC + ((size_t)15 * 512) * 512 + 256;
        a.PE_C = PE_C; a.FE_C = FE_C; a.xh2 = BIG2;
        a.pd_b1 = pd_bih; a.pd_b2 = pd_bhh; a.pd_Wih = pd_Wih;
        a.G = Gm; a.c3 = C3; a.dec_pos = dec_pos;
        a.H1 = H1; a.DELTA = DELTA; a.out = out; a.bar = BAR + 656;
        dec_chain<<<64, 512, 0, stream>>>(a);
    }
}

// Round 21
// 1033.225 us; speedup vs baseline: 1.1730x; 1.1082x over previous
//
#include <hip/hip_runtime.h>

#define HID 256
#define BATCH 512
#define MENC 16
#define HWIN 25
#define SALSZ 4096
#define BH (BATCH * HID)   // 131072

typedef __attribute__((ext_vector_type(8))) short bf16x8;
typedef __attribute__((ext_vector_type(4))) float f32x4;

__device__ __forceinline__ float sigmf(float x) { return 1.0f / (1.0f + __expf(-x)); }
__device__ __forceinline__ ushort f2bf(float f) {
    uint32_t u = __float_as_uint(f);
    return (ushort)((u + 0x7fffu + ((u >> 16) & 1u)) >> 16);   // RNE
}

#define GLOAD_LDS(gp, lp) \
    __builtin_amdgcn_global_load_lds((const __attribute__((address_space(1))) void*)(gp), \
                                     (__attribute__((address_space(3))) void*)(lp), 16, 0, 0)

// ---- wide write-through store for cross-block exchange (L3-visible) ----
__device__ __forceinline__ void st_u64(void* p, unsigned long long v) {
    __hip_atomic_store((unsigned long long*)p, v, __ATOMIC_RELAXED, __HIP_MEMORY_SCOPE_AGENT);
}

// ---- split fence-free barrier (R14-proven) ----
__device__ __forceinline__ void gbar_arrive(unsigned int* slot)
{
    __syncthreads();    // drains vmcnt: this block's stores are L3-acked
    if (threadIdx.x == 0) atomicAdd(slot, 1u);
}
__device__ __forceinline__ void gbar_wait(unsigned int* slot, unsigned int nblk)
{
    if (threadIdx.x == 0) {
        while (__hip_atomic_load(slot, __ATOMIC_RELAXED, __HIP_MEMORY_SCOPE_AGENT) < nblk)
            __builtin_amdgcn_s_sleep(1);
    }
    __syncthreads();
}

// ---- W tile staging for chains: [64][256] bf16, XOR-swizzled 16B units ----
__device__ __forceinline__ void stage_wtile(const ushort* Wsrc, int ldw, int u0,
                                            ushort* lds, int lane, int wq)
{
    const int sub = lane >> 5, uu = lane & 31;
#pragma unroll
    for (int i = 0; i < 8; ++i) {
        const int row = i * 8 + wq * 2 + sub;
        const int su  = uu ^ (row & 7);
        const int gr  = (row >> 4) * HID + u0 + (row & 15);
        GLOAD_LDS(Wsrc + (size_t)gr * ldw + su * 8, lds + i * 2048 + wq * 512);
    }
}

// ---- chain cell quarter: H from global, W from swizzled LDS; 32 MFMA/wave ----
__device__ __forceinline__ void cell_g(const ushort* hrow0, int ldh,
                                       const ushort* WsL, f32x4 acc[4], int lane)
{
    const int fr = lane & 15, fq = lane >> 4;
    const ushort* hrow = hrow0 + (size_t)fr * ldh;
#pragma unroll
    for (int ks = 0; ks < 8; ++ks) {
        const bf16x8 af = *(const bf16x8*)(hrow + ks * 32 + fq * 8);
#pragma unroll
        for (int g = 0; g < 4; ++g) {
            const int vr = g * 16 + fr;
            const bf16x8 bf = *(const bf16x8*)(WsL + vr * 256 + (((ks * 4 + fq)) ^ (vr & 7)) * 8);
            acc[g] = __builtin_amdgcn_mfma_f32_16x16x32_bf16(af, bf, acc[g], 0, 0, 0);
        }
    }
}

// ---------------- fp32 -> bf16, 9 weight segments in one launch ----------------
struct Cvt9 {
    const float* s[9];
    ushort*      d[9];
    int          end[9];
};
__global__ __launch_bounds__(256)
void cvt_multi(Cvt9 A)
{
    int i = blockIdx.x * 256 + threadIdx.x;
    if (i >= A.end[8]) return;
    int seg = 0, beg = 0;
#pragma unroll
    for (int k = 0; k < 8; ++k)
        if (i >= A.end[k]) { seg = k + 1; beg = A.end[k]; }
    const int j = i - beg;
    const float4 v = *(const float4*)(A.s[seg] + (size_t)j * 4);
    *(ushort4*)(A.d[seg] + (size_t)j * 4) = make_ushort4(f2bf(v.x), f2bf(v.y), f2bf(v.z), f2bf(v.w));
}

// ======== 128x128 GEMM body, BK=64; fused fp32->bf16 A (R20-verified) ========
__device__ __forceinline__ void loadA128(const float* Ag, int lda, int tid, float4 ra[4])
{
#pragma unroll
    for (int j = 0; j < 2; ++j) {
        const int idx = j * 512 + tid;
        const int row = idx >> 3, u = idx & 7;
        const int su = (u ^ (row & 7)) * 8;
        ra[2 * j + 0] = *(const float4*)(Ag + (size_t)row * lda + su);
        ra[2 * j + 1] = *(const float4*)(Ag + (size_t)row * lda + su + 4);
    }
}
__device__ __forceinline__ void writeA128(const float4 ra[4], ushort* Al, int tid)
{
#pragma unroll
    for (int j = 0; j < 2; ++j) {
        const int idx = j * 512 + tid;
        uint4 v;
        v.x = (uint)f2bf(ra[2 * j].x) | ((uint)f2bf(ra[2 * j].y) << 16);
        v.y = (uint)f2bf(ra[2 * j].z) | ((uint)f2bf(ra[2 * j].w) << 16);
        v.z = (uint)f2bf(ra[2 * j + 1].x) | ((uint)f2bf(ra[2 * j + 1].y) << 16);
        v.w = (uint)f2bf(ra[2 * j + 1].z) | ((uint)f2bf(ra[2 * j + 1].w) << 16);
        *(uint4*)(Al + idx * 8) = v;
    }
}
__device__ __forceinline__ void stageB128(const ushort* Bg, int ldw, ushort* Bl, int tid)
{
#pragma unroll
    for (int j = 0; j < 2; ++j) {
        const int idx = j * 512 + tid;
        const int row = idx >> 3, u = idx & 7;
        const int su = (u ^ (row & 7)) * 8;
        GLOAD_LDS(Bg + (size_t)row * ldw + su, Bl + idx * 8);
    }
}

__device__ __forceinline__ void gemm128f_body(
    const float* __restrict__ A, const ushort* __restrict__ W, float* __restrict__ C,
    int lda, int ldw, int ldc, int K, int gx, int nwg, int bid,
    ushort* AsB, ushort* BsB, int tid)
{
    const int lane = tid & 63, wid = tid >> 6;
    {   // bijective XCD-chunked swizzle within this job's sub-grid
        const int q = nwg >> 3, r = nwg & 7;
        const int xcd = bid & 7, o = bid >> 3;
        bid = (xcd < r) ? xcd * (q + 1) + o : r * (q + 1) + (xcd - r) * q + o;
    }
    const int m0 = (bid / gx) * 128, n0 = (bid % gx) * 128;

    const int wr = wid >> 1, wc = wid & 1;     // 4m x 2n wave grid
    const int fr = lane & 15, fq = lane >> 4;

    f32x4 acc[2][4] = {};
    const int nt = K / 64;
    const float*  Ab0 = A + (size_t)m0 * lda;
    const ushort* Bb0 = W + (size_t)n0 * ldw;

    float4 ra[4];
    loadA128(Ab0, lda, tid, ra);
    stageB128(Bb0, ldw, BsB, tid);
    writeA128(ra, AsB, tid);
    loadA128(Ab0 + 64, lda, tid, ra);
    asm volatile("s_waitcnt vmcnt(4) lgkmcnt(0)" ::: "memory");
    __builtin_amdgcn_sched_barrier(0);
    __builtin_amdgcn_s_barrier();
    __builtin_amdgcn_sched_barrier(0);

    for (int t = 0; t < nt; ++t) {
        const int p = t & 1;
        const int t1 = (t + 1 < nt) ? t + 1 : nt - 1;
        const int t2 = (t + 2 < nt) ? t + 2 : nt - 1;
        stageB128(Bb0 + t1 * 64, ldw, BsB + (p ^ 1) * 8192, tid);
        writeA128(ra, AsB + (p ^ 1) * 8192, tid);
        loadA128(Ab0 + t2 * 64, lda, tid, ra);

        const ushort* Ab = AsB + p * 8192;
        const ushort* Bb = BsB + p * 8192;
#pragma unroll
        for (int ks = 0; ks < 2; ++ks) {
            bf16x8 bfr[4];
#pragma unroll
            for (int nf = 0; nf < 4; ++nf) {
                const int row = wc * 64 + nf * 16 + fr;
                bfr[nf] = *(const bf16x8*)(Bb + row * 64 + ((ks * 4 + fq) ^ (row & 7)) * 8);
            }
            bf16x8 af[2];
#pragma unroll
            for (int mf = 0; mf < 2; ++mf) {
                const int row = wr * 32 + mf * 16 + fr;
                af[mf] = *(const bf16x8*)(Ab + row * 64 + ((ks * 4 + fq) ^ (row & 7)) * 8);
            }
            __builtin_amdgcn_s_setprio(1);
#pragma unroll
            for (int mf = 0; mf < 2; ++mf)
#pragma unroll
                for (int nf = 0; nf < 4; ++nf)
                    acc[mf][nf] = __builtin_amdgcn_mfma_f32_16x16x32_bf16(
                        af[mf], bfr[nf], acc[mf][nf], 0, 0, 0);
            __builtin_amdgcn_s_setprio(0);
        }
        if (t == nt - 1) break;
        asm volatile("s_waitcnt vmcnt(4) lgkmcnt(0)" ::: "memory");
        __builtin_amdgcn_sched_barrier(0);
        __builtin_amdgcn_s_barrier();
        __builtin_amdgcn_sched_barrier(0);
    }

    const int cl = lane & 15, ch = lane >> 4;
#pragma unroll
    for (int mf = 0; mf < 2; ++mf)
#pragma unroll
        for (int nf = 0; nf < 4; ++nf)
#pragma unroll
            for (int r = 0; r < 4; ++r)
                C[(size_t)(m0 + wr * 32 + mf * 16 + ch * 4 + r) * ldc
                  + n0 + wc * 64 + nf * 16 + cl] = acc[mf][nf][r];
}

__global__ __launch_bounds__(512, 4)
void gemm128f(const float* __restrict__ A, const ushort* __restrict__ W,
              float* __restrict__ C, int gx, int nwg)
{
    __shared__ ushort As[2 * 128 * 64];
    __shared__ ushort Bs[2 * 128 * 64];
    gemm128f_body(A, W, C, SALSZ, SALSZ, 1024, SALSZ, gx, nwg, blockIdx.x, As, Bs, threadIdx.x);
}

// ---------------- merged: encoder chains (blocks 0..127) + sd GEMM (128..927) ----------------
struct EncArgs {
    const ushort *WHse, *WHpe;
    const float  *xg_se;
    const float  *enc_pos;
    const float  *se_b1, *se_b2, *pe_b1, *pe_b2;
    const float  *pe_Wih;
    ushort       *conc;      // [16][512][512]
    float        *SE_C, *PE_C;
    unsigned int *bar;       // 16 groups x 16 steps, degree 8
};

__global__ __launch_bounds__(512, 4)
void enc_sd(EncArgs A, const float* __restrict__ sdA, const ushort* __restrict__ sdW,
            float* __restrict__ sdC)
{
    __shared__ ushort sh[34816];   // 68 KB: enc = Ws[2](32768) + hloc(2048); gemm = As+Bs(32768)
    const int tid = threadIdx.x;

    if (blockIdx.x >= 128) {
        gemm128f_body(sdA, sdW, sdC, SALSZ, SALSZ, 1024, SALSZ, 8, 800,
                      (int)blockIdx.x - 128, sh, sh + 16384, tid);
        return;
    }

    // ---- encoder: 512 threads, 64 b x 32 u per block; degree-8 barrier groups ----
    const int lane = tid & 63, w = tid >> 6;
    const int role  = blockIdx.x >> 6;          // 0 = se, 1 = pe
    const int rem   = blockIdx.x & 63;
    const int btile = rem & 7, usup = rem >> 3;  // 8 usup of 32 u
    const int b0 = btile * 64, ub = usup * 32;
    const int usub = w & 1, bsub = w >> 1;       // 2 u-tiles x 4 b-groups
    const int u0t = ub + usub * 16;
    const int grp = role * 8 + btile;
    const int fr = lane & 15, fq = lane >> 4;
    const int u = u0t + fr;
    const int ul = usub * 16 + fr;
    const int coff = role ? 256 : 0;
    ushort* Ws0 = sh + usub * 16384;             // this u-tile's W (64 rows x 256)
    ushort (*hloc)[32] = (ushort(*)[32])(sh + 32768);

    stage_wtile(role ? A.WHpe : A.WHse, HID, u0t, Ws0, lane, bsub);

    const float* b1 = role ? A.pe_b1 : A.se_b1;
    const float* b2 = role ? A.pe_b2 : A.se_b2;
    float bias[4], wxs[4][3];
#pragma unroll
    for (int g = 0; g < 4; ++g) {
        bias[g] = b1[g * HID + u] + b2[g * HID + u];
        wxs[g][0] = wxs[g][1] = wxs[g][2] = 0.0f;
        if (role) {
            wxs[g][0] = A.pe_Wih[(g * HID + u) * 3 + 0];
            wxs[g][1] = A.pe_Wih[(g * HID + u) * 3 + 1];
            wxs[g][2] = A.pe_Wih[(g * HID + u) * 3 + 2];
        }
    }
    float c[4] = {0.f, 0.f, 0.f, 0.f};
    __syncthreads();   // W tile staged (gload_lds drained by barrier semantics)

    for (int t = 0; t < MENC; ++t) {
        float xg[4][4];
#pragma unroll
        for (int r = 0; r < 4; ++r) {
            const int b = b0 + bsub * 16 + fq * 4 + r;
            if (role) {
                const float* xp = A.enc_pos + ((size_t)b * MENC + t) * 3;
                xg[r][0] = xp[0]; xg[r][1] = xp[1]; xg[r][2] = xp[2]; xg[r][3] = 0.f;
            } else {
#pragma unroll
                for (int g = 0; g < 4; ++g)
                    xg[r][g] = A.xg_se[((size_t)b * MENC + t) * 1024 + g * HID + u];
            }
        }
        if (t > 0) gbar_wait(A.bar + grp * MENC + (t - 1), 8);
        f32x4 acc[4] = {};
        if (t > 0)
            cell_g(A.conc + ((size_t)(t - 1) * 512 + b0 + bsub * 16) * 512 + coff, 512,
                   Ws0, acc, lane);
#pragma unroll
        for (int r = 0; r < 4; ++r) {
            const int bl = bsub * 16 + fq * 4 + r;
            const int b = b0 + bl;
            float gv[4];
#pragma unroll
            for (int g = 0; g < 4; ++g) {
                float v = acc[g][r] + bias[g];
                if (role) v += xg[r][0] * wxs[g][0] + xg[r][1] * wxs[g][1] + xg[r][2] * wxs[g][2];
                else      v += xg[r][g];
                gv[g] = v;
            }
            const float cn = sigmf(gv[1]) * c[r] + sigmf(gv[0]) * tanhf(gv[2]);
            const float hn = sigmf(gv[3]) * tanhf(cn);
            c[r] = cn;
            hloc[bl][ul] = f2bf(hn);
            if (t == MENC - 1) (role ? A.PE_C : A.SE_C)[(size_t)b * HID + u] = cn;
        }
        __syncthreads();   // hloc complete
        {
            const int row = tid >> 3, c8 = tid & 7;
            const unsigned long long v = *(const unsigned long long*)&hloc[row][c8 * 4];
            st_u64(A.conc + ((size_t)t * 512 + b0 + row) * 512 + coff + ub + c8 * 4, v);
        }
        if (t != MENC - 1) gbar_arrive(A.bar + grp * MENC + t);
    }
}

// ---------------- 128x128 bf16 MFMA GEMM (small shapes) ----------------
__global__ __launch_bounds__(256)
void gemm_mfma_bt(const ushort* __restrict__ A, const ushort* __restrict__ W,
                  float* __restrict__ C, int M, int N, int K,
                  int lda, int ldw, int ldc, const float* __restrict__ rbias)
{
    __shared__ ushort As[128 * 32];
    __shared__ ushort Bs[128 * 32];
    const int t    = threadIdx.x;
    const int lane = t & 63, wid = t >> 6;
    const int m0 = blockIdx.y * 128, n0 = blockIdx.x * 128;
    const int wr = wid >> 1, wc = wid & 1;

    f32x4 acc[4][4] = {};

    const int sr = wid * 16 + (lane >> 2);
    const int su = ((lane & 3) ^ ((lane >> 3) & 3)) * 8;
    const ushort* Ag = A + (size_t)(m0 + sr) * lda + su;
    const ushort* Wg = W + (size_t)(n0 + sr) * ldw + su;
    ushort* Al = As + wid * 512;
    ushort* Bl = Bs + wid * 512;

    const int fr = lane & 15;
    const int fq = lane >> 4;
    const int sw = (fr >> 1) & 3;

    for (int k0 = 0; k0 < K; k0 += 32) {
        GLOAD_LDS(Ag,                    Al);
        GLOAD_LDS(Ag + (size_t)64 * lda, Al + 2048);
        GLOAD_LDS(Wg,                    Bl);
        GLOAD_LDS(Wg + (size_t)64 * ldw, Bl + 2048);
        Ag += 32; Wg += 32;
        __syncthreads();

        bf16x8 af[4], bfr[4];
#pragma unroll
        for (int m = 0; m < 4; ++m)
            af[m] = *(const bf16x8*)(As + (wr * 64 + m * 16 + fr) * 32 + (fq ^ sw) * 8);
#pragma unroll
        for (int n = 0; n < 4; ++n)
            bfr[n] = *(const bf16x8*)(Bs + (wc * 64 + n * 16 + fr) * 32 + (fq ^ sw) * 8);
#pragma unroll
        for (int m = 0; m < 4; ++m)
#pragma unroll
            for (int n = 0; n < 4; ++n)
                acc[m][n] = __builtin_amdgcn_mfma_f32_16x16x32_bf16(af[m], bfr[n], acc[m][n], 0, 0, 0);
        __syncthreads();
    }

    const int cl = lane & 15, ch = lane >> 4;
#pragma unroll
    for (int m = 0; m < 4; ++m)
#pragma unroll
        for (int n = 0; n < 4; ++n)
#pragma unroll
            for (int r = 0; r < 4; ++r) {
                const int mm = m0 + wr * 64 + m * 16 + ch * 4 + r;
                const int nn = n0 + wc * 64 + n * 16 + cl;
                float v = acc[m][n][r];
                if (rbias) v += rbias[(size_t)(mm & 511) * ldc + nn];
                C[(size_t)mm * ldc + nn] = v;
            }
}

// ---------------- fp32 tiled GEMM (GBIAS one-off) ----------------
__global__ __launch_bounds__(256)
void gemm_tn(const float* __restrict__ A, const float* __restrict__ W,
             const float* __restrict__ b1, const float* __restrict__ b2,
             float* __restrict__ C,
             int M, int N, int K, int lda, int ldw, int ldc)
{
    __shared__ float AsT[16][68];
    __shared__ float WsT[16][68];
    const int t  = threadIdx.x;
    const int tx = t & 15, ty = t >> 4;
    const int m0 = blockIdx.y * 64, n0 = blockIdx.x * 64;
    const int lr = t >> 2;
    const int c4 = t & 3;

    float acc[4][4];
#pragma unroll
    for (int i = 0; i < 4; ++i)
#pragma unroll
        for (int j = 0; j < 4; ++j) acc[i][j] = 0.0f;

    for (int k0 = 0; k0 < K; k0 += 16) {
        float a[4], w[4];
        const int kb = k0 + c4 * 4;
#pragma unroll
        for (int k = 0; k < 4; ++k) {
            a[k] = (kb + k < K) ? A[(size_t)(m0 + lr) * lda + kb + k] : 0.0f;
            w[k] = (kb + k < K) ? W[(size_t)(n0 + lr) * ldw + kb + k] : 0.0f;
        }
        __syncthreads();
#pragma unroll
        for (int k = 0; k < 4; ++k) {
            AsT[c4 * 4 + k][lr] = a[k];
            WsT[c4 * 4 + k][lr] = w[k];
        }
        __syncthreads();
#pragma unroll
        for (int kk = 0; kk < 16; ++kk) {
            const float4 av = *(const float4*)&AsT[kk][ty * 4];
            const float4 wv = *(const float4*)&WsT[kk][tx * 4];
            acc[0][0] += av.x * wv.x; acc[0][1] += av.x * wv.y; acc[0][2] += av.x * wv.z; acc[0][3] += av.x * wv.w;
            acc[1][0] += av.y * wv.x; acc[1][1] += av.y * wv.y; acc[1][2] += av.y * wv.z; acc[1][3] += av.y * wv.w;
            acc[2][0] += av.z * wv.x; acc[2][1] += av.z * wv.y; acc[2][2] += av.z * wv.z; acc[2][3] += av.z * wv.w;
            acc[3][0] += av.w * wv.x; acc[3][1] += av.w * wv.y; acc[3][2] += av.w * wv.z; acc[3][3] += av.w * wv.w;
        }
    }

#pragma unroll
    for (int i = 0; i < 4; ++i) {
        const int m = m0 + ty * 4 + i;
#pragma unroll
        for (int j = 0; j < 4; ++j) {
            const int n = n0 + tx * 4 + j;
            float v = acc[i][j];
            if (b1) v += b1[n];
            if (b2) v += b2[n];
            C[(size_t)m * ldc + n] = v;
        }
    }
}

// ---------------- persistent mid: sd (25) + fe (16) ----------------
struct MidArgs {
    const ushort *WHsd, *WHfe;
    const float  *xg_sd;
    const float  *xg_fe;
    const float  *sd_b1, *sd_b2, *fe_b1, *fe_b2;
    const ushort *conc;
    const float  *SE_C;
    ushort       *SDB;       // [25][512][256]
    ushort       *FEB;       // [16][512][256]
    float        *FEH, *FE_C;
    unsigned int *bar;
};

__global__ __launch_bounds__(1024)
void mid_chain(MidArgs A)
{
    __shared__ ushort Ws[4][64 * 256];
    __shared__ ushort hloc[64][64];
    const int tid = threadIdx.x, lane = tid & 63, w = tid >> 6;
    const int role  = blockIdx.x >> 5;
    const int rem   = blockIdx.x & 31;
    const int btile = rem & 7, usup = rem >> 3;
    const int b0 = btile * 64, ub = usup * 64;
    const int usub = w & 3, bsub = w >> 2;
    const int u0t = ub + usub * 16;
    const int grp = role * 8 + btile;
    const int fr = lane & 15, fq = lane >> 4;
    const int u = u0t + fr;
    const int ul = usub * 16 + fr;
    const int NT = role ? MENC : HWIN;

    stage_wtile(role ? A.WHfe : A.WHsd, HID, u0t, Ws[usub], lane, bsub);

    const float* b1 = role ? A.fe_b1 : A.sd_b1;
    const float* b2 = role ? A.fe_b2 : A.sd_b2;
    float bias[4];
#pragma unroll
    for (int g = 0; g < 4; ++g) bias[g] = b1[g * HID + u] + b2[g * HID + u];

    float c[4];
#pragma unroll
    for (int r = 0; r < 4; ++r) {
        const int b = b0 + bsub * 16 + fq * 4 + r;
        c[r] = role ? 0.0f : A.SE_C[(size_t)b * HID + u];
    }
    __syncthreads();

    for (int t = 0; t < NT; ++t) {
        float xg[4][4];
#pragma unroll
        for (int r = 0; r < 4; ++r) {
            const int b = b0 + bsub * 16 + fq * 4 + r;
#pragma unroll
            for (int g = 0; g < 4; ++g)
                xg[r][g] = role ? A.xg_fe[((size_t)t * 512 + b) * 1024 + g * HID + u]
                                : A.xg_sd[((size_t)b * HWIN + t) * 1024 + g * HID + u];
        }
        if (t > 0) gbar_wait(A.bar + grp * HWIN + (t - 1), 4);
        f32x4 acc[4] = {};
        if (role == 0) {
            if (t == 0) cell_g(A.conc + ((size_t)15 * 512 + b0 + bsub * 16) * 512, 512,
                               Ws[usub], acc, lane);
            else        cell_g(A.SDB + ((size_t)(t - 1) * 512 + b0 + bsub * 16) * HID, HID,
                               Ws[usub], acc, lane);
        } else if (t > 0) {
            cell_g(A.FEB + ((size_t)(t - 1) * BATCH + b0 + bsub * 16) * HID, HID,
                   Ws[usub], acc, lane);
        }
#pragma unroll
        for (int r = 0; r < 4; ++r) {
            const int bl = bsub * 16 + fq * 4 + r;
            const int b = b0 + bl;
            float gv[4];
#pragma unroll
            for (int g = 0; g < 4; ++g)
                gv[g] = acc[g][r] + bias[g] + xg[r][g];
            const float cn = sigmf(gv[1]) * c[r] + sigmf(gv[0]) * tanhf(gv[2]);
            const float hn = sigmf(gv[3]) * tanhf(cn);
            c[r] = cn;
            hloc[bl][ul] = f2bf(hn);
            if (role == 1 && t == MENC - 1) {
                A.FEH[(size_t)b * HID + u] = hn;
                A.FE_C[(size_t)b * HID + u] = cn;
            }
        }
        __syncthreads();
        {
            const int row = tid >> 4, c8 = tid & 15;
            const unsigned long long v = *(const unsigned long long*)&hloc[row][c8 * 4];
            ushort* dst = role ? (A.FEB + ((size_t)t * BATCH + b0 + row) * 256 + ub + c8 * 4)
                               : (A.SDB + ((size_t)t * 512 + b0 + row) * 256 + ub + c8 * 4);
            st_u64(dst, v);
        }
        if (t != NT - 1) gbar_arrive(A.bar + grp * HWIN + t);
    }
}

// ---------------- persistent decoder: pd + fd + tail, 25 steps ----------------
struct DecArgs {
    const ushort *WHpd;
    const ushort *WFDh;
    const ushort *peF;
    const float  *PE_C, *FE_C;
    const float  *xh2;
    const float  *pd_b1, *pd_b2, *pd_Wih;
    const float  *G, *c3, *dec_pos;
    ushort       *H1;        // [25][512][256]
    float        *DELTA;     // [25][512][3], pre-zeroed
    float        *out;       // [512][25][3]
    unsigned int *bar;       // 8 groups x 50
};

__global__ __launch_bounds__(512)
void dec_chain(DecArgs A)
{
    __shared__ ushort Wpd[2][64 * 256], Wfd[2][64 * 256];
    __shared__ ushort hloc[64][32];
    __shared__ float pred_lds[192];
    const int tid = threadIdx.x, lane = tid & 63, w = tid >> 6;
    const int btile = blockIdx.x & 7, usup = blockIdx.x >> 3;
    const int b0 = btile * 64, ub = usup * 32;
    const int usub = w & 1, bsub = w >> 1;
    const int u0t = ub + usub * 16;
    const int fr = lane & 15, fq = lane >> 4;
    const int u = u0t + fr;
    const int ul = usub * 16 + fr;
    unsigned int* bars = A.bar + btile * 2 * HWIN;

    stage_wtile(A.WHpd, HID, u0t, Wpd[usub], lane, bsub);
    stage_wtile(A.WFDh, 512, u0t, Wfd[usub], lane, bsub);

    float pdb[4], wxs[4][3], cf[4], c1[4], Gu[3];
#pragma unroll
    for (int g = 0; g < 4; ++g) {
        pdb[g] = A.pd_b1[g * HID + u] + A.pd_b2[g * HID + u];
        wxs[g][0] = A.pd_Wih[(g * HID + u) * 3 + 0];
        wxs[g][1] = A.pd_Wih[(g * HID + u) * 3 + 1];
        wxs[g][2] = A.pd_Wih[(g * HID + u) * 3 + 2];
    }
#pragma unroll
    for (int r = 0; r < 4; ++r) {
        const int b = b0 + bsub * 16 + fq * 4 + r;
        c1[r] = A.PE_C[(size_t)b * HID + u];
        cf[r] = A.FE_C[(size_t)b * HID + u];
    }
    Gu[0] = A.G[0 * HID + u]; Gu[1] = A.G[1 * HID + u]; Gu[2] = A.G[2 * HID + u];
    const float c3r = (tid < 192) ? A.c3[tid % 3] : 0.0f;
    if (tid < 192) pred_lds[tid] = A.dec_pos[(size_t)(b0 + tid / 3) * 3 + tid % 3];
    __syncthreads();

    for (int t = 0; t < HWIN; ++t) {
        f32x4 acc[4] = {};
        if (t == 0) cell_g(A.peF + (size_t)(b0 + bsub * 16) * 512, 512, Wpd[usub], acc, lane);
        else        cell_g(A.H1 + ((size_t)(t - 1) * BATCH + b0 + bsub * 16) * HID, HID,
                           Wpd[usub], acc, lane);
        if (t > 0) {
            gbar_wait(bars + 2 * (t - 1) + 1, 8);
            if (tid < 192) {
                pred_lds[tid] += A.DELTA[((size_t)(t - 1) * 512 + b0 + tid / 3) * 3 + tid % 3] + c3r;
                if (usup == 0)
                    A.out[((size_t)(b0 + tid / 3) * HWIN + (t - 1)) * 3 + tid % 3] = pred_lds[tid];
            }
            __syncthreads();
        }
#pragma unroll
        for (int r = 0; r < 4; ++r) {
            const int bl = bsub * 16 + fq * 4 + r;
            const float x0 = pred_lds[bl * 3 + 0];
            const float x1 = pred_lds[bl * 3 + 1];
            const float x2 = pred_lds[bl * 3 + 2];
            float gv[4];
#pragma unroll
            for (int g = 0; g < 4; ++g)
                gv[g] = acc[g][r] + pdb[g] + x0 * wxs[g][0] + x1 * wxs[g][1] + x2 * wxs[g][2];
            const float cn = sigmf(gv[1]) * c1[r] + sigmf(gv[0]) * tanhf(gv[2]);
            const float hn = sigmf(gv[3]) * tanhf(cn);
            c1[r] = cn;
            hloc[bl][ul] = f2bf(hn);
        }
        __syncthreads();
        {
            const int row = tid >> 3, c8 = tid & 7;
            const unsigned long long v = *(const unsigned long long*)&hloc[row][c8 * 4];
            st_u64(A.H1 + ((size_t)t * BATCH + b0 + row) * 256 + ub + c8 * 4, v);
        }
        gbar_arrive(bars + 2 * t);
        float xh[4][4];
#pragma unroll
        for (int r = 0; r < 4; ++r) {
            const int b = b0 + bsub * 16 + fq * 4 + r;
#pragma unroll
            for (int g = 0; g < 4; ++g)
                xh[r][g] = A.xh2[((size_t)t * 512 + b) * 1024 + g * HID + u];
        }
        gbar_wait(bars + 2 * t, 8);
        {
            f32x4 accB[4] = {};
            cell_g(A.H1 + ((size_t)t * BATCH + b0 + bsub * 16) * HID, HID,
                   Wfd[usub], accB, lane);
#pragma unroll
            for (int r = 0; r < 4; ++r) {
                const int b = b0 + bsub * 16 + fq * 4 + r;
                float gv[4];
#pragma unroll
                for (int g = 0; g < 4; ++g)
                    gv[g] = accB[g][r] + xh[r][g];
                const float cn = sigmf(gv[1]) * cf[r] + sigmf(gv[0]) * tanhf(gv[2]);
                const float hn = sigmf(gv[3]) * tanhf(cn);
                float p0 = hn * Gu[0], p1 = hn * Gu[1], p2 = hn * Gu[2];
#pragma unroll
                for (int s = 1; s < 16; s <<= 1) {
                    p0 += __shfl_xor(p0, s);
                    p1 += __shfl_xor(p1, s);
                    p2 += __shfl_xor(p2, s);
                }
                if (fr == 0) {
                    float* d = A.DELTA + ((size_t)t * 512 + b) * 3;
                    atomicAdd(d + 0, p0); atomicAdd(d + 1, p1); atomicAdd(d + 2, p2);
                }
            }
        }
        gbar_arrive(bars + 2 * t + 1);
    }
    gbar_wait(bars + 2 * (HWIN - 1) + 1, 8);
    if (tid < 192) {
        pred_lds[tid] += A.DELTA[((size_t)(HWIN - 1) * 512 + b0 + tid / 3) * 3 + tid % 3] + c3r;
        if (usup == 0)
            A.out[((size_t)(b0 + tid / 3) * HWIN + (HWIN - 1)) * 3 + tid % 3] = pred_lds[tid];
    }
}

// ---------------- G = out_W @ f2_W, c3 = out_b + out_W @ f2_b ----------------
__global__ __launch_bounds__(256)
void precompute_G(const float* __restrict__ f2W, const float* __restrict__ f2b,
                  const float* __restrict__ outW, const float* __restrict__ outb,
                  float* __restrict__ G, float* __restrict__ c3)
{
    const int k = threadIdx.x;
    float g0 = 0.f, g1 = 0.f, g2 = 0.f;
    for (int n = 0; n < HID; ++n) {
        const float w = f2W[n * HID + k];
        g0 += outW[n] * w;
        g1 += outW[HID + n] * w;
        g2 += outW[2 * HID + n] * w;
    }
    G[k] = g0; G[HID + k] = g1; G[2 * HID + k] = g2;
    if (k < 3) {
        float s = outb[k];
        for (int n = 0; n < HID; ++n) s += outW[k * HID + n] * f2b[n];
        c3[k] = s;
    }
}

extern "C" void kernel_launch(void* const* d_in, const int* in_sizes, int n_in,
                              void* d_out, int out_size, void* d_ws, size_t ws_size,
                              hipStream_t stream)
{
    (void)in_sizes; (void)n_in; (void)out_size; (void)ws_size;
    const float* enc_pos = (const float*)d_in[0];
    const float* enc_sal = (const float*)d_in[1];
    const float* dec_pos = (const float*)d_in[2];
    const float* dec_sal = (const float*)d_in[3];
    const float *pe_Wih = (const float*)d_in[4],  *pe_Whh = (const float*)d_in[5],
                *pe_bih = (const float*)d_in[6],  *pe_bhh = (const float*)d_in[7];
    const float *se_Wih = (const float*)d_in[8],  *se_Whh = (const float*)d_in[9],
                *se_bih = (const float*)d_in[10], *se_bhh = (const float*)d_in[11];
    const float *fe_Wih = (const float*)d_in[12], *fe_Whh = (const float*)d_in[13],
                *fe_bih = (const float*)d_in[14], *fe_bhh = (const float*)d_in[15];
    const float *pd_Wih = (const float*)d_in[16], *pd_Whh = (const float*)d_in[17],
                *pd_bih = (const float*)d_in[18], *pd_bhh = (const float*)d_in[19];
    const float *sd_Wih = (const float*)d_in[20], *sd_Whh = (const float*)d_in[21],
                *sd_bih = (const float*)d_in[22], *sd_bhh = (const float*)d_in[23];
    const float *fd_Wih = (const float*)d_in[24], *fd_Whh = (const float*)d_in[25],
                *fd_bih = (const float*)d_in[26], *fd_bhh = (const float*)d_in[27];
    const float *f2_W = (const float*)d_in[28], *f2_b = (const float*)d_in[29];
    const float *out_W = (const float*)d_in[30], *out_b = (const float*)d_in[31];
    float* out = (float*)d_out;
    float* ws  = (float*)d_ws;

    size_t off = 0;
    float* XG_SE = ws + off; off += (size_t)8192 * 1024;
    float* XG_FE = ws + off; off += (size_t)8192 * 1024;
    float* BIG   = ws + off; off += (size_t)12800 * 1024;
    float* BIG2  = ws + off; off += (size_t)12800 * 1024;
    float* GBIAS = ws + off; off += (size_t)BATCH * 1024;
    float* PE_C  = ws + off; off += BH;
    float* SE_C  = ws + off; off += BH;
    float* FE_C  = ws + off; off += BH;
    float* FEH   = ws + off; off += BH;
    float* Gm    = ws + off; off += 1024;
    float* C3    = ws + off; off += 8;
    float* DELTA = ws + off; off += (size_t)HWIN * BATCH * 3 + 64;
    unsigned int* BAR = (unsigned int*)(ws + off); off += 1280;
    ushort* WSE  = (ushort*)(ws + off); off += ((size_t)1024 * 4096) / 2;
    ushort* WSD  = (ushort*)(ws + off); off += ((size_t)1024 * 4096) / 2;
    ushort* WFE  = (ushort*)(ws + off); off += ((size_t)1024 * 512) / 2;
    ushort* WFD  = (ushort*)(ws + off); off += ((size_t)1024 * 512) / 2;
    ushort* WHpe = (ushort*)(ws + off); off += ((size_t)1024 * 256) / 2;
    ushort* WHse = (ushort*)(ws + off); off += ((size_t)1024 * 256) / 2;
    ushort* WHfe = (ushort*)(ws + off); off += ((size_t)1024 * 256) / 2;
    ushort* WHsd = (ushort*)(ws + off); off += ((size_t)1024 * 256) / 2;
    ushort* WHpd = (ushort*)(ws + off); off += ((size_t)1024 * 256) / 2;
    ushort* CONC = (ushort*)(ws + off); off += ((size_t)MENC * 512 * 512) / 2;
    ushort* SDB  = (ushort*)(ws + off); off += ((size_t)HWIN * BH) / 2;
    ushort* FEB  = (ushort*)(ws + off); off += ((size_t)MENC * BH) / 2;
    ushort* H1   = (ushort*)(ws + off); off += ((size_t)HWIN * BH) / 2;

    // DELTA and BAR contiguous: one memset
    hipMemsetAsync(DELTA, 0, ((size_t)HWIN * BATCH * 3 + 64 + 1280) * 4, stream);

    auto mgemm = [&](const ushort* A, const ushort* W, float* C,
                     int M, int N, int K, int lda, int ldw, int ldc, const float* rb) {
        gemm_mfma_bt<<<dim3(N / 128, M / 128), 256, 0, stream>>>(A, W, C, M, N, K, lda, ldw, ldc, rb);
    };

    // ---- all 9 weight conversions in ONE launch ----
    {
        Cvt9 a;
        const float* srcs[9] = { se_Wih, sd_Wih, fe_Wih, fd_Wih, pe_Whh, se_Whh, fe_Whh, sd_Whh, pd_Whh };
        ushort*      dsts[9] = { WSE,    WSD,    WFE,    WFD,    WHpe,   WHse,   WHfe,   WHsd,   WHpd };
        const int    n4s[9]  = { 1024*4096/4, 1024*4096/4, 1024*512/4, 1024*512/4,
                                 1024*256/4, 1024*256/4, 1024*256/4, 1024*256/4, 1024*256/4 };
        int acc9 = 0;
        for (int i = 0; i < 9; ++i) { a.s[i] = srcs[i]; a.d[i] = dsts[i]; acc9 += n4s[i]; a.end[i] = acc9; }
        cvt_multi<<<(acc9 + 255) / 256, 256, 0, stream>>>(a);
    }
    precompute_G<<<1, 256, 0, stream>>>(f2_W, f2_b, out_W, out_b, Gm, C3);

    // ---- se x-proj (alone) ----
    gemm128f<<<512, 512, 0, stream>>>(enc_sal, WSE, XG_SE, 8, 512);

    // ---- MERGED: encoder chains (128 blocks) + sd x-proj GEMM (800 blocks) ----
    {
        EncArgs a;
        a.WHse = WHse; a.WHpe = WHpe; a.xg_se = XG_SE; a.enc_pos = enc_pos;
        a.se_b1 = se_bih; a.se_b2 = se_bhh; a.pe_b1 = pe_bih; a.pe_b2 = pe_bhh;
        a.pe_Wih = pe_Wih; a.conc = CONC; a.SE_C = SE_C; a.PE_C = PE_C;
        a.bar = BAR;
        enc_sd<<<928, 512, 0, stream>>>(a, dec_sal, WSD, BIG);
    }

    // ---- fe x-proj (rows t,b) ----
    mgemm(CONC, WFE, XG_FE, 8192, 1024, 512, 512, 512, 1024, nullptr);

    // ---- persistent mid (sd + fe): 64 blocks x 1024 ----
    {
        MidArgs a;
        a.WHsd = WHsd; a.WHfe = WHfe; a.xg_sd = BIG; a.xg_fe = XG_FE;
        a.sd_b1 = sd_bih; a.sd_b2 = sd_bhh; a.fe_b1 = fe_bih; a.fe_b2 = fe_bhh;
        a.conc = CONC; a.SE_C = SE_C; a.SDB = SDB; a.FEB = FEB;
        a.FEH = FEH; a.FE_C = FE_C; a.bar = BAR + 256;
        mid_chain<<<64, 1024, 0, stream>>>(a);
    }

    // ---- fd precomputations ----
    gemm_tn<<<dim3(16, 8), 256, 0, stream>>>(FEH, fd_Whh, fd_bih, fd_bhh, GBIAS,
                                             BATCH, 1024, HID, HID, HID, 1024);
    mgemm(SDB, WFD, BIG2, 12800, 1024, HID, HID, 512, 1024, GBIAS);

    // ---- persistent decoder (pd + fd + tail): 64 blocks x 512 ----
    {
        DecArgs a;
        a.WHpd = WHpd; a.WFDh = WFD + 256;
        a.peF = CONC + ((size_t)15 * 512) * 512 + 256;
        a.PE_C = PE_C; a.FE_C = FE_C; a.xh2 = BIG2;
        a.pd_b1 = pd_bih; a.pd_b2 = pd_bhh; a.pd_Wih = pd_Wih;
        a.G = Gm; a.c3 = C3; a.dec_pos = dec_pos;
        a.H1 = H1; a.DELTA = DELTA; a.out = out; a.bar = BAR + 656;
        dec_chain<<<64, 512, 0, stream>>>(a);
    }
}

// Round 22
// 964.078 us; speedup vs baseline: 1.2572x; 1.0717x over previous
//
#include <hip/hip_runtime.h>

#define HID 256
#define BATCH 512
#define MENC 16
#define HWIN 25
#define SALSZ 4096
#define BH (BATCH * HID)   // 131072

typedef __attribute__((ext_vector_type(8))) short bf16x8;
typedef __attribute__((ext_vector_type(4))) float f32x4;

__device__ __forceinline__ float sigmf(float x) { return 1.0f / (1.0f + __expf(-x)); }
__device__ __forceinline__ ushort f2bf(float f) {
    uint32_t u = __float_as_uint(f);
    return (ushort)((u + 0x7fffu + ((u >> 16) & 1u)) >> 16);   // RNE
}

#define GLOAD_LDS(gp, lp) \
    __builtin_amdgcn_global_load_lds((const __attribute__((address_space(1))) void*)(gp), \
                                     (__attribute__((address_space(3))) void*)(lp), 16, 0, 0)

// ---- write-through stores for cross-block exchange (L3-visible; R7/R10-proven) ----
__device__ __forceinline__ void st_u64(void* p, unsigned long long v) {
    __hip_atomic_store((unsigned long long*)p, v, __ATOMIC_RELAXED, __HIP_MEMORY_SCOPE_AGENT);
}
__device__ __forceinline__ void st_f32(float* p, float v) {
    __hip_atomic_store(p, v, __ATOMIC_RELAXED, __HIP_MEMORY_SCOPE_AGENT);
}

// ---- split fence-free barrier (R14-proven) ----
__device__ __forceinline__ void gbar_arrive(unsigned int* slot)
{
    __syncthreads();    // drains vmcnt: this block's stores are L3-acked
    if (threadIdx.x == 0) atomicAdd(slot, 1u);
}
__device__ __forceinline__ void gbar_wait(unsigned int* slot, unsigned int nblk)
{
    if (threadIdx.x == 0) {
        while (__hip_atomic_load(slot, __ATOMIC_RELAXED, __HIP_MEMORY_SCOPE_AGENT) < nblk)
            __builtin_amdgcn_s_sleep(1);
    }
    __syncthreads();
}

// ---- W tile staging for chains: [64][256] bf16, XOR-swizzled 16B units ----
__device__ __forceinline__ void stage_wtile(const ushort* Wsrc, int ldw, int u0,
                                            ushort* lds, int lane, int wq)
{
    const int sub = lane >> 5, uu = lane & 31;
#pragma unroll
    for (int i = 0; i < 8; ++i) {
        const int row = i * 8 + wq * 2 + sub;
        const int su  = uu ^ (row & 7);
        const int gr  = (row >> 4) * HID + u0 + (row & 15);
        GLOAD_LDS(Wsrc + (size_t)gr * ldw + su * 8, lds + i * 2048 + wq * 512);
    }
}

// ---- chain cell quarter: H from global, W from swizzled LDS; 32 MFMA/wave ----
__device__ __forceinline__ void cell_g(const ushort* hrow0, int ldh,
                                       const ushort* WsL, f32x4 acc[4], int lane)
{
    const int fr = lane & 15, fq = lane >> 4;
    const ushort* hrow = hrow0 + (size_t)fr * ldh;
#pragma unroll
    for (int ks = 0; ks < 8; ++ks) {
        const bf16x8 af = *(const bf16x8*)(hrow + ks * 32 + fq * 8);
#pragma unroll
        for (int g = 0; g < 4; ++g) {
            const int vr = g * 16 + fr;
            const bf16x8 bf = *(const bf16x8*)(WsL + vr * 256 + (((ks * 4 + fq)) ^ (vr & 7)) * 8);
            acc[g] = __builtin_amdgcn_mfma_f32_16x16x32_bf16(af, bf, acc[g], 0, 0, 0);
        }
    }
}

// ---------------- fp32 -> bf16, 9 weight segments in one launch ----------------
struct Cvt9 {
    const float* s[9];
    ushort*      d[9];
    int          end[9];
};
__global__ __launch_bounds__(256)
void cvt_multi(Cvt9 A)
{
    int i = blockIdx.x * 256 + threadIdx.x;
    if (i >= A.end[8]) return;
    int seg = 0, beg = 0;
#pragma unroll
    for (int k = 0; k < 8; ++k)
        if (i >= A.end[k]) { seg = k + 1; beg = A.end[k]; }
    const int j = i - beg;
    const float4 v = *(const float4*)(A.s[seg] + (size_t)j * 4);
    *(ushort4*)(A.d[seg] + (size_t)j * 4) = make_ushort4(f2bf(v.x), f2bf(v.y), f2bf(v.z), f2bf(v.w));
}

// ======== 128x128 GEMM body, BK=64; fused fp32->bf16 A (R20-verified) ========
__device__ __forceinline__ void loadA128(const float* Ag, int lda, int tid, float4 ra[4])
{
#pragma unroll
    for (int j = 0; j < 2; ++j) {
        const int idx = j * 512 + tid;
        const int row = idx >> 3, u = idx & 7;
        const int su = (u ^ (row & 7)) * 8;
        ra[2 * j + 0] = *(const float4*)(Ag + (size_t)row * lda + su);
        ra[2 * j + 1] = *(const float4*)(Ag + (size_t)row * lda + su + 4);
    }
}
__device__ __forceinline__ void writeA128(const float4 ra[4], ushort* Al, int tid)
{
#pragma unroll
    for (int j = 0; j < 2; ++j) {
        const int idx = j * 512 + tid;
        uint4 v;
        v.x = (uint)f2bf(ra[2 * j].x) | ((uint)f2bf(ra[2 * j].y) << 16);
        v.y = (uint)f2bf(ra[2 * j].z) | ((uint)f2bf(ra[2 * j].w) << 16);
        v.z = (uint)f2bf(ra[2 * j + 1].x) | ((uint)f2bf(ra[2 * j + 1].y) << 16);
        v.w = (uint)f2bf(ra[2 * j + 1].z) | ((uint)f2bf(ra[2 * j + 1].w) << 16);
        *(uint4*)(Al + idx * 8) = v;
    }
}
__device__ __forceinline__ void stageB128(const ushort* Bg, int ldw, ushort* Bl, int tid)
{
#pragma unroll
    for (int j = 0; j < 2; ++j) {
        const int idx = j * 512 + tid;
        const int row = idx >> 3, u = idx & 7;
        const int su = (u ^ (row & 7)) * 8;
        GLOAD_LDS(Bg + (size_t)row * ldw + su, Bl + idx * 8);
    }
}

__device__ __forceinline__ void gemm128f_body(
    const float* __restrict__ A, const ushort* __restrict__ W, float* __restrict__ C,
    int lda, int ldw, int ldc, int K, int gx, int nwg, int bid,
    ushort* AsB, ushort* BsB, int tid)
{
    const int lane = tid & 63, wid = tid >> 6;
    {   // bijective XCD-chunked swizzle within this job's sub-grid
        const int q = nwg >> 3, r = nwg & 7;
        const int xcd = bid & 7, o = bid >> 3;
        bid = (xcd < r) ? xcd * (q + 1) + o : r * (q + 1) + (xcd - r) * q + o;
    }
    const int m0 = (bid / gx) * 128, n0 = (bid % gx) * 128;

    const int wr = wid >> 1, wc = wid & 1;     // 4m x 2n wave grid
    const int fr = lane & 15, fq = lane >> 4;

    f32x4 acc[2][4] = {};
    const int nt = K / 64;
    const float*  Ab0 = A + (size_t)m0 * lda;
    const ushort* Bb0 = W + (size_t)n0 * ldw;

    float4 ra[4];
    loadA128(Ab0, lda, tid, ra);
    stageB128(Bb0, ldw, BsB, tid);
    writeA128(ra, AsB, tid);
    loadA128(Ab0 + 64, lda, tid, ra);
    asm volatile("s_waitcnt vmcnt(4) lgkmcnt(0)" ::: "memory");
    __builtin_amdgcn_sched_barrier(0);
    __builtin_amdgcn_s_barrier();
    __builtin_amdgcn_sched_barrier(0);

    for (int t = 0; t < nt; ++t) {
        const int p = t & 1;
        const int t1 = (t + 1 < nt) ? t + 1 : nt - 1;
        const int t2 = (t + 2 < nt) ? t + 2 : nt - 1;
        stageB128(Bb0 + t1 * 64, ldw, BsB + (p ^ 1) * 8192, tid);
        writeA128(ra, AsB + (p ^ 1) * 8192, tid);
        loadA128(Ab0 + t2 * 64, lda, tid, ra);

        const ushort* Ab = AsB + p * 8192;
        const ushort* Bb = BsB + p * 8192;
#pragma unroll
        for (int ks = 0; ks < 2; ++ks) {
            bf16x8 bfr[4];
#pragma unroll
            for (int nf = 0; nf < 4; ++nf) {
                const int row = wc * 64 + nf * 16 + fr;
                bfr[nf] = *(const bf16x8*)(Bb + row * 64 + ((ks * 4 + fq) ^ (row & 7)) * 8);
            }
            bf16x8 af[2];
#pragma unroll
            for (int mf = 0; mf < 2; ++mf) {
                const int row = wr * 32 + mf * 16 + fr;
                af[mf] = *(const bf16x8*)(Ab + row * 64 + ((ks * 4 + fq) ^ (row & 7)) * 8);
            }
            __builtin_amdgcn_s_setprio(1);
#pragma unroll
            for (int mf = 0; mf < 2; ++mf)
#pragma unroll
                for (int nf = 0; nf < 4; ++nf)
                    acc[mf][nf] = __builtin_amdgcn_mfma_f32_16x16x32_bf16(
                        af[mf], bfr[nf], acc[mf][nf], 0, 0, 0);
            __builtin_amdgcn_s_setprio(0);
        }
        if (t == nt - 1) break;
        asm volatile("s_waitcnt vmcnt(4) lgkmcnt(0)" ::: "memory");
        __builtin_amdgcn_sched_barrier(0);
        __builtin_amdgcn_s_barrier();
        __builtin_amdgcn_sched_barrier(0);
    }

    const int cl = lane & 15, ch = lane >> 4;
#pragma unroll
    for (int mf = 0; mf < 2; ++mf)
#pragma unroll
        for (int nf = 0; nf < 4; ++nf)
#pragma unroll
            for (int r = 0; r < 4; ++r)
                C[(size_t)(m0 + wr * 32 + mf * 16 + ch * 4 + r) * ldc
                  + n0 + wc * 64 + nf * 16 + cl] = acc[mf][nf][r];
}

__global__ __launch_bounds__(512, 4)
void gemm128f(const float* __restrict__ A, const ushort* __restrict__ W,
              float* __restrict__ C, int gx, int nwg)
{
    __shared__ ushort As[2 * 128 * 64];
    __shared__ ushort Bs[2 * 128 * 64];
    gemm128f_body(A, W, C, SALSZ, SALSZ, 1024, SALSZ, gx, nwg, blockIdx.x, As, Bs, threadIdx.x);
}

// ======== 128x128 GEMM body, bf16 A and B, 2-phase; write-through C + slice flag ========
__device__ __forceinline__ void gemm128b_body(
    const ushort* __restrict__ A, const ushort* __restrict__ W, float* __restrict__ C,
    int lda, int ldw, int ldc, int K, int gx, int nwg, int bid,
    const float* __restrict__ rbias, unsigned int* flag,
    ushort* AsB, ushort* BsB, int tid)
{
    const int lane = tid & 63, wid = tid >> 6;
    {   // bijective XCD-chunked swizzle
        const int q = nwg >> 3, r = nwg & 7;
        const int xcd = bid & 7, o = bid >> 3;
        bid = (xcd < r) ? xcd * (q + 1) + o : r * (q + 1) + (xcd - r) * q + o;
    }
    const int m0 = (bid / gx) * 128, n0 = (bid % gx) * 128;

    const int wr = wid >> 1, wc = wid & 1;
    const int fr = lane & 15, fq = lane >> 4;

    f32x4 acc[2][4] = {};
    const int nt = K / 64;
    const ushort* Ab0 = A + (size_t)m0 * lda;
    const ushort* Bb0 = W + (size_t)n0 * ldw;

    stageB128(Ab0, lda, AsB, tid);
    stageB128(Bb0, ldw, BsB, tid);
    __syncthreads();

    for (int t = 0; t < nt; ++t) {
        const int p = t & 1;
        if (t + 1 < nt) {
            stageB128(Ab0 + (t + 1) * 64, lda, AsB + (p ^ 1) * 8192, tid);
            stageB128(Bb0 + (t + 1) * 64, ldw, BsB + (p ^ 1) * 8192, tid);
        }
        const ushort* Ab = AsB + p * 8192;
        const ushort* Bb = BsB + p * 8192;
#pragma unroll
        for (int ks = 0; ks < 2; ++ks) {
            bf16x8 bfr[4];
#pragma unroll
            for (int nf = 0; nf < 4; ++nf) {
                const int row = wc * 64 + nf * 16 + fr;
                bfr[nf] = *(const bf16x8*)(Bb + row * 64 + ((ks * 4 + fq) ^ (row & 7)) * 8);
            }
            bf16x8 af[2];
#pragma unroll
            for (int mf = 0; mf < 2; ++mf) {
                const int row = wr * 32 + mf * 16 + fr;
                af[mf] = *(const bf16x8*)(Ab + row * 64 + ((ks * 4 + fq) ^ (row & 7)) * 8);
            }
#pragma unroll
            for (int mf = 0; mf < 2; ++mf)
#pragma unroll
                for (int nf = 0; nf < 4; ++nf)
                    acc[mf][nf] = __builtin_amdgcn_mfma_f32_16x16x32_bf16(
                        af[mf], bfr[nf], acc[mf][nf], 0, 0, 0);
        }
        if (t == nt - 1) break;
        __syncthreads();
    }

    const int cl = lane & 15, ch = lane >> 4;
#pragma unroll
    for (int mf = 0; mf < 2; ++mf)
#pragma unroll
        for (int nf = 0; nf < 4; ++nf)
#pragma unroll
            for (int r = 0; r < 4; ++r) {
                const int mm = m0 + wr * 32 + mf * 16 + ch * 4 + r;
                const int nn = n0 + wc * 64 + nf * 16 + cl;
                float v = acc[mf][nf][r];
                if (rbias) v += rbias[(size_t)(mm & 511) * ldc + nn];
                st_f32(C + (size_t)mm * ldc + nn, v);   // write-through (same-kernel readers)
            }
    __syncthreads();   // drain write-throughs
    if (tid == 0) atomicAdd(flag + (m0 >> 9), 1u);
}

// ---------------- merged: encoder chains (0..127) + sd GEMM (128..927) ----------------
struct EncArgs {
    const ushort *WHse, *WHpe;
    const float  *xg_se;
    const float  *enc_pos;
    const float  *se_b1, *se_b2, *pe_b1, *pe_b2;
    const float  *pe_Wih;
    ushort       *conc;      // [16][512][512]
    float        *SE_C, *PE_C;
    unsigned int *bar;       // 16 groups x 16 steps, degree 8
};

__global__ __launch_bounds__(512, 4)
void enc_sd(EncArgs A, const float* __restrict__ sdA, const ushort* __restrict__ sdW,
            float* __restrict__ sdC)
{
    __shared__ ushort sh[34816];
    const int tid = threadIdx.x;

    if (blockIdx.x >= 128) {
        gemm128f_body(sdA, sdW, sdC, SALSZ, SALSZ, 1024, SALSZ, 8, 800,
                      (int)blockIdx.x - 128, sh, sh + 16384, tid);
        return;
    }

    const int lane = tid & 63, w = tid >> 6;
    const int role  = blockIdx.x >> 6;
    const int rem   = blockIdx.x & 63;
    const int btile = rem & 7, usup = rem >> 3;
    const int b0 = btile * 64, ub = usup * 32;
    const int usub = w & 1, bsub = w >> 1;
    const int u0t = ub + usub * 16;
    const int grp = role * 8 + btile;
    const int fr = lane & 15, fq = lane >> 4;
    const int u = u0t + fr;
    const int ul = usub * 16 + fr;
    const int coff = role ? 256 : 0;
    ushort* Ws0 = sh + usub * 16384;
    ushort (*hloc)[32] = (ushort(*)[32])(sh + 32768);

    stage_wtile(role ? A.WHpe : A.WHse, HID, u0t, Ws0, lane, bsub);

    const float* b1 = role ? A.pe_b1 : A.se_b1;
    const float* b2 = role ? A.pe_b2 : A.se_b2;
    float bias[4], wxs[4][3];
#pragma unroll
    for (int g = 0; g < 4; ++g) {
        bias[g] = b1[g * HID + u] + b2[g * HID + u];
        wxs[g][0] = wxs[g][1] = wxs[g][2] = 0.0f;
        if (role) {
            wxs[g][0] = A.pe_Wih[(g * HID + u) * 3 + 0];
            wxs[g][1] = A.pe_Wih[(g * HID + u) * 3 + 1];
            wxs[g][2] = A.pe_Wih[(g * HID + u) * 3 + 2];
        }
    }
    float c[4] = {0.f, 0.f, 0.f, 0.f};
    __syncthreads();

    for (int t = 0; t < MENC; ++t) {
        float xg[4][4];
#pragma unroll
        for (int r = 0; r < 4; ++r) {
            const int b = b0 + bsub * 16 + fq * 4 + r;
            if (role) {
                const float* xp = A.enc_pos + ((size_t)b * MENC + t) * 3;
                xg[r][0] = xp[0]; xg[r][1] = xp[1]; xg[r][2] = xp[2]; xg[r][3] = 0.f;
            } else {
#pragma unroll
                for (int g = 0; g < 4; ++g)
                    xg[r][g] = A.xg_se[((size_t)b * MENC + t) * 1024 + g * HID + u];
            }
        }
        if (t > 0) gbar_wait(A.bar + grp * MENC + (t - 1), 8);
        f32x4 acc[4] = {};
        if (t > 0)
            cell_g(A.conc + ((size_t)(t - 1) * 512 + b0 + bsub * 16) * 512 + coff, 512,
                   Ws0, acc, lane);
#pragma unroll
        for (int r = 0; r < 4; ++r) {
            const int bl = bsub * 16 + fq * 4 + r;
            const int b = b0 + bl;
            float gv[4];
#pragma unroll
            for (int g = 0; g < 4; ++g) {
                float v = acc[g][r] + bias[g];
                if (role) v += xg[r][0] * wxs[g][0] + xg[r][1] * wxs[g][1] + xg[r][2] * wxs[g][2];
                else      v += xg[r][g];
                gv[g] = v;
            }
            const float cn = sigmf(gv[1]) * c[r] + sigmf(gv[0]) * tanhf(gv[2]);
            const float hn = sigmf(gv[3]) * tanhf(cn);
            c[r] = cn;
            hloc[bl][ul] = f2bf(hn);
            if (t == MENC - 1) (role ? A.PE_C : A.SE_C)[(size_t)b * HID + u] = cn;
        }
        __syncthreads();
        {
            const int row = tid >> 3, c8 = tid & 7;
            const unsigned long long v = *(const unsigned long long*)&hloc[row][c8 * 4];
            st_u64(A.conc + ((size_t)t * 512 + b0 + row) * 512 + coff + ub + c8 * 4, v);
        }
        if (t != MENC - 1) gbar_arrive(A.bar + grp * MENC + t);
    }
}

// ---------------- merged: mid chains (0..127) + fe GEMM (128..639) ----------------
struct MidArgs {
    const ushort *WHsd, *WHfe;
    const float  *xg_sd;
    const float  *xg_fe;
    const float  *sd_b1, *sd_b2, *fe_b1, *fe_b2;
    const ushort *conc;
    const float  *SE_C;
    ushort       *SDB;       // [25][512][256]
    ushort       *FEB;       // [16][512][256]
    float        *FEH, *FE_C;
    unsigned int *bar;       // 16 groups x 25 steps, degree 8
    unsigned int *fe_done;   // [16] slice flags (32 blocks each)
};

__global__ __launch_bounds__(512, 4)
void mid_fe(MidArgs A, const ushort* __restrict__ feA, const ushort* __restrict__ feW,
            float* __restrict__ feC)
{
    __shared__ ushort sh[34816];
    const int tid = threadIdx.x;

    if (blockIdx.x >= 128) {
        gemm128b_body(feA, feW, feC, 512, 512, 1024, 512, 8, 512,
                      (int)blockIdx.x - 128, nullptr, A.fe_done, sh, sh + 16384, tid);
        return;
    }

    const int lane = tid & 63, w = tid >> 6;
    const int role  = blockIdx.x >> 6;          // 0 = sd, 1 = fe
    const int rem   = blockIdx.x & 63;
    const int btile = rem & 7, usup = rem >> 3;
    const int b0 = btile * 64, ub = usup * 32;
    const int usub = w & 1, bsub = w >> 1;
    const int u0t = ub + usub * 16;
    const int grp = role * 8 + btile;
    const int fr = lane & 15, fq = lane >> 4;
    const int u = u0t + fr;
    const int ul = usub * 16 + fr;
    const int NT = role ? MENC : HWIN;
    ushort* Ws0 = sh + usub * 16384;
    ushort (*hloc)[32] = (ushort(*)[32])(sh + 32768);

    stage_wtile(role ? A.WHfe : A.WHsd, HID, u0t, Ws0, lane, bsub);

    const float* b1 = role ? A.fe_b1 : A.sd_b1;
    const float* b2 = role ? A.fe_b2 : A.sd_b2;
    float bias[4];
#pragma unroll
    for (int g = 0; g < 4; ++g) bias[g] = b1[g * HID + u] + b2[g * HID + u];

    float c[4];
#pragma unroll
    for (int r = 0; r < 4; ++r) {
        const int b = b0 + bsub * 16 + fq * 4 + r;
        c[r] = role ? 0.0f : A.SE_C[(size_t)b * HID + u];
    }
    __syncthreads();

    for (int t = 0; t < NT; ++t) {
        if (role) gbar_wait(A.fe_done + t, 32);   // XG_FE slice t ready
        float xg[4][4];
#pragma unroll
        for (int r = 0; r < 4; ++r) {
            const int b = b0 + bsub * 16 + fq * 4 + r;
#pragma unroll
            for (int g = 0; g < 4; ++g)
                xg[r][g] = role ? A.xg_fe[((size_t)t * 512 + b) * 1024 + g * HID + u]
                                : A.xg_sd[((size_t)b * HWIN + t) * 1024 + g * HID + u];
        }
        if (t > 0) gbar_wait(A.bar + grp * HWIN + (t - 1), 8);
        f32x4 acc[4] = {};
        if (role == 0) {
            if (t == 0) cell_g(A.conc + ((size_t)15 * 512 + b0 + bsub * 16) * 512, 512,
                               Ws0, acc, lane);
            else        cell_g(A.SDB + ((size_t)(t - 1) * 512 + b0 + bsub * 16) * HID, HID,
                               Ws0, acc, lane);
        } else if (t > 0) {
            cell_g(A.FEB + ((size_t)(t - 1) * BATCH + b0 + bsub * 16) * HID, HID,
                   Ws0, acc, lane);
        }
#pragma unroll
        for (int r = 0; r < 4; ++r) {
            const int bl = bsub * 16 + fq * 4 + r;
            const int b = b0 + bl;
            float gv[4];
#pragma unroll
            for (int g = 0; g < 4; ++g)
                gv[g] = acc[g][r] + bias[g] + xg[r][g];
            const float cn = sigmf(gv[1]) * c[r] + sigmf(gv[0]) * tanhf(gv[2]);
            const float hn = sigmf(gv[3]) * tanhf(cn);
            c[r] = cn;
            hloc[bl][ul] = f2bf(hn);
            if (role == 1 && t == MENC - 1) {
                A.FEH[(size_t)b * HID + u] = hn;
                A.FE_C[(size_t)b * HID + u] = cn;
            }
        }
        __syncthreads();
        {
            const int row = tid >> 3, c8 = tid & 7;
            const unsigned long long v = *(const unsigned long long*)&hloc[row][c8 * 4];
            ushort* dst = role ? (A.FEB + ((size_t)t * BATCH + b0 + row) * 256 + ub + c8 * 4)
                               : (A.SDB + ((size_t)t * 512 + b0 + row) * 256 + ub + c8 * 4);
            st_u64(dst, v);
        }
        if (t != NT - 1) gbar_arrive(A.bar + grp * HWIN + t);
    }
}

// ---------------- fp32 tiled GEMM (GBIAS one-off) ----------------
__global__ __launch_bounds__(256)
void gemm_tn(const float* __restrict__ A, const float* __restrict__ W,
             const float* __restrict__ b1, const float* __restrict__ b2,
             float* __restrict__ C,
             int M, int N, int K, int lda, int ldw, int ldc)
{
    __shared__ float AsT[16][68];
    __shared__ float WsT[16][68];
    const int t  = threadIdx.x;
    const int tx = t & 15, ty = t >> 4;
    const int m0 = blockIdx.y * 64, n0 = blockIdx.x * 64;
    const int lr = t >> 2;
    const int c4 = t & 3;

    float acc[4][4];
#pragma unroll
    for (int i = 0; i < 4; ++i)
#pragma unroll
        for (int j = 0; j < 4; ++j) acc[i][j] = 0.0f;

    for (int k0 = 0; k0 < K; k0 += 16) {
        float a[4], w[4];
        const int kb = k0 + c4 * 4;
#pragma unroll
        for (int k = 0; k < 4; ++k) {
            a[k] = (kb + k < K) ? A[(size_t)(m0 + lr) * lda + kb + k] : 0.0f;
            w[k] = (kb + k < K) ? W[(size_t)(n0 + lr) * ldw + kb + k] : 0.0f;
        }
        __syncthreads();
#pragma unroll
        for (int k = 0; k < 4; ++k) {
            AsT[c4 * 4 + k][lr] = a[k];
            WsT[c4 * 4 + k][lr] = w[k];
        }
        __syncthreads();
#pragma unroll
        for (int kk = 0; kk < 16; ++kk) {
            const float4 av = *(const float4*)&AsT[kk][ty * 4];
            const float4 wv = *(const float4*)&WsT[kk][tx * 4];
            acc[0][0] += av.x * wv.x; acc[0][1] += av.x * wv.y; acc[0][2] += av.x * wv.z; acc[0][3] += av.x * wv.w;
            acc[1][0] += av.y * wv.x; acc[1][1] += av.y * wv.y; acc[1][2] += av.y * wv.z; acc[1][3] += av.y * wv.w;
            acc[2][0] += av.z * wv.x; acc[2][1] += av.z * wv.y; acc[2][2] += av.z * wv.z; acc[2][3] += av.z * wv.w;
            acc[3][0] += av.w * wv.x; acc[3][1] += av.w * wv.y; acc[3][2] += av.w * wv.z; acc[3][3] += av.w * wv.w;
        }
    }

#pragma unroll
    for (int i = 0; i < 4; ++i) {
        const int m = m0 + ty * 4 + i;
#pragma unroll
        for (int j = 0; j < 4; ++j) {
            const int n = n0 + tx * 4 + j;
            float v = acc[i][j];
            if (b1) v += b1[n];
            if (b2) v += b2[n];
            C[(size_t)m * ldc + n] = v;
        }
    }
}

// ---------------- merged: decoder (0..63) + xh2 GEMM (64..863) ----------------
struct DecArgs {
    const ushort *WHpd;
    const ushort *WFDh;
    const ushort *peF;
    const float  *PE_C, *FE_C;
    const float  *xh2;
    const float  *pd_b1, *pd_b2, *pd_Wih;
    const float  *G, *c3, *dec_pos;
    ushort       *H1;        // [25][512][256]
    float        *DELTA;     // [25][512][3], pre-zeroed
    float        *out;       // [512][25][3]
    unsigned int *bar;       // 8 groups x 50
    unsigned int *xh2_done;  // [25] slice flags (32 blocks each)
};

__global__ __launch_bounds__(512)
void dec_xh2(DecArgs A, const ushort* __restrict__ xA, const ushort* __restrict__ xW,
             float* __restrict__ xC, const float* __restrict__ xrb)
{
    __shared__ ushort sh[68096];   // dec: Wpd(32768)+Wfd(32768)+hloc(2048)+pred(512); gemm: 32768
    const int tid = threadIdx.x;

    if (blockIdx.x >= 64) {
        gemm128b_body(xA, xW, xC, 256, 512, 1024, 256, 8, 800,
                      (int)blockIdx.x - 64, xrb, A.xh2_done, sh, sh + 16384, tid);
        return;
    }

    ushort* Wpd0 = sh;
    ushort* Wfd0 = sh + 32768;
    ushort (*hloc)[32] = (ushort(*)[32])(sh + 65536);
    float* pred_lds = (float*)(sh + 67584);

    const int lane = tid & 63, w = tid >> 6;
    const int btile = blockIdx.x & 7, usup = blockIdx.x >> 3;
    const int b0 = btile * 64, ub = usup * 32;
    const int usub = w & 1, bsub = w >> 1;
    const int u0t = ub + usub * 16;
    const int fr = lane & 15, fq = lane >> 4;
    const int u = u0t + fr;
    const int ul = usub * 16 + fr;
    unsigned int* bars = A.bar + btile * 2 * HWIN;

    stage_wtile(A.WHpd, HID, u0t, Wpd0 + usub * 16384, lane, bsub);
    stage_wtile(A.WFDh, 512, u0t, Wfd0 + usub * 16384, lane, bsub);

    float pdb[4], wxs[4][3], cf[4], c1[4], Gu[3];
#pragma unroll
    for (int g = 0; g < 4; ++g) {
        pdb[g] = A.pd_b1[g * HID + u] + A.pd_b2[g * HID + u];
        wxs[g][0] = A.pd_Wih[(g * HID + u) * 3 + 0];
        wxs[g][1] = A.pd_Wih[(g * HID + u) * 3 + 1];
        wxs[g][2] = A.pd_Wih[(g * HID + u) * 3 + 2];
    }
#pragma unroll
    for (int r = 0; r < 4; ++r) {
        const int b = b0 + bsub * 16 + fq * 4 + r;
        c1[r] = A.PE_C[(size_t)b * HID + u];
        cf[r] = A.FE_C[(size_t)b * HID + u];
    }
    Gu[0] = A.G[0 * HID + u]; Gu[1] = A.G[1 * HID + u]; Gu[2] = A.G[2 * HID + u];
    const float c3r = (tid < 192) ? A.c3[tid % 3] : 0.0f;
    if (tid < 192) pred_lds[tid] = A.dec_pos[(size_t)(b0 + tid / 3) * 3 + tid % 3];
    __syncthreads();

    for (int t = 0; t < HWIN; ++t) {
        f32x4 acc[4] = {};
        if (t == 0) cell_g(A.peF + (size_t)(b0 + bsub * 16) * 512, 512,
                           Wpd0 + usub * 16384, acc, lane);
        else        cell_g(A.H1 + ((size_t)(t - 1) * BATCH + b0 + bsub * 16) * HID, HID,
                           Wpd0 + usub * 16384, acc, lane);
        if (t > 0) {
            gbar_wait(bars + 2 * (t - 1) + 1, 8);
            if (tid < 192) {
                pred_lds[tid] += A.DELTA[((size_t)(t - 1) * 512 + b0 + tid / 3) * 3 + tid % 3] + c3r;
                if (usup == 0)
                    A.out[((size_t)(b0 + tid / 3) * HWIN + (t - 1)) * 3 + tid % 3] = pred_lds[tid];
            }
            __syncthreads();
        }
#pragma unroll
        for (int r = 0; r < 4; ++r) {
            const int bl = bsub * 16 + fq * 4 + r;
            const float x0 = pred_lds[bl * 3 + 0];
            const float x1 = pred_lds[bl * 3 + 1];
            const float x2 = pred_lds[bl * 3 + 2];
            float gv[4];
#pragma unroll
            for (int g = 0; g < 4; ++g)
                gv[g] = acc[g][r] + pdb[g] + x0 * wxs[g][0] + x1 * wxs[g][1] + x2 * wxs[g][2];
            const float cn = sigmf(gv[1]) * c1[r] + sigmf(gv[0]) * tanhf(gv[2]);
            const float hn = sigmf(gv[3]) * tanhf(cn);
            c1[r] = cn;
            hloc[bl][ul] = f2bf(hn);
        }
        __syncthreads();
        {
            const int row = tid >> 3, c8 = tid & 7;
            const unsigned long long v = *(const unsigned long long*)&hloc[row][c8 * 4];
            st_u64(A.H1 + ((size_t)t * BATCH + b0 + row) * 256 + ub + c8 * 4, v);
        }
        gbar_arrive(bars + 2 * t);
        gbar_wait(A.xh2_done + t, 32);     // xh2 slice t ready (same-kernel producer)
        float xh[4][4];
#pragma unroll
        for (int r = 0; r < 4; ++r) {
            const int b = b0 + bsub * 16 + fq * 4 + r;
#pragma unroll
            for (int g = 0; g < 4; ++g)
                xh[r][g] = A.xh2[((size_t)t * 512 + b) * 1024 + g * HID + u];
        }
        gbar_wait(bars + 2 * t, 8);
        {
            f32x4 accB[4] = {};
            cell_g(A.H1 + ((size_t)t * BATCH + b0 + bsub * 16) * HID, HID,
                   Wfd0 + usub * 16384, accB, lane);
#pragma unroll
            for (int r = 0; r < 4; ++r) {
                const int b = b0 + bsub * 16 + fq * 4 + r;
                float gv[4];
#pragma unroll
                for (int g = 0; g < 4; ++g)
                    gv[g] = accB[g][r] + xh[r][g];
                const float cn = sigmf(gv[1]) * cf[r] + sigmf(gv[0]) * tanhf(gv[2]);
                const float hn = sigmf(gv[3]) * tanhf(cn);
                float p0 = hn * Gu[0], p1 = hn * Gu[1], p2 = hn * Gu[2];
#pragma unroll
                for (int s = 1; s < 16; s <<= 1) {
                    p0 += __shfl_xor(p0, s);
                    p1 += __shfl_xor(p1, s);
                    p2 += __shfl_xor(p2, s);
                }
                if (fr == 0) {
                    float* d = A.DELTA + ((size_t)t * 512 + b) * 3;
                    atomicAdd(d + 0, p0); atomicAdd(d + 1, p1); atomicAdd(d + 2, p2);
                }
            }
        }
        gbar_arrive(bars + 2 * t + 1);
    }
    gbar_wait(bars + 2 * (HWIN - 1) + 1, 8);
    if (tid < 192) {
        pred_lds[tid] += A.DELTA[((size_t)(HWIN - 1) * 512 + b0 + tid / 3) * 3 + tid % 3] + c3r;
        if (usup == 0)
            A.out[((size_t)(b0 + tid / 3) * HWIN + (HWIN - 1)) * 3 + tid % 3] = pred_lds[tid];
    }
}

// ---------------- G = out_W @ f2_W, c3 = out_b + out_W @ f2_b ----------------
__global__ __launch_bounds__(256)
void precompute_G(const float* __restrict__ f2W, const float* __restrict__ f2b,
                  const float* __restrict__ outW, const float* __restrict__ outb,
                  float* __restrict__ G, float* __restrict__ c3)
{
    const int k = threadIdx.x;
    float g0 = 0.f, g1 = 0.f, g2 = 0.f;
    for (int n = 0; n < HID; ++n) {
        const float w = f2W[n * HID + k];
        g0 += outW[n] * w;
        g1 += outW[HID + n] * w;
        g2 += outW[2 * HID + n] * w;
    }
    G[k] = g0; G[HID + k] = g1; G[2 * HID + k] = g2;
    if (k < 3) {
        float s = outb[k];
        for (int n = 0; n < HID; ++n) s += outW[k * HID + n] * f2b[n];
        c3[k] = s;
    }
}

extern "C" void kernel_launch(void* const* d_in, const int* in_sizes, int n_in,
                              void* d_out, int out_size, void* d_ws, size_t ws_size,
                              hipStream_t stream)
{
    (void)in_sizes; (void)n_in; (void)out_size; (void)ws_size;
    const float* enc_pos = (const float*)d_in[0];
    const float* enc_sal = (const float*)d_in[1];
    const float* dec_pos = (const float*)d_in[2];
    const float* dec_sal = (const float*)d_in[3];
    const float *pe_Wih = (const float*)d_in[4],  *pe_Whh = (const float*)d_in[5],
                *pe_bih = (const float*)d_in[6],  *pe_bhh = (const float*)d_in[7];
    const float *se_Wih = (const float*)d_in[8],  *se_Whh = (const float*)d_in[9],
                *se_bih = (const float*)d_in[10], *se_bhh = (const float*)d_in[11];
    const float *fe_Wih = (const float*)d_in[12], *fe_Whh = (const float*)d_in[13],
                *fe_bih = (const float*)d_in[14], *fe_bhh = (const float*)d_in[15];
    const float *pd_Wih = (const float*)d_in[16], *pd_Whh = (const float*)d_in[17],
                *pd_bih = (const float*)d_in[18], *pd_bhh = (const float*)d_in[19];
    const float *sd_Wih = (const float*)d_in[20], *sd_Whh = (const float*)d_in[21],
                *sd_bih = (const float*)d_in[22], *sd_bhh = (const float*)d_in[23];
    const float *fd_Wih = (const float*)d_in[24], *fd_Whh = (const float*)d_in[25],
                *fd_bih = (const float*)d_in[26], *fd_bhh = (const float*)d_in[27];
    const float *f2_W = (const float*)d_in[28], *f2_b = (const float*)d_in[29];
    const float *out_W = (const float*)d_in[30], *out_b = (const float*)d_in[31];
    float* out = (float*)d_out;
    float* ws  = (float*)d_ws;

    size_t off = 0;
    float* XG_SE = ws + off; off += (size_t)8192 * 1024;
    float* XG_FE = ws + off; off += (size_t)8192 * 1024;
    float* BIG   = ws + off; off += (size_t)12800 * 1024;
    float* BIG2  = ws + off; off += (size_t)12800 * 1024;
    float* GBIAS = ws + off; off += (size_t)BATCH * 1024;
    float* PE_C  = ws + off; off += BH;
    float* SE_C  = ws + off; off += BH;
    float* FE_C  = ws + off; off += BH;
    float* FEH   = ws + off; off += BH;
    float* Gm    = ws + off; off += 1024;
    float* C3    = ws + off; off += 8;
    float* DELTA = ws + off; off += (size_t)HWIN * BATCH * 3 + 64;
    unsigned int* BAR = (unsigned int*)(ws + off); off += 1280;
    ushort* WSE  = (ushort*)(ws + off); off += ((size_t)1024 * 4096) / 2;
    ushort* WSD  = (ushort*)(ws + off); off += ((size_t)1024 * 4096) / 2;
    ushort* WFE  = (ushort*)(ws + off); off += ((size_t)1024 * 512) / 2;
    ushort* WFD  = (ushort*)(ws + off); off += ((size_t)1024 * 512) / 2;
    ushort* WHpe = (ushort*)(ws + off); off += ((size_t)1024 * 256) / 2;
    ushort* WHse = (ushort*)(ws + off); off += ((size_t)1024 * 256) / 2;
    ushort* WHfe = (ushort*)(ws + off); off += ((size_t)1024 * 256) / 2;
    ushort* WHsd = (ushort*)(ws + off); off += ((size_t)1024 * 256) / 2;
    ushort* WHpd = (ushort*)(ws + off); off += ((size_t)1024 * 256) / 2;
    ushort* CONC = (ushort*)(ws + off); off += ((size_t)MENC * 512 * 512) / 2;
    ushort* SDB  = (ushort*)(ws + off); off += ((size_t)HWIN * BH) / 2;
    ushort* FEB  = (ushort*)(ws + off); off += ((size_t)MENC * BH) / 2;
    ushort* H1   = (ushort*)(ws + off); off += ((size_t)HWIN * BH) / 2;

    unsigned int* FE_DONE  = BAR + 1100;   // 16 slots
    unsigned int* XH2_DONE = BAR + 1128;   // 25 slots

    // DELTA and BAR contiguous: one memset (covers flags too)
    hipMemsetAsync(DELTA, 0, ((size_t)HWIN * BATCH * 3 + 64 + 1280) * 4, stream);

    // ---- all 9 weight conversions in ONE launch ----
    {
        Cvt9 a;
        const float* srcs[9] = { se_Wih, sd_Wih, fe_Wih, fd_Wih, pe_Whh, se_Whh, fe_Whh, sd_Whh, pd_Whh };
        ushort*      dsts[9] = { WSE,    WSD,    WFE,    WFD,    WHpe,   WHse,   WHfe,   WHsd,   WHpd };
        const int    n4s[9]  = { 1024*4096/4, 1024*4096/4, 1024*512/4, 1024*512/4,
                                 1024*256/4, 1024*256/4, 1024*256/4, 1024*256/4, 1024*256/4 };
        int acc9 = 0;
        for (int i = 0; i < 9; ++i) { a.s[i] = srcs[i]; a.d[i] = dsts[i]; acc9 += n4s[i]; a.end[i] = acc9; }
        cvt_multi<<<(acc9 + 255) / 256, 256, 0, stream>>>(a);
    }
    precompute_G<<<1, 256, 0, stream>>>(f2_W, f2_b, out_W, out_b, Gm, C3);

    // ---- se x-proj (alone) ----
    gemm128f<<<512, 512, 0, stream>>>(enc_sal, WSE, XG_SE, 8, 512);

    // ---- MERGED: encoder chains (128) + sd x-proj GEMM (800) ----
    {
        EncArgs a;
        a.WHse = WHse; a.WHpe = WHpe; a.xg_se = XG_SE; a.enc_pos = enc_pos;
        a.se_b1 = se_bih; a.se_b2 = se_bhh; a.pe_b1 = pe_bih; a.pe_b2 = pe_bhh;
        a.pe_Wih = pe_Wih; a.conc = CONC; a.SE_C = SE_C; a.PE_C = PE_C;
        a.bar = BAR;
        enc_sd<<<928, 512, 0, stream>>>(a, dec_sal, WSD, BIG);
    }

    // ---- MERGED: mid chains (128) + fe x-proj GEMM (512) ----
    {
        MidArgs a;
        a.WHsd = WHsd; a.WHfe = WHfe; a.xg_sd = BIG; a.xg_fe = XG_FE;
        a.sd_b1 = sd_bih; a.sd_b2 = sd_bhh; a.fe_b1 = fe_bih; a.fe_b2 = fe_bhh;
        a.conc = CONC; a.SE_C = SE_C; a.SDB = SDB; a.FEB = FEB;
        a.FEH = FEH; a.FE_C = FE_C; a.bar = BAR + 256; a.fe_done = FE_DONE;
        mid_fe<<<640, 512, 0, stream>>>(a, CONC, WFE, XG_FE);
    }

    // ---- GBIAS (needs FEH) ----
    gemm_tn<<<dim3(16, 8), 256, 0, stream>>>(FEH, fd_Whh, fd_bih, fd_bhh, GBIAS,
                                             BATCH, 1024, HID, HID, HID, 1024);

    // ---- MERGED: decoder (64) + xh2 GEMM (800, rbias = GBIAS) ----
    {
        DecArgs a;
        a.WHpd = WHpd; a.WFDh = WFD + 256;
        a.peF = CONC + ((size_t)15 * 512) * 512 + 256;
        a.PE_C = PE_C; a.FE_C = FE_C; a.xh2 = BIG2;
        a.pd_b1 = pd_bih; a.pd_b2 = pd_bhh; a.pd_Wih = pd_Wih;
        a.G = Gm; a.c3 = C3; a.dec_pos = dec_pos;
        a.H1 = H1; a.DELTA = DELTA; a.out = out; a.bar = BAR + 656;
        a.xh2_done = XH2_DONE;
        dec_xh2<<<864, 512, 0, stream>>>(a, SDB, WFD, BIG2, GBIAS);
    }
}

// Round 23
// 957.063 us; speedup vs baseline: 1.2664x; 1.0073x over previous
//
#include <hip/hip_runtime.h>

#define HID 256
#define BATCH 512
#define MENC 16
#define HWIN 25
#define SALSZ 4096
#define BH (BATCH * HID)   // 131072

typedef __attribute__((ext_vector_type(8))) short bf16x8;
typedef __attribute__((ext_vector_type(4))) float f32x4;

__device__ __forceinline__ float sigmf(float x) { return 1.0f / (1.0f + __expf(-x)); }
__device__ __forceinline__ ushort f2bf(float f) {
    uint32_t u = __float_as_uint(f);
    return (ushort)((u + 0x7fffu + ((u >> 16) & 1u)) >> 16);   // RNE
}

#define GLOAD_LDS(gp, lp) \
    __builtin_amdgcn_global_load_lds((const __attribute__((address_space(1))) void*)(gp), \
                                     (__attribute__((address_space(3))) void*)(lp), 16, 0, 0)

// ---- write-through stores for cross-block exchange (L3-visible; R7/R10-proven) ----
__device__ __forceinline__ void st_u64(void* p, unsigned long long v) {
    __hip_atomic_store((unsigned long long*)p, v, __ATOMIC_RELAXED, __HIP_MEMORY_SCOPE_AGENT);
}
__device__ __forceinline__ void st_f32(float* p, float v) {
    __hip_atomic_store(p, v, __ATOMIC_RELAXED, __HIP_MEMORY_SCOPE_AGENT);
}

// ---- split fence-free barrier (R14-proven) ----
__device__ __forceinline__ void gbar_arrive(unsigned int* slot)
{
    __syncthreads();    // drains vmcnt: this block's stores are L3-acked
    if (threadIdx.x == 0) atomicAdd(slot, 1u);
}
__device__ __forceinline__ void gbar_wait(unsigned int* slot, unsigned int nblk)
{
    if (threadIdx.x == 0) {
        while (__hip_atomic_load(slot, __ATOMIC_RELAXED, __HIP_MEMORY_SCOPE_AGENT) < nblk)
            __builtin_amdgcn_s_sleep(1);
    }
    __syncthreads();
}

// ---- W tile staging for chains: [64][256] bf16, XOR-swizzled 16B units ----
__device__ __forceinline__ void stage_wtile(const ushort* Wsrc, int ldw, int u0,
                                            ushort* lds, int lane, int wq)
{
    const int sub = lane >> 5, uu = lane & 31;
#pragma unroll
    for (int i = 0; i < 8; ++i) {
        const int row = i * 8 + wq * 2 + sub;
        const int su  = uu ^ (row & 7);
        const int gr  = (row >> 4) * HID + u0 + (row & 15);
        GLOAD_LDS(Wsrc + (size_t)gr * ldw + su * 8, lds + i * 2048 + wq * 512);
    }
}

// ---- chain cell quarter: H from global, W from swizzled LDS; 32 MFMA/wave ----
__device__ __forceinline__ void cell_g(const ushort* hrow0, int ldh,
                                       const ushort* WsL, f32x4 acc[4], int lane)
{
    const int fr = lane & 15, fq = lane >> 4;
    const ushort* hrow = hrow0 + (size_t)fr * ldh;
#pragma unroll
    for (int ks = 0; ks < 8; ++ks) {
        const bf16x8 af = *(const bf16x8*)(hrow + ks * 32 + fq * 8);
#pragma unroll
        for (int g = 0; g < 4; ++g) {
            const int vr = g * 16 + fr;
            const bf16x8 bf = *(const bf16x8*)(WsL + vr * 256 + (((ks * 4 + fq)) ^ (vr & 7)) * 8);
            acc[g] = __builtin_amdgcn_mfma_f32_16x16x32_bf16(af, bf, acc[g], 0, 0, 0);
        }
    }
}

// ---------------- fp32 -> bf16, 9 weight segments in one launch ----------------
struct Cvt9 {
    const float* s[9];
    ushort*      d[9];
    int          end[9];
};
__global__ __launch_bounds__(256)
void cvt_multi(Cvt9 A)
{
    int i = blockIdx.x * 256 + threadIdx.x;
    if (i >= A.end[8]) return;
    int seg = 0, beg = 0;
#pragma unroll
    for (int k = 0; k < 8; ++k)
        if (i >= A.end[k]) { seg = k + 1; beg = A.end[k]; }
    const int j = i - beg;
    const float4 v = *(const float4*)(A.s[seg] + (size_t)j * 4);
    *(ushort4*)(A.d[seg] + (size_t)j * 4) = make_ushort4(f2bf(v.x), f2bf(v.y), f2bf(v.z), f2bf(v.w));
}

// ======== 128x128 GEMM body, BK=64; fused fp32->bf16 A (R20-verified) ========
__device__ __forceinline__ void loadA128(const float* Ag, int lda, int tid, float4 ra[4])
{
#pragma unroll
    for (int j = 0; j < 2; ++j) {
        const int idx = j * 512 + tid;
        const int row = idx >> 3, u = idx & 7;
        const int su = (u ^ (row & 7)) * 8;
        ra[2 * j + 0] = *(const float4*)(Ag + (size_t)row * lda + su);
        ra[2 * j + 1] = *(const float4*)(Ag + (size_t)row * lda + su + 4);
    }
}
__device__ __forceinline__ void writeA128(const float4 ra[4], ushort* Al, int tid)
{
#pragma unroll
    for (int j = 0; j < 2; ++j) {
        const int idx = j * 512 + tid;
        uint4 v;
        v.x = (uint)f2bf(ra[2 * j].x) | ((uint)f2bf(ra[2 * j].y) << 16);
        v.y = (uint)f2bf(ra[2 * j].z) | ((uint)f2bf(ra[2 * j].w) << 16);
        v.z = (uint)f2bf(ra[2 * j + 1].x) | ((uint)f2bf(ra[2 * j + 1].y) << 16);
        v.w = (uint)f2bf(ra[2 * j + 1].z) | ((uint)f2bf(ra[2 * j + 1].w) << 16);
        *(uint4*)(Al + idx * 8) = v;
    }
}
__device__ __forceinline__ void stageB128(const ushort* Bg, int ldw, ushort* Bl, int tid)
{
#pragma unroll
    for (int j = 0; j < 2; ++j) {
        const int idx = j * 512 + tid;
        const int row = idx >> 3, u = idx & 7;
        const int su = (u ^ (row & 7)) * 8;
        GLOAD_LDS(Bg + (size_t)row * ldw + su, Bl + idx * 8);
    }
}

__device__ __forceinline__ void gemm128f_body(
    const float* __restrict__ A, const ushort* __restrict__ W, float* __restrict__ C,
    int lda, int ldw, int ldc, int K, int gx, int nwg, int bid,
    ushort* AsB, ushort* BsB, int tid)
{
    const int lane = tid & 63, wid = tid >> 6;
    {   // bijective XCD-chunked swizzle within this job's sub-grid
        const int q = nwg >> 3, r = nwg & 7;
        const int xcd = bid & 7, o = bid >> 3;
        bid = (xcd < r) ? xcd * (q + 1) + o : r * (q + 1) + (xcd - r) * q + o;
    }
    const int m0 = (bid / gx) * 128, n0 = (bid % gx) * 128;

    const int wr = wid >> 1, wc = wid & 1;     // 4m x 2n wave grid
    const int fr = lane & 15, fq = lane >> 4;

    f32x4 acc[2][4] = {};
    const int nt = K / 64;
    const float*  Ab0 = A + (size_t)m0 * lda;
    const ushort* Bb0 = W + (size_t)n0 * ldw;

    float4 ra[4];
    loadA128(Ab0, lda, tid, ra);
    stageB128(Bb0, ldw, BsB, tid);
    writeA128(ra, AsB, tid);
    loadA128(Ab0 + 64, lda, tid, ra);
    asm volatile("s_waitcnt vmcnt(4) lgkmcnt(0)" ::: "memory");
    __builtin_amdgcn_sched_barrier(0);
    __builtin_amdgcn_s_barrier();
    __builtin_amdgcn_sched_barrier(0);

    for (int t = 0; t < nt; ++t) {
        const int p = t & 1;
        const int t1 = (t + 1 < nt) ? t + 1 : nt - 1;
        const int t2 = (t + 2 < nt) ? t + 2 : nt - 1;
        stageB128(Bb0 + t1 * 64, ldw, BsB + (p ^ 1) * 8192, tid);
        writeA128(ra, AsB + (p ^ 1) * 8192, tid);
        loadA128(Ab0 + t2 * 64, lda, tid, ra);

        const ushort* Ab = AsB + p * 8192;
        const ushort* Bb = BsB + p * 8192;
#pragma unroll
        for (int ks = 0; ks < 2; ++ks) {
            bf16x8 bfr[4];
#pragma unroll
            for (int nf = 0; nf < 4; ++nf) {
                const int row = wc * 64 + nf * 16 + fr;
                bfr[nf] = *(const bf16x8*)(Bb + row * 64 + ((ks * 4 + fq) ^ (row & 7)) * 8);
            }
            bf16x8 af[2];
#pragma unroll
            for (int mf = 0; mf < 2; ++mf) {
                const int row = wr * 32 + mf * 16 + fr;
                af[mf] = *(const bf16x8*)(Ab + row * 64 + ((ks * 4 + fq) ^ (row & 7)) * 8);
            }
            __builtin_amdgcn_s_setprio(1);
#pragma unroll
            for (int mf = 0; mf < 2; ++mf)
#pragma unroll
                for (int nf = 0; nf < 4; ++nf)
                    acc[mf][nf] = __builtin_amdgcn_mfma_f32_16x16x32_bf16(
                        af[mf], bfr[nf], acc[mf][nf], 0, 0, 0);
            __builtin_amdgcn_s_setprio(0);
        }
        if (t == nt - 1) break;
        asm volatile("s_waitcnt vmcnt(4) lgkmcnt(0)" ::: "memory");
        __builtin_amdgcn_sched_barrier(0);
        __builtin_amdgcn_s_barrier();
        __builtin_amdgcn_sched_barrier(0);
    }

    const int cl = lane & 15, ch = lane >> 4;
#pragma unroll
    for (int mf = 0; mf < 2; ++mf)
#pragma unroll
        for (int nf = 0; nf < 4; ++nf)
#pragma unroll
            for (int r = 0; r < 4; ++r)
                C[(size_t)(m0 + wr * 32 + mf * 16 + ch * 4 + r) * ldc
                  + n0 + wc * 64 + nf * 16 + cl] = acc[mf][nf][r];
}

__global__ __launch_bounds__(512, 4)
void gemm128f(const float* __restrict__ A, const ushort* __restrict__ W,
              float* __restrict__ C, int gx, int nwg)
{
    __shared__ ushort As[2 * 128 * 64];
    __shared__ ushort Bs[2 * 128 * 64];
    gemm128f_body(A, W, C, SALSZ, SALSZ, 1024, SALSZ, gx, nwg, blockIdx.x, As, Bs, threadIdx.x);
}

// ======== 128x128 GEMM body, bf16 A/B, 2-phase; optional wait-flag (per slice),
// ======== optional signal-flag, optional write-through C. ========
__device__ __forceinline__ void gemm128b_body(
    const ushort* __restrict__ A, const ushort* __restrict__ W, float* __restrict__ C,
    int lda, int ldw, int ldc, int K, int gx, int nwg, int bid,
    unsigned int* wflag, unsigned int wcnt, unsigned int* sflag, bool wt,
    ushort* AsB, ushort* BsB, int tid)
{
    const int lane = tid & 63, wid = tid >> 6;
    {   // bijective XCD-chunked swizzle
        const int q = nwg >> 3, r = nwg & 7;
        const int xcd = bid & 7, o = bid >> 3;
        bid = (xcd < r) ? xcd * (q + 1) + o : r * (q + 1) + (xcd - r) * q + o;
    }
    const int m0 = (bid / gx) * 128, n0 = (bid % gx) * 128;

    if (wflag) gbar_wait(wflag + (m0 >> 9), wcnt);   // A slice ready (same-kernel producer)

    const int wr = wid >> 1, wc = wid & 1;
    const int fr = lane & 15, fq = lane >> 4;

    f32x4 acc[2][4] = {};
    const int nt = K / 64;
    const ushort* Ab0 = A + (size_t)m0 * lda;
    const ushort* Bb0 = W + (size_t)n0 * ldw;

    stageB128(Ab0, lda, AsB, tid);
    stageB128(Bb0, ldw, BsB, tid);
    __syncthreads();

    for (int t = 0; t < nt; ++t) {
        const int p = t & 1;
        if (t + 1 < nt) {
            stageB128(Ab0 + (t + 1) * 64, lda, AsB + (p ^ 1) * 8192, tid);
            stageB128(Bb0 + (t + 1) * 64, ldw, BsB + (p ^ 1) * 8192, tid);
        }
        const ushort* Ab = AsB + p * 8192;
        const ushort* Bb = BsB + p * 8192;
#pragma unroll
        for (int ks = 0; ks < 2; ++ks) {
            bf16x8 bfr[4];
#pragma unroll
            for (int nf = 0; nf < 4; ++nf) {
                const int row = wc * 64 + nf * 16 + fr;
                bfr[nf] = *(const bf16x8*)(Bb + row * 64 + ((ks * 4 + fq) ^ (row & 7)) * 8);
            }
            bf16x8 af[2];
#pragma unroll
            for (int mf = 0; mf < 2; ++mf) {
                const int row = wr * 32 + mf * 16 + fr;
                af[mf] = *(const bf16x8*)(Ab + row * 64 + ((ks * 4 + fq) ^ (row & 7)) * 8);
            }
#pragma unroll
            for (int mf = 0; mf < 2; ++mf)
#pragma unroll
                for (int nf = 0; nf < 4; ++nf)
                    acc[mf][nf] = __builtin_amdgcn_mfma_f32_16x16x32_bf16(
                        af[mf], bfr[nf], acc[mf][nf], 0, 0, 0);
        }
        if (t == nt - 1) break;
        __syncthreads();
    }

    const int cl = lane & 15, ch = lane >> 4;
#pragma unroll
    for (int mf = 0; mf < 2; ++mf)
#pragma unroll
        for (int nf = 0; nf < 4; ++nf)
#pragma unroll
            for (int r = 0; r < 4; ++r) {
                const int mm = m0 + wr * 32 + mf * 16 + ch * 4 + r;
                const int nn = n0 + wc * 64 + nf * 16 + cl;
                if (wt) st_f32(C + (size_t)mm * ldc + nn, acc[mf][nf][r]);
                else    C[(size_t)mm * ldc + nn] = acc[mf][nf][r];
            }
    if (sflag) {
        __syncthreads();   // drain write-throughs
        if (tid == 0) atomicAdd(sflag + (m0 >> 9), 1u);
    }
}

// ---------------- merged: encoder chains (0..127) + sd GEMM (128..927) ----------------
struct EncArgs {
    const ushort *WHse, *WHpe;
    const float  *xg_se;
    const float  *enc_pos;
    const float  *se_b1, *se_b2, *pe_b1, *pe_b2;
    const float  *pe_Wih;
    ushort       *conc;      // [16][512][512]
    float        *SE_C, *PE_C;
    unsigned int *bar;       // 16 groups x 16 steps, degree 8
};

__global__ __launch_bounds__(512, 4)
void enc_sd(EncArgs A, const float* __restrict__ sdA, const ushort* __restrict__ sdW,
            float* __restrict__ sdC)
{
    __shared__ ushort sh[34816];
    const int tid = threadIdx.x;

    if (blockIdx.x >= 128) {
        gemm128f_body(sdA, sdW, sdC, SALSZ, SALSZ, 1024, SALSZ, 8, 800,
                      (int)blockIdx.x - 128, sh, sh + 16384, tid);
        return;
    }

    const int lane = tid & 63, w = tid >> 6;
    const int role  = blockIdx.x >> 6;
    const int rem   = blockIdx.x & 63;
    const int btile = rem & 7, usup = rem >> 3;
    const int b0 = btile * 64, ub = usup * 32;
    const int usub = w & 1, bsub = w >> 1;
    const int u0t = ub + usub * 16;
    const int grp = role * 8 + btile;
    const int fr = lane & 15, fq = lane >> 4;
    const int u = u0t + fr;
    const int ul = usub * 16 + fr;
    const int coff = role ? 256 : 0;
    ushort* Ws0 = sh + usub * 16384;
    ushort (*hloc)[32] = (ushort(*)[32])(sh + 32768);

    stage_wtile(role ? A.WHpe : A.WHse, HID, u0t, Ws0, lane, bsub);

    const float* b1 = role ? A.pe_b1 : A.se_b1;
    const float* b2 = role ? A.pe_b2 : A.se_b2;
    float bias[4], wxs[4][3];
#pragma unroll
    for (int g = 0; g < 4; ++g) {
        bias[g] = b1[g * HID + u] + b2[g * HID + u];
        wxs[g][0] = wxs[g][1] = wxs[g][2] = 0.0f;
        if (role) {
            wxs[g][0] = A.pe_Wih[(g * HID + u) * 3 + 0];
            wxs[g][1] = A.pe_Wih[(g * HID + u) * 3 + 1];
            wxs[g][2] = A.pe_Wih[(g * HID + u) * 3 + 2];
        }
    }
    float c[4] = {0.f, 0.f, 0.f, 0.f};
    __syncthreads();

    for (int t = 0; t < MENC; ++t) {
        float xg[4][4];
#pragma unroll
        for (int r = 0; r < 4; ++r) {
            const int b = b0 + bsub * 16 + fq * 4 + r;
            if (role) {
                const float* xp = A.enc_pos + ((size_t)b * MENC + t) * 3;
                xg[r][0] = xp[0]; xg[r][1] = xp[1]; xg[r][2] = xp[2]; xg[r][3] = 0.f;
            } else {
#pragma unroll
                for (int g = 0; g < 4; ++g)
                    xg[r][g] = A.xg_se[((size_t)b * MENC + t) * 1024 + g * HID + u];
            }
        }
        if (t > 0) gbar_wait(A.bar + grp * MENC + (t - 1), 8);
        f32x4 acc[4] = {};
        if (t > 0)
            cell_g(A.conc + ((size_t)(t - 1) * 512 + b0 + bsub * 16) * 512 + coff, 512,
                   Ws0, acc, lane);
#pragma unroll
        for (int r = 0; r < 4; ++r) {
            const int bl = bsub * 16 + fq * 4 + r;
            const int b = b0 + bl;
            float gv[4];
#pragma unroll
            for (int g = 0; g < 4; ++g) {
                float v = acc[g][r] + bias[g];
                if (role) v += xg[r][0] * wxs[g][0] + xg[r][1] * wxs[g][1] + xg[r][2] * wxs[g][2];
                else      v += xg[r][g];
                gv[g] = v;
            }
            const float cn = sigmf(gv[1]) * c[r] + sigmf(gv[0]) * tanhf(gv[2]);
            const float hn = sigmf(gv[3]) * tanhf(cn);
            c[r] = cn;
            hloc[bl][ul] = f2bf(hn);
            if (t == MENC - 1) (role ? A.PE_C : A.SE_C)[(size_t)b * HID + u] = cn;
        }
        __syncthreads();
        {
            const int row = tid >> 3, c8 = tid & 7;
            const unsigned long long v = *(const unsigned long long*)&hloc[row][c8 * 4];
            st_u64(A.conc + ((size_t)t * 512 + b0 + row) * 512 + coff + ub + c8 * 4, v);
        }
        if (t != MENC - 1) gbar_arrive(A.bar + grp * MENC + t);
    }
}

// ---------------- merged: mid chains (0..127) + fe GEMM (128..639) + xh2 GEMM (640..1439) ----------------
struct MidArgs {
    const ushort *WHsd, *WHfe;
    const float  *xg_sd;
    const float  *xg_fe;
    const float  *sd_b1, *sd_b2, *fe_b1, *fe_b2;
    const ushort *conc;
    const float  *SE_C;
    ushort       *SDB;       // [25][512][256]
    ushort       *FEB;       // [16][512][256]
    float        *FEH, *FE_C;
    unsigned int *bar;       // 16 groups x 25 steps, degree 8
    unsigned int *fe_done;   // [16] slice flags (32 blocks each)
    unsigned int *sdb_done;  // [25] slice flags (64 sd-role blocks each)
};

__global__ __launch_bounds__(512, 4)
void mid_fe_xh2(MidArgs A, const ushort* __restrict__ feA, const ushort* __restrict__ feW,
                float* __restrict__ feC,
                const ushort* __restrict__ xA, const ushort* __restrict__ xW,
                float* __restrict__ xC)
{
    __shared__ ushort sh[34816];
    const int tid = threadIdx.x;

    if (blockIdx.x >= 640) {
        // xh2 GEMM: A = SDB rows (t,b); waits per-slice on sd-role; plain C stores
        gemm128b_body(xA, xW, xC, 256, 512, 1024, 256, 8, 800,
                      (int)blockIdx.x - 640, A.sdb_done, 64, nullptr, false,
                      sh, sh + 16384, tid);
        return;
    }
    if (blockIdx.x >= 128) {
        // fe GEMM: write-through C + fe_done slice flags (same-kernel mid readers)
        gemm128b_body(feA, feW, feC, 512, 512, 1024, 512, 8, 512,
                      (int)blockIdx.x - 128, nullptr, 0, A.fe_done, true,
                      sh, sh + 16384, tid);
        return;
    }

    const int lane = tid & 63, w = tid >> 6;
    const int role  = blockIdx.x >> 6;          // 0 = sd, 1 = fe
    const int rem   = blockIdx.x & 63;
    const int btile = rem & 7, usup = rem >> 3;
    const int b0 = btile * 64, ub = usup * 32;
    const int usub = w & 1, bsub = w >> 1;
    const int u0t = ub + usub * 16;
    const int grp = role * 8 + btile;
    const int fr = lane & 15, fq = lane >> 4;
    const int u = u0t + fr;
    const int ul = usub * 16 + fr;
    const int NT = role ? MENC : HWIN;
    ushort* Ws0 = sh + usub * 16384;
    ushort (*hloc)[32] = (ushort(*)[32])(sh + 32768);

    stage_wtile(role ? A.WHfe : A.WHsd, HID, u0t, Ws0, lane, bsub);

    const float* b1 = role ? A.fe_b1 : A.sd_b1;
    const float* b2 = role ? A.fe_b2 : A.sd_b2;
    float bias[4];
#pragma unroll
    for (int g = 0; g < 4; ++g) bias[g] = b1[g * HID + u] + b2[g * HID + u];

    float c[4];
#pragma unroll
    for (int r = 0; r < 4; ++r) {
        const int b = b0 + bsub * 16 + fq * 4 + r;
        c[r] = role ? 0.0f : A.SE_C[(size_t)b * HID + u];
    }
    __syncthreads();

    for (int t = 0; t < NT; ++t) {
        if (role) gbar_wait(A.fe_done + t, 32);   // XG_FE slice t ready
        float xg[4][4];
#pragma unroll
        for (int r = 0; r < 4; ++r) {
            const int b = b0 + bsub * 16 + fq * 4 + r;
#pragma unroll
            for (int g = 0; g < 4; ++g)
                xg[r][g] = role ? A.xg_fe[((size_t)t * 512 + b) * 1024 + g * HID + u]
                                : A.xg_sd[((size_t)b * HWIN + t) * 1024 + g * HID + u];
        }
        if (t > 0) gbar_wait(A.bar + grp * HWIN + (t - 1), 8);
        f32x4 acc[4] = {};
        if (role == 0) {
            if (t == 0) cell_g(A.conc + ((size_t)15 * 512 + b0 + bsub * 16) * 512, 512,
                               Ws0, acc, lane);
            else        cell_g(A.SDB + ((size_t)(t - 1) * 512 + b0 + bsub * 16) * HID, HID,
                               Ws0, acc, lane);
        } else if (t > 0) {
            cell_g(A.FEB + ((size_t)(t - 1) * BATCH + b0 + bsub * 16) * HID, HID,
                   Ws0, acc, lane);
        }
#pragma unroll
        for (int r = 0; r < 4; ++r) {
            const int bl = bsub * 16 + fq * 4 + r;
            const int b = b0 + bl;
            float gv[4];
#pragma unroll
            for (int g = 0; g < 4; ++g)
                gv[g] = acc[g][r] + bias[g] + xg[r][g];
            const float cn = sigmf(gv[1]) * c[r] + sigmf(gv[0]) * tanhf(gv[2]);
            const float hn = sigmf(gv[3]) * tanhf(cn);
            c[r] = cn;
            hloc[bl][ul] = f2bf(hn);
            if (role == 1 && t == MENC - 1) {
                A.FEH[(size_t)b * HID + u] = hn;
                A.FE_C[(size_t)b * HID + u] = cn;
            }
        }
        __syncthreads();
        {
            const int row = tid >> 3, c8 = tid & 7;
            const unsigned long long v = *(const unsigned long long*)&hloc[row][c8 * 4];
            ushort* dst = role ? (A.FEB + ((size_t)t * BATCH + b0 + row) * 256 + ub + c8 * 4)
                               : (A.SDB + ((size_t)t * 512 + b0 + row) * 256 + ub + c8 * 4);
            st_u64(dst, v);
        }
        __syncthreads();   // drain h stores before signaling
        if (tid == 0) {
            if (role == 0) atomicAdd(A.sdb_done + t, 1u);       // SDB slice t contribution
            if (t != NT - 1) atomicAdd(A.bar + grp * HWIN + t, 1u);
        }
    }
}

// ---------------- fp32 tiled GEMM (GBIAS one-off) ----------------
__global__ __launch_bounds__(256)
void gemm_tn(const float* __restrict__ A, const float* __restrict__ W,
             const float* __restrict__ b1, const float* __restrict__ b2,
             float* __restrict__ C,
             int M, int N, int K, int lda, int ldw, int ldc)
{
    __shared__ float AsT[16][68];
    __shared__ float WsT[16][68];
    const int t  = threadIdx.x;
    const int tx = t & 15, ty = t >> 4;
    const int m0 = blockIdx.y * 64, n0 = blockIdx.x * 64;
    const int lr = t >> 2;
    const int c4 = t & 3;

    float acc[4][4];
#pragma unroll
    for (int i = 0; i < 4; ++i)
#pragma unroll
        for (int j = 0; j < 4; ++j) acc[i][j] = 0.0f;

    for (int k0 = 0; k0 < K; k0 += 16) {
        float a[4], w[4];
        const int kb = k0 + c4 * 4;
#pragma unroll
        for (int k = 0; k < 4; ++k) {
            a[k] = (kb + k < K) ? A[(size_t)(m0 + lr) * lda + kb + k] : 0.0f;
            w[k] = (kb + k < K) ? W[(size_t)(n0 + lr) * ldw + kb + k] : 0.0f;
        }
        __syncthreads();
#pragma unroll
        for (int k = 0; k < 4; ++k) {
            AsT[c4 * 4 + k][lr] = a[k];
            WsT[c4 * 4 + k][lr] = w[k];
        }
        __syncthreads();
#pragma unroll
        for (int kk = 0; kk < 16; ++kk) {
            const float4 av = *(const float4*)&AsT[kk][ty * 4];
            const float4 wv = *(const float4*)&WsT[kk][tx * 4];
            acc[0][0] += av.x * wv.x; acc[0][1] += av.x * wv.y; acc[0][2] += av.x * wv.z; acc[0][3] += av.x * wv.w;
            acc[1][0] += av.y * wv.x; acc[1][1] += av.y * wv.y; acc[1][2] += av.y * wv.z; acc[1][3] += av.y * wv.w;
            acc[2][0] += av.z * wv.x; acc[2][1] += av.z * wv.y; acc[2][2] += av.z * wv.z; acc[2][3] += av.z * wv.w;
            acc[3][0] += av.w * wv.x; acc[3][1] += av.w * wv.y; acc[3][2] += av.w * wv.z; acc[3][3] += av.w * wv.w;
        }
    }

#pragma unroll
    for (int i = 0; i < 4; ++i) {
        const int m = m0 + ty * 4 + i;
#pragma unroll
        for (int j = 0; j < 4; ++j) {
            const int n = n0 + tx * 4 + j;
            float v = acc[i][j];
            if (b1) v += b1[n];
            if (b2) v += b2[n];
            C[(size_t)m * ldc + n] = v;
        }
    }
}

// ---------------- persistent decoder: pd + fd + tail, 25 steps (R20 + gb init) ----------------
struct DecArgs {
    const ushort *WHpd;
    const ushort *WFDh;
    const ushort *peF;
    const float  *PE_C, *FE_C, *GBIAS;
    const float  *xh2;
    const float  *pd_b1, *pd_b2, *pd_Wih;
    const float  *G, *c3, *dec_pos;
    ushort       *H1;        // [25][512][256]
    float        *DELTA;     // [25][512][3], pre-zeroed
    float        *out;       // [512][25][3]
    unsigned int *bar;       // 8 groups x 50
};

__global__ __launch_bounds__(512)
void dec_chain(DecArgs A)
{
    __shared__ ushort Wpd[2][64 * 256], Wfd[2][64 * 256];
    __shared__ ushort hloc[64][32];
    __shared__ float pred_lds[192];
    const int tid = threadIdx.x, lane = tid & 63, w = tid >> 6;
    const int btile = blockIdx.x & 7, usup = blockIdx.x >> 3;
    const int b0 = btile * 64, ub = usup * 32;
    const int usub = w & 1, bsub = w >> 1;
    const int u0t = ub + usub * 16;
    const int fr = lane & 15, fq = lane >> 4;
    const int u = u0t + fr;
    const int ul = usub * 16 + fr;
    unsigned int* bars = A.bar + btile * 2 * HWIN;

    stage_wtile(A.WHpd, HID, u0t, Wpd[usub], lane, bsub);
    stage_wtile(A.WFDh, 512, u0t, Wfd[usub], lane, bsub);

    float pdb[4], wxs[4][3], cf[4], c1[4], Gu[3], gb[4][4];
#pragma unroll
    for (int g = 0; g < 4; ++g) {
        pdb[g] = A.pd_b1[g * HID + u] + A.pd_b2[g * HID + u];
        wxs[g][0] = A.pd_Wih[(g * HID + u) * 3 + 0];
        wxs[g][1] = A.pd_Wih[(g * HID + u) * 3 + 1];
        wxs[g][2] = A.pd_Wih[(g * HID + u) * 3 + 2];
    }
#pragma unroll
    for (int r = 0; r < 4; ++r) {
        const int b = b0 + bsub * 16 + fq * 4 + r;
        c1[r] = A.PE_C[(size_t)b * HID + u];
        cf[r] = A.FE_C[(size_t)b * HID + u];
#pragma unroll
        for (int g = 0; g < 4; ++g) gb[r][g] = A.GBIAS[(size_t)b * 1024 + g * HID + u];
    }
    Gu[0] = A.G[0 * HID + u]; Gu[1] = A.G[1 * HID + u]; Gu[2] = A.G[2 * HID + u];
    const float c3r = (tid < 192) ? A.c3[tid % 3] : 0.0f;
    if (tid < 192) pred_lds[tid] = A.dec_pos[(size_t)(b0 + tid / 3) * 3 + tid % 3];
    __syncthreads();

    for (int t = 0; t < HWIN; ++t) {
        f32x4 acc[4] = {};
        if (t == 0) cell_g(A.peF + (size_t)(b0 + bsub * 16) * 512, 512, Wpd[usub], acc, lane);
        else        cell_g(A.H1 + ((size_t)(t - 1) * BATCH + b0 + bsub * 16) * HID, HID,
                           Wpd[usub], acc, lane);
        if (t > 0) {
            gbar_wait(bars + 2 * (t - 1) + 1, 8);
            if (tid < 192) {
                pred_lds[tid] += A.DELTA[((size_t)(t - 1) * 512 + b0 + tid / 3) * 3 + tid % 3] + c3r;
                if (usup == 0)
                    A.out[((size_t)(b0 + tid / 3) * HWIN + (t - 1)) * 3 + tid % 3] = pred_lds[tid];
            }
            __syncthreads();
        }
#pragma unroll
        for (int r = 0; r < 4; ++r) {
            const int bl = bsub * 16 + fq * 4 + r;
            const float x0 = pred_lds[bl * 3 + 0];
            const float x1 = pred_lds[bl * 3 + 1];
            const float x2 = pred_lds[bl * 3 + 2];
            float gv[4];
#pragma unroll
            for (int g = 0; g < 4; ++g)
                gv[g] = acc[g][r] + pdb[g] + x0 * wxs[g][0] + x1 * wxs[g][1] + x2 * wxs[g][2];
            const float cn = sigmf(gv[1]) * c1[r] + sigmf(gv[0]) * tanhf(gv[2]);
            const float hn = sigmf(gv[3]) * tanhf(cn);
            c1[r] = cn;
            hloc[bl][ul] = f2bf(hn);
        }
        __syncthreads();
        {
            const int row = tid >> 3, c8 = tid & 7;
            const unsigned long long v = *(const unsigned long long*)&hloc[row][c8 * 4];
            st_u64(A.H1 + ((size_t)t * BATCH + b0 + row) * 256 + ub + c8 * 4, v);
        }
        gbar_arrive(bars + 2 * t);
        float xh[4][4];
#pragma unroll
        for (int r = 0; r < 4; ++r) {
            const int b = b0 + bsub * 16 + fq * 4 + r;
#pragma unroll
            for (int g = 0; g < 4; ++g)
                xh[r][g] = A.xh2[((size_t)t * 512 + b) * 1024 + g * HID + u];
        }
        gbar_wait(bars + 2 * t, 8);
        {
            f32x4 accB[4] = {};
            cell_g(A.H1 + ((size_t)t * BATCH + b0 + bsub * 16) * HID, HID,
                   Wfd[usub], accB, lane);
#pragma unroll
            for (int r = 0; r < 4; ++r) {
                const int b = b0 + bsub * 16 + fq * 4 + r;
                float gv[4];
#pragma unroll
                for (int g = 0; g < 4; ++g)
                    gv[g] = accB[g][r] + xh[r][g] + gb[r][g];
                const float cn = sigmf(gv[1]) * cf[r] + sigmf(gv[0]) * tanhf(gv[2]);
                const float hn = sigmf(gv[3]) * tanhf(cn);
                float p0 = hn * Gu[0], p1 = hn * Gu[1], p2 = hn * Gu[2];
#pragma unroll
                for (int s = 1; s < 16; s <<= 1) {
                    p0 += __shfl_xor(p0, s);
                    p1 += __shfl_xor(p1, s);
                    p2 += __shfl_xor(p2, s);
                }
                if (fr == 0) {
                    float* d = A.DELTA + ((size_t)t * 512 + b) * 3;
                    atomicAdd(d + 0, p0); atomicAdd(d + 1, p1); atomicAdd(d + 2, p2);
                }
            }
        }
        gbar_arrive(bars + 2 * t + 1);
    }
    gbar_wait(bars + 2 * (HWIN - 1) + 1, 8);
    if (tid < 192) {
        pred_lds[tid] += A.DELTA[((size_t)(HWIN - 1) * 512 + b0 + tid / 3) * 3 + tid % 3] + c3r;
        if (usup == 0)
            A.out[((size_t)(b0 + tid / 3) * HWIN + (HWIN - 1)) * 3 + tid % 3] = pred_lds[tid];
    }
}

// ---------------- G = out_W @ f2_W, c3 = out_b + out_W @ f2_b ----------------
__global__ __launch_bounds__(256)
void precompute_G(const float* __restrict__ f2W, const float* __restrict__ f2b,
                  const float* __restrict__ outW, const float* __restrict__ outb,
                  float* __restrict__ G, float* __restrict__ c3)
{
    const int k = threadIdx.x;
    float g0 = 0.f, g1 = 0.f, g2 = 0.f;
    for (int n = 0; n < HID; ++n) {
        const float w = f2W[n * HID + k];
        g0 += outW[n] * w;
        g1 += outW[HID + n] * w;
        g2 += outW[2 * HID + n] * w;
    }
    G[k] = g0; G[HID + k] = g1; G[2 * HID + k] = g2;
    if (k < 3) {
        float s = outb[k];
        for (int n = 0; n < HID; ++n) s += outW[k * HID + n] * f2b[n];
        c3[k] = s;
    }
}

extern "C" void kernel_launch(void* const* d_in, const int* in_sizes, int n_in,
                              void* d_out, int out_size, void* d_ws, size_t ws_size,
                              hipStream_t stream)
{
    (void)in_sizes; (void)n_in; (void)out_size; (void)ws_size;
    const float* enc_pos = (const float*)d_in[0];
    const float* enc_sal = (const float*)d_in[1];
    const float* dec_pos = (const float*)d_in[2];
    const float* dec_sal = (const float*)d_in[3];
    const float *pe_Wih = (const float*)d_in[4],  *pe_Whh = (const float*)d_in[5],
                *pe_bih = (const float*)d_in[6],  *pe_bhh = (const float*)d_in[7];
    const float *se_Wih = (const float*)d_in[8],  *se_Whh = (const float*)d_in[9],
                *se_bih = (const float*)d_in[10], *se_bhh = (const float*)d_in[11];
    const float *fe_Wih = (const float*)d_in[12], *fe_Whh = (const float*)d_in[13],
                *fe_bih = (const float*)d_in[14], *fe_bhh = (const float*)d_in[15];
    const float *pd_Wih = (const float*)d_in[16], *pd_Whh = (const float*)d_in[17],
                *pd_bih = (const float*)d_in[18], *pd_bhh = (const float*)d_in[19];
    const float *sd_Wih = (const float*)d_in[20], *sd_Whh = (const float*)d_in[21],
                *sd_bih = (const float*)d_in[22], *sd_bhh = (const float*)d_in[23];
    const float *fd_Wih = (const float*)d_in[24], *fd_Whh = (const float*)d_in[25],
                *fd_bih = (const float*)d_in[26], *fd_bhh = (const float*)d_in[27];
    const float *f2_W = (const float*)d_in[28], *f2_b = (const float*)d_in[29];
    const float *out_W = (const float*)d_in[30], *out_b = (const float*)d_in[31];
    float* out = (float*)d_out;
    float* ws  = (float*)d_ws;

    size_t off = 0;
    float* XG_SE = ws + off; off += (size_t)8192 * 1024;
    float* XG_FE = ws + off; off += (size_t)8192 * 1024;
    float* BIG   = ws + off; off += (size_t)12800 * 1024;
    float* BIG2  = ws + off; off += (size_t)12800 * 1024;
    float* GBIAS = ws + off; off += (size_t)BATCH * 1024;
    float* PE_C  = ws + off; off += BH;
    float* SE_C  = ws + off; off += BH;
    float* FE_C  = ws + off; off += BH;
    float* FEH   = ws + off; off += BH;
    float* Gm    = ws + off; off += 1024;
    float* C3    = ws + off; off += 8;
    float* DELTA = ws + off; off += (size_t)HWIN * BATCH * 3 + 64;
    unsigned int* BAR = (unsigned int*)(ws + off); off += 1280;
    ushort* WSE  = (ushort*)(ws + off); off += ((size_t)1024 * 4096) / 2;
    ushort* WSD  = (ushort*)(ws + off); off += ((size_t)1024 * 4096) / 2;
    ushort* WFE  = (ushort*)(ws + off); off += ((size_t)1024 * 512) / 2;
    ushort* WFD  = (ushort*)(ws + off); off += ((size_t)1024 * 512) / 2;
    ushort* WHpe = (ushort*)(ws + off); off += ((size_t)1024 * 256) / 2;
    ushort* WHse = (ushort*)(ws + off); off += ((size_t)1024 * 256) / 2;
    ushort* WHfe = (ushort*)(ws + off); off += ((size_t)1024 * 256) / 2;
    ushort* WHsd = (ushort*)(ws + off); off += ((size_t)1024 * 256) / 2;
    ushort* WHpd = (ushort*)(ws + off); off += ((size_t)1024 * 256) / 2;
    ushort* CONC = (ushort*)(ws + off); off += ((size_t)MENC * 512 * 512) / 2;
    ushort* SDB  = (ushort*)(ws + off); off += ((size_t)HWIN * BH) / 2;
    ushort* FEB  = (ushort*)(ws + off); off += ((size_t)MENC * BH) / 2;
    ushort* H1   = (ushort*)(ws + off); off += ((size_t)HWIN * BH) / 2;

    unsigned int* FE_DONE  = BAR + 1100;   // 16 slots
    unsigned int* SDB_DONE = BAR + 1160;   // 25 slots

    // DELTA and BAR contiguous: one memset (covers flags too)
    hipMemsetAsync(DELTA, 0, ((size_t)HWIN * BATCH * 3 + 64 + 1280) * 4, stream);

    // ---- all 9 weight conversions in ONE launch ----
    {
        Cvt9 a;
        const float* srcs[9] = { se_Wih, sd_Wih, fe_Wih, fd_Wih, pe_Whh, se_Whh, fe_Whh, sd_Whh, pd_Whh };
        ushort*      dsts[9] = { WSE,    WSD,    WFE,    WFD,    WHpe,   WHse,   WHfe,   WHsd,   WHpd };
        const int    n4s[9]  = { 1024*4096/4, 1024*4096/4, 1024*512/4, 1024*512/4,
                                 1024*256/4, 1024*256/4, 1024*256/4, 1024*256/4, 1024*256/4 };
        int acc9 = 0;
        for (int i = 0; i < 9; ++i) { a.s[i] = srcs[i]; a.d[i] = dsts[i]; acc9 += n4s[i]; a.end[i] = acc9; }
        cvt_multi<<<(acc9 + 255) / 256, 256, 0, stream>>>(a);
    }
    precompute_G<<<1, 256, 0, stream>>>(f2_W, f2_b, out_W, out_b, Gm, C3);

    // ---- se x-proj (alone) ----
    gemm128f<<<512, 512, 0, stream>>>(enc_sal, WSE, XG_SE, 8, 512);

    // ---- MERGED: encoder chains (128) + sd x-proj GEMM (800) ----
    {
        EncArgs a;
        a.WHse = WHse; a.WHpe = WHpe; a.xg_se = XG_SE; a.enc_pos = enc_pos;
        a.se_b1 = se_bih; a.se_b2 = se_bhh; a.pe_b1 = pe_bih; a.pe_b2 = pe_bhh;
        a.pe_Wih = pe_Wih; a.conc = CONC; a.SE_C = SE_C; a.PE_C = PE_C;
        a.bar = BAR;
        enc_sd<<<928, 512, 0, stream>>>(a, dec_sal, WSD, BIG);
    }

    // ---- MERGED: mid chains (128) + fe GEMM (512) + xh2 GEMM (800, slice-gated) ----
    {
        MidArgs a;
        a.WHsd = WHsd; a.WHfe = WHfe; a.xg_sd = BIG; a.xg_fe = XG_FE;
        a.sd_b1 = sd_bih; a.sd_b2 = sd_bhh; a.fe_b1 = fe_bih; a.fe_b2 = fe_bhh;
        a.conc = CONC; a.SE_C = SE_C; a.SDB = SDB; a.FEB = FEB;
        a.FEH = FEH; a.FE_C = FE_C; a.bar = BAR + 256;
        a.fe_done = FE_DONE; a.sdb_done = SDB_DONE;
        mid_fe_xh2<<<1440, 512, 0, stream>>>(a, CONC, WFE, XG_FE, SDB, WFD, BIG2);
    }

    // ---- GBIAS (needs FEH) ----
    gemm_tn<<<dim3(16, 8), 256, 0, stream>>>(FEH, fd_Whh, fd_bih, fd_bhh, GBIAS,
                                             BATCH, 1024, HID, HID, HID, 1024);

    // ---- persistent decoder (pd + fd + tail): 64 blocks x 512 ----
    {
        DecArgs a;
        a.WHpd = WHpd; a.WFDh = WFD + 256;
        a.peF = CONC + ((size_t)15 * 512) * 512 + 256;
        a.PE_C = PE_C; a.FE_C = FE_C; a.GBIAS = GBIAS; a.xh2 = BIG2;
        a.pd_b1 = pd_bih; a.pd_b2 = pd_bhh; a.pd_Wih = pd_Wih;
        a.G = Gm; a.c3 = C3; a.dec_pos = dec_pos;
        a.H1 = H1; a.DELTA = DELTA; a.out = out; a.bar = BAR + 656;
        dec_chain<<<64, 512, 0, stream>>>(a);
    }
}